// Round 3
// baseline (3126.468 us; speedup 1.0000x reference)
//
#include <hip/hip_runtime.h>
#include <hip/hip_bf16.h>
#include <math.h>

#define NN 50000
#define EE 640000
#define HD 128
#define ECD 64
#define NHD 4
#define HH 32
#define EPB 8
#define SCAN_B 256
#define NBLK ((NN + SCAN_B - 1) / SCAN_B)   // 196

__device__ __forceinline__ float ssp_f(float v) {
    return fmaxf(v, 0.0f) + log1pf(expf(-fabsf(v))) - 0.69314718055994531f;
}

// ---------------- K1: LN1 + per-head projections ----------------
__global__ __launch_bounds__(128) void k_node_prep(
    const float* __restrict__ x, const float* __restrict__ k_w,
    const float* __restrict__ q_w, const float* __restrict__ v_w,
    const float* __restrict__ ln1_g, const float* __restrict__ ln1_b,
    float* __restrict__ h_k, float* __restrict__ h_q, float* __restrict__ h_v)
{
    const int n = blockIdx.x;
    const int t = threadIdx.x;
    __shared__ float sy[HD];
    __shared__ float red[4];

    float xv = x[(size_t)n * HD + t];
    float s1 = xv, s2 = xv * xv;
    #pragma unroll
    for (int off = 32; off; off >>= 1) {
        s1 += __shfl_down(s1, off);
        s2 += __shfl_down(s2, off);
    }
    const int wid = t >> 6;
    if ((t & 63) == 0) { red[wid * 2] = s1; red[wid * 2 + 1] = s2; }
    __syncthreads();
    const float mean = (red[0] + red[2]) * (1.0f / HD);
    const float var  = (red[1] + red[3]) * (1.0f / HD) - mean * mean;
    const float rstd = rsqrtf(var + 1e-5f);
    const float y = (xv - mean) * rstd * ln1_g[t] + ln1_b[t];
    sy[t] = y;
    __syncthreads();

    const int h = t >> 5, k = t & 31;
    const float* syh = sy + h * HH;
    const float* kw = k_w + (size_t)(h * HH + k) * HH;
    const float* qw = q_w + (size_t)(h * HH + k) * HH;
    const float* vw = v_w + (size_t)(h * HH + k) * HH;
    float ak = 0.f, aq = 0.f, av = 0.f;
    #pragma unroll
    for (int d = 0; d < HH; ++d) {
        const float yv = syh[d];
        ak = fmaf(yv, kw[d], ak);
        aq = fmaf(yv, qw[d], aq);
        av = fmaf(yv, vw[d], av);
    }
    h_k[(size_t)n * HD + t] = ak;
    h_q[(size_t)n * HD + t] = aq;
    h_v[(size_t)n * HD + t] = av;
}

// ---------------- CSR build ----------------
__global__ __launch_bounds__(256) void k_deg(
    const int* __restrict__ edge_index, int* __restrict__ deg)
{
    for (int e = blockIdx.x * blockDim.x + threadIdx.x; e < EE;
         e += gridDim.x * blockDim.x)
        atomicAdd(&deg[edge_index[e]], 1);
}

__global__ __launch_bounds__(SCAN_B) void k_scan_block(
    const int* __restrict__ deg, int* __restrict__ base, int* __restrict__ bsum)
{
    const int i = blockIdx.x * SCAN_B + threadIdx.x;
    const int v = (i < NN) ? deg[i] : 0;
    __shared__ int s[SCAN_B];
    s[threadIdx.x] = v;
    __syncthreads();
    for (int off = 1; off < SCAN_B; off <<= 1) {
        int t = (threadIdx.x >= off) ? s[threadIdx.x - off] : 0;
        __syncthreads();
        s[threadIdx.x] += t;
        __syncthreads();
    }
    if (i < NN) base[i] = s[threadIdx.x] - v;   // exclusive
    if (threadIdx.x == SCAN_B - 1) bsum[blockIdx.x] = s[SCAN_B - 1];
}

__global__ __launch_bounds__(SCAN_B) void k_scan_top(int* __restrict__ bsum)
{
    const int i = threadIdx.x;
    const int v = (i < NBLK) ? bsum[i] : 0;
    __shared__ int s[SCAN_B];
    s[i] = v;
    __syncthreads();
    for (int off = 1; off < SCAN_B; off <<= 1) {
        int t = (i >= off) ? s[i - off] : 0;
        __syncthreads();
        s[i] += t;
        __syncthreads();
    }
    if (i < NBLK) bsum[i] = s[i] - v;   // exclusive, in place
}

__global__ __launch_bounds__(SCAN_B) void k_scan_add(
    int* __restrict__ base, const int* __restrict__ bsum, int* __restrict__ cursor)
{
    const int i = blockIdx.x * SCAN_B + threadIdx.x;
    if (i < NN) {
        const int b = base[i] + bsum[i >> 8];
        base[i] = b;
        cursor[i] = b;
    }
}

__global__ __launch_bounds__(256) void k_scatter(
    const int* __restrict__ edge_index, int* __restrict__ cursor,
    int* __restrict__ eidx)
{
    for (int e = blockIdx.x * blockDim.x + threadIdx.x; e < EE;
         e += gridDim.x * blockDim.x) {
        const int pos = atomicAdd(&cursor[edge_index[e]], 1);
        eidx[pos] = e;
    }
}

// ---------------- K2: fused edge kernel (qk + msg, no atomics) ----------------
__global__ __launch_bounds__(256) void k_edge_all(
    const float* __restrict__ edge_attr, const int* __restrict__ edge_index,
    const float* __restrict__ h_k, const float* __restrict__ h_q,
    const float* __restrict__ h_v,
    const float* __restrict__ wk1_w, const float* __restrict__ wk1_b,
    const float* __restrict__ wk2_w, const float* __restrict__ wk2_b,
    const float* __restrict__ wkl_w, const float* __restrict__ wkl_b,
    const float* __restrict__ wv1_w, const float* __restrict__ wv1_b,
    const float* __restrict__ wv2_w, const float* __restrict__ wv2_b,
    const float* __restrict__ wvl_w, const float* __restrict__ wvl_b,
    float* __restrict__ qk_out, __hip_bfloat16* __restrict__ msg_out)
{
    const int g = threadIdx.x >> 5;
    const int l = threadIdx.x & 31;
    const int e = blockIdx.x * EPB + g;
    __shared__ float sEA[EPB][ECD];
    __shared__ float sT[EPB][HH];
    __shared__ float sZ[EPB][NHD][HH];

    const float* ea = edge_attr + (size_t)e * ECD;
    sEA[g][l] = ea[l];
    sEA[g][l + 32] = ea[l + 32];
    const int row = edge_index[e];
    const int col = edge_index[EE + e];

    // prefetch all gathers up front
    const float* hkp = h_k + (size_t)col * HD;
    const float* hqp = h_q + (size_t)row * HD;
    const float* hvp = h_v + (size_t)col * HD;
    const float hk0 = hkp[l], hk1 = hkp[32 + l], hk2 = hkp[64 + l], hk3 = hkp[96 + l];
    const float hq0 = hqp[l], hq1 = hqp[32 + l], hq2 = hqp[64 + l], hq3 = hqp[96 + l];
    const float hv0 = hvp[l], hv1 = hvp[32 + l], hv2 = hvp[64 + l], hv3 = hvp[96 + l];
    __syncthreads();   // S1: sEA ready

    // ---- K path ----
    float a = wk1_b[l];
    const float* w1 = wk1_w + (size_t)l * ECD;
    #pragma unroll
    for (int c = 0; c < ECD; ++c) a = fmaf(sEA[g][c], w1[c], a);
    sT[g][l] = ssp_f(a);
    __syncthreads();   // S2: sT ready

    float wk = wk2_b[l];
    const float* w2 = wk2_w + (size_t)l * HH;
    #pragma unroll
    for (int c = 0; c < HH; ++c) wk = fmaf(sT[g][c], w2[c], wk);
    sZ[g][0][l] = wk * hk0;
    sZ[g][1][l] = wk * hk1;
    sZ[g][2][l] = wk * hk2;
    sZ[g][3][l] = wk * hk3;
    __syncthreads();   // S3: sZ ready

    const float* wl = wkl_w + (size_t)l * HH;
    const float klb = wkl_b[l];
    float p0 = 0.f, p1 = 0.f, p2 = 0.f, p3 = 0.f;
    {
        float k0 = klb, k1 = klb, k2 = klb, k3 = klb;
        #pragma unroll
        for (int c = 0; c < HH; ++c) {
            const float w = wl[c];
            k0 = fmaf(sZ[g][0][c], w, k0);
            k1 = fmaf(sZ[g][1][c], w, k1);
            k2 = fmaf(sZ[g][2][c], w, k2);
            k3 = fmaf(sZ[g][3][c], w, k3);
        }
        p0 = k0 * hq0; p1 = k1 * hq1; p2 = k2 * hq2; p3 = k3 * hq3;
    }
    #pragma unroll
    for (int off = 16; off; off >>= 1) {
        p0 += __shfl_xor(p0, off, 32);
        p1 += __shfl_xor(p1, off, 32);
        p2 += __shfl_xor(p2, off, 32);
        p3 += __shfl_xor(p3, off, 32);
    }
    if (l < 4) {
        const float pv = (l == 0) ? p0 : (l == 1) ? p1 : (l == 2) ? p2 : p3;
        qk_out[(size_t)e * NHD + l] = pv;
    }

    // ---- V path (reuses sT, sZ) ----
    float a2 = wv1_b[l];
    const float* v1 = wv1_w + (size_t)l * ECD;
    #pragma unroll
    for (int c = 0; c < ECD; ++c) a2 = fmaf(sEA[g][c], v1[c], a2);
    __syncthreads();   // S4: everyone done reading sT (K path) and sZ (keys)
    sT[g][l] = ssp_f(a2);
    __syncthreads();   // S5: sT ready

    float wv = wv2_b[l];
    const float* v2 = wv2_w + (size_t)l * HH;
    #pragma unroll
    for (int c = 0; c < HH; ++c) wv = fmaf(sT[g][c], v2[c], wv);
    sZ[g][0][l] = wv * hv0;
    sZ[g][1][l] = wv * hv1;
    sZ[g][2][l] = wv * hv2;
    sZ[g][3][l] = wv * hv3;
    __syncthreads();   // S6: sZ ready

    const float* vl = wvl_w + (size_t)l * HH;
    const float vlb = wvl_b[l];
    __hip_bfloat16* mo = msg_out + (size_t)e * HD;
    float m0 = vlb, m1 = vlb, m2 = vlb, m3 = vlb;
    #pragma unroll
    for (int c = 0; c < HH; ++c) {
        const float w = vl[c];
        m0 = fmaf(sZ[g][0][c], w, m0);
        m1 = fmaf(sZ[g][1][c], w, m1);
        m2 = fmaf(sZ[g][2][c], w, m2);
        m3 = fmaf(sZ[g][3][c], w, m3);
    }
    mo[l]      = __float2bfloat16(m0);
    mo[32 + l] = __float2bfloat16(m1);
    mo[64 + l] = __float2bfloat16(m2);
    mo[96 + l] = __float2bfloat16(m3);
}

// ---------------- K3: per-node softmax + aggregate + LN2 + out ----------------
__global__ __launch_bounds__(128) void k_node_fin(
    const float* __restrict__ x, const float* __restrict__ qk,
    const __hip_bfloat16* __restrict__ msg, const int* __restrict__ eidx,
    const int* __restrict__ base, const int* __restrict__ deg,
    const float* __restrict__ out_w, const float* __restrict__ out_b,
    const float* __restrict__ ln2_g, const float* __restrict__ ln2_b,
    float* __restrict__ out)
{
    const int n = blockIdx.x;
    const int t = threadIdx.x;
    const int b0 = base[n];
    const int dn = deg[n];
    __shared__ float sred[128];
    __shared__ float sS[HD];
    __shared__ float red[4];

    // phase A: per-head max over this node's edges. t = j*4 + h
    {
        const int h = t & 3, j = t >> 2;
        float m = -3.0e38f;
        for (int i = j; i < dn; i += 32)
            m = fmaxf(m, qk[(size_t)eidx[b0 + i] * NHD + h]);
        sred[t] = m;
    }
    __syncthreads();
    #pragma unroll
    for (int s = 64; s >= 4; s >>= 1) {
        if (t < s) sred[t] = fmaxf(sred[t], sred[t + s]);
        __syncthreads();
    }
    const int hB = t >> 5;
    const float mh = sred[hB];
    __syncthreads();

    // phase B: weighted sum (each thread owns output element t)
    float acc = 0.f, den = 0.f;
    for (int i = 0; i < dn; ++i) {
        const int e = eidx[b0 + i];
        const float w = __expf(qk[(size_t)e * NHD + hB] - mh);
        den += w;
        acc = fmaf(w, __bfloat162float(msg[(size_t)e * HD + t]), acc);
    }
    const float x2 = ((den > 0.f) ? acc / den : 0.f) + x[(size_t)n * HD + t];

    // LN2 + ssp + out matmul + residual
    float s1 = x2, s2 = x2 * x2;
    #pragma unroll
    for (int off = 32; off; off >>= 1) {
        s1 += __shfl_down(s1, off);
        s2 += __shfl_down(s2, off);
    }
    const int wid = t >> 6;
    if ((t & 63) == 0) { red[wid * 2] = s1; red[wid * 2 + 1] = s2; }
    __syncthreads();
    const float mean = (red[0] + red[2]) * (1.0f / HD);
    const float var  = (red[1] + red[3]) * (1.0f / HD) - mean * mean;
    const float rstd = rsqrtf(var + 1e-5f);
    const float y2 = (x2 - mean) * rstd * ln2_g[t] + ln2_b[t];
    sS[t] = ssp_f(y2);
    __syncthreads();

    float accum = out_b[t] + x2;
    const float* wrow = out_w + (size_t)t * HD;
    #pragma unroll 8
    for (int d = 0; d < HD; ++d) accum = fmaf(sS[d], wrow[d], accum);
    out[(size_t)n * HD + t] = accum;
}

extern "C" void kernel_launch(void* const* d_in, const int* in_sizes, int n_in,
                              void* d_out, int out_size, void* d_ws, size_t ws_size,
                              hipStream_t stream) {
    const float* x         = (const float*)d_in[0];
    const float* edge_attr = (const float*)d_in[1];
    const int*   edge_index= (const int*)  d_in[2];
    const float* k_w   = (const float*)d_in[3];
    const float* q_w   = (const float*)d_in[4];
    const float* v_w   = (const float*)d_in[5];
    const float* wk1_w = (const float*)d_in[6];
    const float* wk1_b = (const float*)d_in[7];
    const float* wk2_w = (const float*)d_in[8];
    const float* wk2_b = (const float*)d_in[9];
    const float* wkl_w = (const float*)d_in[10];
    const float* wkl_b = (const float*)d_in[11];
    const float* wv1_w = (const float*)d_in[12];
    const float* wv1_b = (const float*)d_in[13];
    const float* wv2_w = (const float*)d_in[14];
    const float* wv2_b = (const float*)d_in[15];
    const float* wvl_w = (const float*)d_in[16];
    const float* wvl_b = (const float*)d_in[17];
    const float* out_w = (const float*)d_in[18];
    const float* out_b = (const float*)d_in[19];
    const float* ln1_g = (const float*)d_in[20];
    const float* ln1_b = (const float*)d_in[21];
    const float* ln2_g = (const float*)d_in[22];
    const float* ln2_b = (const float*)d_in[23];

    char* ws = (char*)d_ws;
    float* h_k = (float*)ws;                              ws += (size_t)NN * HD * 4;
    float* h_q = (float*)ws;                              ws += (size_t)NN * HD * 4;
    float* h_v = (float*)ws;                              ws += (size_t)NN * HD * 4;
    float* qk  = (float*)ws;                              ws += (size_t)EE * NHD * 4;
    __hip_bfloat16* msg = (__hip_bfloat16*)ws;            ws += (size_t)EE * HD * 2;
    int* deg    = (int*)ws;                               ws += (size_t)NN * 4;
    int* base   = (int*)ws;                               ws += (size_t)NN * 4;
    int* cursor = (int*)ws;                               ws += (size_t)NN * 4;
    int* bsum   = (int*)ws;                               ws += (size_t)SCAN_B * 4;
    int* eidx   = (int*)ws;                               ws += (size_t)EE * 4;

    (void)hipMemsetAsync(deg, 0, (size_t)NN * 4, stream);

    k_node_prep<<<NN, 128, 0, stream>>>(x, k_w, q_w, v_w, ln1_g, ln1_b, h_k, h_q, h_v);
    k_deg<<<1024, 256, 0, stream>>>(edge_index, deg);
    k_scan_block<<<NBLK, SCAN_B, 0, stream>>>(deg, base, bsum);
    k_scan_top<<<1, SCAN_B, 0, stream>>>(bsum);
    k_scan_add<<<NBLK, SCAN_B, 0, stream>>>(base, bsum, cursor);
    k_scatter<<<1024, 256, 0, stream>>>(edge_index, cursor, eidx);
    k_edge_all<<<EE / EPB, 256, 0, stream>>>(edge_attr, edge_index, h_k, h_q, h_v,
        wk1_w, wk1_b, wk2_w, wk2_b, wkl_w, wkl_b,
        wv1_w, wv1_b, wv2_w, wv2_b, wvl_w, wvl_b, qk, msg);
    k_node_fin<<<NN, 128, 0, stream>>>(x, qk, msg, eidx, base, deg,
        out_w, out_b, ln2_g, ln2_b, (float*)d_out);
}

// Round 4
// 1840.822 us; speedup vs baseline: 1.6984x; 1.6984x over previous
//
#include <hip/hip_runtime.h>
#include <math.h>

#define NN 50000
#define EE 640000
#define HD 128
#define ECD 64
#define NHD 4
#define HH 32
#define SCAN_B 256
#define NBLK ((NN + SCAN_B - 1) / SCAN_B)   // 196

__device__ __forceinline__ float ssp_f(float v) {
    return fmaxf(v, 0.0f) + log1pf(__expf(-fabsf(v))) - 0.69314718055994531f;
}
__device__ __forceinline__ unsigned short f2bf(float f) {
    unsigned u = __float_as_uint(f);
    unsigned r = ((u >> 16) & 1u) + 0x7FFFu;
    return (unsigned short)((u + r) >> 16);
}
__device__ __forceinline__ float bf2f(unsigned short s) {
    return __uint_as_float(((unsigned)s) << 16);
}

// ---------------- K1: LN1 + projections + g/c0 precompute ----------------
__global__ __launch_bounds__(128) void k_node_prep(
    const float* __restrict__ x, const float* __restrict__ k_w,
    const float* __restrict__ q_w, const float* __restrict__ v_w,
    const float* __restrict__ wkl_w, const float* __restrict__ wkl_b,
    const float* __restrict__ ln1_g, const float* __restrict__ ln1_b,
    float* __restrict__ h_k, float* __restrict__ h_v,
    float* __restrict__ g_out, float* __restrict__ c0_out)
{
    const int n = blockIdx.x;
    const int t = threadIdx.x;
    __shared__ float sy[HD];
    __shared__ float red[4];

    float xv = x[(size_t)n * HD + t];
    float s1 = xv, s2 = xv * xv;
    #pragma unroll
    for (int off = 32; off; off >>= 1) {
        s1 += __shfl_down(s1, off);
        s2 += __shfl_down(s2, off);
    }
    const int wid = t >> 6;
    if ((t & 63) == 0) { red[wid * 2] = s1; red[wid * 2 + 1] = s2; }
    __syncthreads();
    const float mean = (red[0] + red[2]) * (1.0f / HD);
    const float var  = (red[1] + red[3]) * (1.0f / HD) - mean * mean;
    const float rstd = rsqrtf(var + 1e-5f);
    const float y = (xv - mean) * rstd * ln1_g[t] + ln1_b[t];
    sy[t] = y;
    __syncthreads();

    const int h = t >> 5, k = t & 31;
    const float* syh = sy + h * HH;
    const float* kw = k_w + (size_t)(h * HH + k) * HH;
    const float* qw = q_w + (size_t)(h * HH + k) * HH;
    const float* vw = v_w + (size_t)(h * HH + k) * HH;
    float ak = 0.f, aq = 0.f, av = 0.f;
    #pragma unroll
    for (int d = 0; d < HH; ++d) {
        const float yv = syh[d];
        ak = fmaf(yv, kw[d], ak);
        aq = fmaf(yv, qw[d], aq);
        av = fmaf(yv, vw[d], av);
    }
    h_k[(size_t)n * HD + t] = ak;
    h_v[(size_t)n * HD + t] = av;

    __syncthreads();            // everyone done with sy
    sy[t] = aq;                 // stage h_q in LDS
    __syncthreads();

    // g[n,h,k] = sum_j hq[h,j] * wkl_w[j*32+k]
    float gv = 0.f;
    const float* sq = sy + h * HH;
    #pragma unroll
    for (int j = 0; j < HH; ++j) gv = fmaf(sq[j], wkl_w[j * HH + k], gv);
    g_out[(size_t)n * HD + t] = gv;

    // c0[n,h] = sum_j hq[h,j] * wkl_b[j]
    float p = aq * wkl_b[k];
    #pragma unroll
    for (int off = 16; off; off >>= 1) p += __shfl_xor(p, off, 32);
    if (k == 0) c0_out[n * NHD + h] = p;
}

// ---------------- CSR build ----------------
__global__ __launch_bounds__(256) void k_deg(
    const int* __restrict__ edge_index, int* __restrict__ deg)
{
    for (int e = blockIdx.x * blockDim.x + threadIdx.x; e < EE;
         e += gridDim.x * blockDim.x)
        atomicAdd(&deg[edge_index[e]], 1);
}

__global__ __launch_bounds__(SCAN_B) void k_scan_block(
    const int* __restrict__ deg, int* __restrict__ base, int* __restrict__ bsum)
{
    const int i = blockIdx.x * SCAN_B + threadIdx.x;
    const int v = (i < NN) ? deg[i] : 0;
    __shared__ int s[SCAN_B];
    s[threadIdx.x] = v;
    __syncthreads();
    for (int off = 1; off < SCAN_B; off <<= 1) {
        int t = (threadIdx.x >= off) ? s[threadIdx.x - off] : 0;
        __syncthreads();
        s[threadIdx.x] += t;
        __syncthreads();
    }
    if (i < NN) base[i] = s[threadIdx.x] - v;
    if (threadIdx.x == SCAN_B - 1) bsum[blockIdx.x] = s[SCAN_B - 1];
}

__global__ __launch_bounds__(SCAN_B) void k_scan_top(int* __restrict__ bsum)
{
    const int i = threadIdx.x;
    const int v = (i < NBLK) ? bsum[i] : 0;
    __shared__ int s[SCAN_B];
    s[i] = v;
    __syncthreads();
    for (int off = 1; off < SCAN_B; off <<= 1) {
        int t = (i >= off) ? s[i - off] : 0;
        __syncthreads();
        s[i] += t;
        __syncthreads();
    }
    if (i < NBLK) bsum[i] = s[i] - v;
}

__global__ __launch_bounds__(SCAN_B) void k_scan_add(
    int* __restrict__ base, const int* __restrict__ bsum, int* __restrict__ cursor)
{
    const int i = blockIdx.x * SCAN_B + threadIdx.x;
    if (i < NN) {
        const int b = base[i] + bsum[i >> 8];
        base[i] = b;
        cursor[i] = b;
    }
}

__global__ __launch_bounds__(256) void k_scatter(
    const int* __restrict__ edge_index, int* __restrict__ cursor,
    int* __restrict__ eidx, int* __restrict__ rowv, int* __restrict__ colv)
{
    for (int e = blockIdx.x * blockDim.x + threadIdx.x; e < EE;
         e += gridDim.x * blockDim.x) {
        const int r = edge_index[e];
        const int pos = atomicAdd(&cursor[r], 1);
        eidx[pos] = e;
        rowv[pos] = r;
        colv[pos] = edge_index[EE + e];
    }
}

// ---------------- K2: edge kernel, lane-per-edge, no LDS ----------------
__global__ __launch_bounds__(256) void k_edge_all(
    const float* __restrict__ edge_attr,
    const int* __restrict__ eidx, const int* __restrict__ rowv,
    const int* __restrict__ colv,
    const float* __restrict__ h_k, const float* __restrict__ h_v,
    const float* __restrict__ g_in, const float* __restrict__ c0_in,
    const float* __restrict__ wk1_w, const float* __restrict__ wk1_b,
    const float* __restrict__ wk2_w, const float* __restrict__ wk2_b,
    const float* __restrict__ wv1_w, const float* __restrict__ wv1_b,
    const float* __restrict__ wv2_w, const float* __restrict__ wv2_b,
    float* __restrict__ qkP, unsigned int* __restrict__ mvP)
{
    const int pos = blockIdx.x * 256 + threadIdx.x;
    const int e   = eidx[pos];
    const int row = rowv[pos];
    const int col = colv[pos];
    const float* ea = edge_attr + (size_t)e * ECD;

    float c0v0, c0v1, c0v2, c0v3;
    {
        const float4 cv = *(const float4*)(c0_in + (size_t)row * NHD);
        c0v0 = cv.x; c0v1 = cv.y; c0v2 = cv.z; c0v3 = cv.w;
    }

    float acc[32];

    // ======== K path: MLP1 ========
    #pragma unroll
    for (int k = 0; k < 32; ++k) acc[k] = wk1_b[k];
    #pragma unroll 1
    for (int cc = 0; cc < 4; ++cc) {
        float eav[16];
        #pragma unroll
        for (int c4 = 0; c4 < 4; ++c4) {
            const float4 v = *(const float4*)(ea + cc * 16 + c4 * 4);
            eav[c4 * 4 + 0] = v.x; eav[c4 * 4 + 1] = v.y;
            eav[c4 * 4 + 2] = v.z; eav[c4 * 4 + 3] = v.w;
        }
        const float* w = wk1_w + cc * 16;
        #pragma unroll
        for (int k = 0; k < 32; ++k) {
            #pragma unroll
            for (int c = 0; c < 16; ++c)
                acc[k] = fmaf(eav[c], w[(size_t)k * ECD + c], acc[k]);
        }
    }
    // ssp
    float t1[32];
    #pragma unroll
    for (int k = 0; k < 32; ++k) t1[k] = ssp_f(acc[k]);
    // MLP2 (fully unrolled; acc becomes Wk)
    #pragma unroll
    for (int k = 0; k < 32; ++k) acc[k] = wk2_b[k];
    #pragma unroll
    for (int c = 0; c < 32; ++c) {
        #pragma unroll
        for (int k = 0; k < 32; ++k)
            acc[k] = fmaf(t1[c], wk2_w[(size_t)k * HH + c], acc[k]);
    }

    // qk[h] = c0 + sum_k Wk[k] * h_k[col,h,k] * g[row,h,k]
    #pragma unroll 1
    for (int h = 0; h < NHD; ++h) {
        float hkv[32], gv[32];
        const float* hkp = h_k + (size_t)col * HD + h * HH;
        const float* gp  = g_in + (size_t)row * HD + h * HH;
        #pragma unroll
        for (int q = 0; q < 8; ++q) {
            const float4 a = *(const float4*)(hkp + q * 4);
            const float4 b = *(const float4*)(gp + q * 4);
            hkv[q * 4 + 0] = a.x; hkv[q * 4 + 1] = a.y;
            hkv[q * 4 + 2] = a.z; hkv[q * 4 + 3] = a.w;
            gv[q * 4 + 0] = b.x; gv[q * 4 + 1] = b.y;
            gv[q * 4 + 2] = b.z; gv[q * 4 + 3] = b.w;
        }
        float s0 = 0.f, s1 = 0.f, s2 = 0.f, s3 = 0.f;
        #pragma unroll
        for (int k = 0; k < 32; k += 4) {
            s0 = fmaf(acc[k + 0] * hkv[k + 0], gv[k + 0], s0);
            s1 = fmaf(acc[k + 1] * hkv[k + 1], gv[k + 1], s1);
            s2 = fmaf(acc[k + 2] * hkv[k + 2], gv[k + 2], s2);
            s3 = fmaf(acc[k + 3] * hkv[k + 3], gv[k + 3], s3);
        }
        const float c0h = (h == 0) ? c0v0 : (h == 1) ? c0v1 : (h == 2) ? c0v2 : c0v3;
        qkP[(size_t)h * EE + pos] = (s0 + s1) + (s2 + s3) + c0h;
    }

    // ======== V path: MLP1 ========
    #pragma unroll
    for (int k = 0; k < 32; ++k) acc[k] = wv1_b[k];
    #pragma unroll 1
    for (int cc = 0; cc < 4; ++cc) {
        float eav[16];
        #pragma unroll
        for (int c4 = 0; c4 < 4; ++c4) {
            const float4 v = *(const float4*)(ea + cc * 16 + c4 * 4);
            eav[c4 * 4 + 0] = v.x; eav[c4 * 4 + 1] = v.y;
            eav[c4 * 4 + 2] = v.z; eav[c4 * 4 + 3] = v.w;
        }
        const float* w = wv1_w + cc * 16;
        #pragma unroll
        for (int k = 0; k < 32; ++k) {
            #pragma unroll
            for (int c = 0; c < 16; ++c)
                acc[k] = fmaf(eav[c], w[(size_t)k * ECD + c], acc[k]);
        }
    }
    #pragma unroll
    for (int k = 0; k < 32; ++k) t1[k] = ssp_f(acc[k]);
    #pragma unroll
    for (int k = 0; k < 32; ++k) acc[k] = wv2_b[k];
    #pragma unroll
    for (int c = 0; c < 32; ++c) {
        #pragma unroll
        for (int k = 0; k < 32; ++k)
            acc[k] = fmaf(t1[c], wv2_w[(size_t)k * HH + c], acc[k]);
    }

    // mv[h,d] = Wv[d] * h_v[col,h,d]  (bf16 packed)
    #pragma unroll 1
    for (int h = 0; h < NHD; ++h) {
        float hvv[32];
        const float* hvp = h_v + (size_t)col * HD + h * HH;
        #pragma unroll
        for (int q = 0; q < 8; ++q) {
            const float4 a = *(const float4*)(hvp + q * 4);
            hvv[q * 4 + 0] = a.x; hvv[q * 4 + 1] = a.y;
            hvv[q * 4 + 2] = a.z; hvv[q * 4 + 3] = a.w;
        }
        unsigned uu[16];
        #pragma unroll
        for (int d2 = 0; d2 < 16; ++d2) {
            const float m0 = acc[d2 * 2 + 0] * hvv[d2 * 2 + 0];
            const float m1 = acc[d2 * 2 + 1] * hvv[d2 * 2 + 1];
            uu[d2] = (unsigned)f2bf(m0) | ((unsigned)f2bf(m1) << 16);
        }
        unsigned* mb = mvP + (size_t)pos * 64 + h * 16;
        #pragma unroll
        for (int q = 0; q < 4; ++q) {
            uint4 o;
            o.x = uu[q * 4 + 0]; o.y = uu[q * 4 + 1];
            o.z = uu[q * 4 + 2]; o.w = uu[q * 4 + 3];
            *(uint4*)(mb + q * 4) = o;
        }
    }
}

// ---------------- K3: per-node softmax + aggregate + LN2 + out ----------------
__global__ __launch_bounds__(128) void k_node_fin(
    const float* __restrict__ x, const float* __restrict__ qkP,
    const unsigned short* __restrict__ mv,
    const int* __restrict__ base, const int* __restrict__ deg,
    const float* __restrict__ wvl_w, const float* __restrict__ wvl_b,
    const float* __restrict__ out_w, const float* __restrict__ out_b,
    const float* __restrict__ ln2_g, const float* __restrict__ ln2_b,
    float* __restrict__ out)
{
    const int n = blockIdx.x;
    const int t = threadIdx.x;
    const int h = t >> 5, j = t & 31;
    const int b0 = base[n];
    const int dn = deg[n];
    __shared__ float su[HD];
    __shared__ float sS[HD];
    __shared__ float red[4];

    const float* qkh = qkP + (size_t)h * EE + b0;

    // per-head max (32 lanes per head, strided)
    float mh = -3.0e38f;
    for (int i = j; i < dn; i += 32) mh = fmaxf(mh, qkh[i]);
    #pragma unroll
    for (int off = 16; off; off >>= 1) mh = fmaxf(mh, __shfl_xor(mh, off, 32));

    // denominator
    float den = 0.f;
    for (int i = j; i < dn; i += 32) den += __expf(qkh[i] - mh);
    #pragma unroll
    for (int off = 16; off; off >>= 1) den += __shfl_xor(den, off, 32);

    // u[t] = (1/den) * sum_i ex_i * mv[b0+i][t]
    float u = 0.f;
    const unsigned short* mvp = mv + (size_t)b0 * HD + t;
    for (int i = 0; i < dn; ++i)
        u = fmaf(__expf(qkh[i] - mh), bf2f(mvp[(size_t)i * HD]), u);
    u = (dn > 0 && den > 0.f) ? u / den : 0.f;
    su[t] = u;
    __syncthreads();

    // aggr[j] = wvl_b[j] + sum_d wvl_w[j][d] * u[h][d]   (0 if no edges)
    float ag = 0.f;
    if (dn > 0) {
        ag = wvl_b[j];
        const float* wr = wvl_w + (size_t)j * HH;
        const float* uh = su + h * HH;
        #pragma unroll
        for (int d = 0; d < HH; ++d) ag = fmaf(uh[d], wr[d], ag);
    }

    const float x2 = ag + x[(size_t)n * HD + t];

    // LN2 + ssp + out matmul + residual
    float s1 = x2, s2 = x2 * x2;
    #pragma unroll
    for (int off = 32; off; off >>= 1) {
        s1 += __shfl_down(s1, off);
        s2 += __shfl_down(s2, off);
    }
    const int wid = t >> 6;
    if ((t & 63) == 0) { red[wid * 2] = s1; red[wid * 2 + 1] = s2; }
    __syncthreads();
    const float mean = (red[0] + red[2]) * (1.0f / HD);
    const float var  = (red[1] + red[3]) * (1.0f / HD) - mean * mean;
    const float rstd = rsqrtf(var + 1e-5f);
    const float y2 = (x2 - mean) * rstd * ln2_g[t] + ln2_b[t];
    sS[t] = ssp_f(y2);
    __syncthreads();

    float accum = out_b[t] + x2;
    const float* wrow = out_w + (size_t)t * HD;
    #pragma unroll 8
    for (int d = 0; d < HD; ++d) accum = fmaf(sS[d], wrow[d], accum);
    out[(size_t)n * HD + t] = accum;
}

extern "C" void kernel_launch(void* const* d_in, const int* in_sizes, int n_in,
                              void* d_out, int out_size, void* d_ws, size_t ws_size,
                              hipStream_t stream) {
    const float* x         = (const float*)d_in[0];
    const float* edge_attr = (const float*)d_in[1];
    const int*   edge_index= (const int*)  d_in[2];
    const float* k_w   = (const float*)d_in[3];
    const float* q_w   = (const float*)d_in[4];
    const float* v_w   = (const float*)d_in[5];
    const float* wk1_w = (const float*)d_in[6];
    const float* wk1_b = (const float*)d_in[7];
    const float* wk2_w = (const float*)d_in[8];
    const float* wk2_b = (const float*)d_in[9];
    const float* wkl_w = (const float*)d_in[10];
    const float* wkl_b = (const float*)d_in[11];
    const float* wv1_w = (const float*)d_in[12];
    const float* wv1_b = (const float*)d_in[13];
    const float* wv2_w = (const float*)d_in[14];
    const float* wv2_b = (const float*)d_in[15];
    const float* wvl_w = (const float*)d_in[16];
    const float* wvl_b = (const float*)d_in[17];
    const float* out_w = (const float*)d_in[18];
    const float* out_b = (const float*)d_in[19];
    const float* ln1_g = (const float*)d_in[20];
    const float* ln1_b = (const float*)d_in[21];
    const float* ln2_g = (const float*)d_in[22];
    const float* ln2_b = (const float*)d_in[23];

    char* ws = (char*)d_ws;
    float* h_k = (float*)ws;                    ws += (size_t)NN * HD * 4;
    float* h_v = (float*)ws;                    ws += (size_t)NN * HD * 4;
    float* g   = (float*)ws;                    ws += (size_t)NN * HD * 4;
    float* c0  = (float*)ws;                    ws += (size_t)NN * NHD * 4;
    float* qkP = (float*)ws;                    ws += (size_t)NHD * EE * 4;
    unsigned* mvP = (unsigned*)ws;              ws += (size_t)EE * HD * 2;
    int* deg    = (int*)ws;                     ws += (size_t)NN * 4;
    int* base   = (int*)ws;                     ws += (size_t)NN * 4;
    int* cursor = (int*)ws;                     ws += (size_t)NN * 4;
    int* bsum   = (int*)ws;                     ws += (size_t)SCAN_B * 4;
    int* eidx   = (int*)ws;                     ws += (size_t)EE * 4;
    int* rowv   = (int*)ws;                     ws += (size_t)EE * 4;
    int* colv   = (int*)ws;                     ws += (size_t)EE * 4;

    (void)hipMemsetAsync(deg, 0, (size_t)NN * 4, stream);

    k_node_prep<<<NN, 128, 0, stream>>>(x, k_w, q_w, v_w, wkl_w, wkl_b,
        ln1_g, ln1_b, h_k, h_v, g, c0);
    k_deg<<<1024, 256, 0, stream>>>(edge_index, deg);
    k_scan_block<<<NBLK, SCAN_B, 0, stream>>>(deg, base, bsum);
    k_scan_top<<<1, SCAN_B, 0, stream>>>(bsum);
    k_scan_add<<<NBLK, SCAN_B, 0, stream>>>(base, bsum, cursor);
    k_scatter<<<1024, 256, 0, stream>>>(edge_index, cursor, eidx, rowv, colv);
    k_edge_all<<<EE / 256, 256, 0, stream>>>(edge_attr, eidx, rowv, colv,
        h_k, h_v, g, c0,
        wk1_w, wk1_b, wk2_w, wk2_b, wv1_w, wv1_b, wv2_w, wv2_b, qkP, mvP);
    k_node_fin<<<NN, 128, 0, stream>>>(x, qkP, (const unsigned short*)mvP,
        base, deg, wvl_w, wvl_b, out_w, out_b, ln2_g, ln2_b, (float*)d_out);
}

// Round 5
// 1475.224 us; speedup vs baseline: 2.1193x; 1.2478x over previous
//
#include <hip/hip_runtime.h>
#include <math.h>

#define NN 50000
#define EE 640000
#define HD 128
#define ECD 64
#define NHD 4
#define HH 32
#define SCAN_B 256
#define NBLK ((NN + SCAN_B - 1) / SCAN_B)   // 196

__device__ __forceinline__ float ssp_f(float v) {
    return fmaxf(v, 0.0f) + log1pf(__expf(-fabsf(v))) - 0.69314718055994531f;
}
__device__ __forceinline__ unsigned f2bf_u(float f) {
    unsigned u = __float_as_uint(f);
    unsigned r = ((u >> 16) & 1u) + 0x7FFFu;
    return (u + r) >> 16;
}
__device__ __forceinline__ unsigned pk2(float a, float b) {
    return f2bf_u(a) | (f2bf_u(b) << 16);
}
__device__ __forceinline__ void unp2(unsigned u, float& a, float& b) {
    a = __uint_as_float(u << 16);
    b = __uint_as_float(u & 0xffff0000u);
}
__device__ __forceinline__ float bf2f(unsigned short s) {
    return __uint_as_float(((unsigned)s) << 16);
}

// ---------------- K1: LN1 + projections + g/c0 precompute (bf16 packed out) ----
__global__ __launch_bounds__(128) void k_node_prep(
    const float* __restrict__ x, const float* __restrict__ k_w,
    const float* __restrict__ q_w, const float* __restrict__ v_w,
    const float* __restrict__ wkl_w, const float* __restrict__ wkl_b,
    const float* __restrict__ ln1_g, const float* __restrict__ ln1_b,
    unsigned* __restrict__ hk_bf, unsigned* __restrict__ hv_bf,
    unsigned* __restrict__ g_bf, float* __restrict__ c0_out)
{
    const int n = blockIdx.x;
    const int t = threadIdx.x;
    __shared__ float sy[HD];
    __shared__ float sk[HD], sv[HD], sg[HD];
    __shared__ float red[4];

    float xv = x[(size_t)n * HD + t];
    float s1 = xv, s2 = xv * xv;
    #pragma unroll
    for (int off = 32; off; off >>= 1) {
        s1 += __shfl_down(s1, off);
        s2 += __shfl_down(s2, off);
    }
    const int wid = t >> 6;
    if ((t & 63) == 0) { red[wid * 2] = s1; red[wid * 2 + 1] = s2; }
    __syncthreads();
    const float mean = (red[0] + red[2]) * (1.0f / HD);
    const float var  = (red[1] + red[3]) * (1.0f / HD) - mean * mean;
    const float rstd = rsqrtf(var + 1e-5f);
    const float y = (xv - mean) * rstd * ln1_g[t] + ln1_b[t];
    sy[t] = y;
    __syncthreads();

    const int h = t >> 5, k = t & 31;
    const float* syh = sy + h * HH;
    const float* kw = k_w + (size_t)(h * HH + k) * HH;
    const float* qw = q_w + (size_t)(h * HH + k) * HH;
    const float* vw = v_w + (size_t)(h * HH + k) * HH;
    float ak = 0.f, aq = 0.f, av = 0.f;
    #pragma unroll
    for (int d = 0; d < HH; ++d) {
        const float yv = syh[d];
        ak = fmaf(yv, kw[d], ak);
        aq = fmaf(yv, qw[d], aq);
        av = fmaf(yv, vw[d], av);
    }
    sk[t] = ak;
    sv[t] = av;

    __syncthreads();            // everyone done with sy
    sy[t] = aq;                 // stage h_q in LDS
    __syncthreads();

    // g[n,h,k] = sum_j hq[h,j] * wkl_w[j*32+k]
    float gv = 0.f;
    const float* sq = sy + h * HH;
    #pragma unroll
    for (int j = 0; j < HH; ++j) gv = fmaf(sq[j], wkl_w[j * HH + k], gv);
    sg[t] = gv;

    // c0[n,h] = sum_j hq[h,j] * wkl_b[j]
    float p = aq * wkl_b[k];
    #pragma unroll
    for (int off = 16; off; off >>= 1) p += __shfl_xor(p, off, 32);
    if (k == 0) c0_out[n * NHD + h] = p;

    __syncthreads();
    if (t < 64) {
        hk_bf[(size_t)n * 64 + t] = pk2(sk[2 * t], sk[2 * t + 1]);
        hv_bf[(size_t)n * 64 + t] = pk2(sv[2 * t], sv[2 * t + 1]);
        g_bf [(size_t)n * 64 + t] = pk2(sg[2 * t], sg[2 * t + 1]);
    }
}

// ---------------- CSR build ----------------
__global__ __launch_bounds__(256) void k_deg(
    const int* __restrict__ edge_index, int* __restrict__ deg)
{
    for (int e = blockIdx.x * blockDim.x + threadIdx.x; e < EE;
         e += gridDim.x * blockDim.x)
        atomicAdd(&deg[edge_index[e]], 1);
}

__global__ __launch_bounds__(SCAN_B) void k_scan_block(
    const int* __restrict__ deg, int* __restrict__ base, int* __restrict__ bsum)
{
    const int i = blockIdx.x * SCAN_B + threadIdx.x;
    const int v = (i < NN) ? deg[i] : 0;
    __shared__ int s[SCAN_B];
    s[threadIdx.x] = v;
    __syncthreads();
    for (int off = 1; off < SCAN_B; off <<= 1) {
        int t = (threadIdx.x >= off) ? s[threadIdx.x - off] : 0;
        __syncthreads();
        s[threadIdx.x] += t;
        __syncthreads();
    }
    if (i < NN) base[i] = s[threadIdx.x] - v;
    if (threadIdx.x == SCAN_B - 1) bsum[blockIdx.x] = s[SCAN_B - 1];
}

__global__ __launch_bounds__(SCAN_B) void k_scan_top(int* __restrict__ bsum)
{
    const int i = threadIdx.x;
    const int v = (i < NBLK) ? bsum[i] : 0;
    __shared__ int s[SCAN_B];
    s[i] = v;
    __syncthreads();
    for (int off = 1; off < SCAN_B; off <<= 1) {
        int t = (i >= off) ? s[i - off] : 0;
        __syncthreads();
        s[i] += t;
        __syncthreads();
    }
    if (i < NBLK) bsum[i] = s[i] - v;
}

__global__ __launch_bounds__(SCAN_B) void k_scan_add(
    int* __restrict__ base, const int* __restrict__ bsum, int* __restrict__ cursor)
{
    const int i = blockIdx.x * SCAN_B + threadIdx.x;
    if (i < NN) {
        const int b = base[i] + bsum[i >> 8];
        base[i] = b;
        cursor[i] = b;
    }
}

__global__ __launch_bounds__(256) void k_scatter(
    const int* __restrict__ edge_index, int* __restrict__ cursor,
    int* __restrict__ eidx, int* __restrict__ rowv, int* __restrict__ colv)
{
    for (int e = blockIdx.x * blockDim.x + threadIdx.x; e < EE;
         e += gridDim.x * blockDim.x) {
        const int r = edge_index[e];
        const int pos = atomicAdd(&cursor[r], 1);
        eidx[pos] = e;
        rowv[pos] = r;
        colv[pos] = edge_index[EE + e];
    }
}

// ---------------- ea -> bf16, permuted to CSR order ----------------
// 32 threads per edge; each packs 2 floats -> 1 uint. Coalesced read+write.
__global__ __launch_bounds__(256) void k_ea_csr(
    const float* __restrict__ ea, const int* __restrict__ eidx,
    unsigned* __restrict__ ea_bf)
{
    const int i = blockIdx.x * 256 + threadIdx.x;
    const int pos = i >> 5, u = i & 31;
    const int e = eidx[pos];
    const float2 v = *(const float2*)(ea + (size_t)e * ECD + u * 2);
    ea_bf[(size_t)pos * 32 + u] = pk2(v.x, v.y);
}

// ---------------- K2: edge kernel, lane-per-edge, all bf16 inputs ----------
__global__ __launch_bounds__(256) void k_edge_all(
    const unsigned* __restrict__ ea_bf,
    const int* __restrict__ rowv, const int* __restrict__ colv,
    const unsigned* __restrict__ hk_bf, const unsigned* __restrict__ hv_bf,
    const unsigned* __restrict__ g_bf, const float* __restrict__ c0_in,
    const float* __restrict__ wk1_w, const float* __restrict__ wk1_b,
    const float* __restrict__ wk2_w, const float* __restrict__ wk2_b,
    const float* __restrict__ wv1_w, const float* __restrict__ wv1_b,
    const float* __restrict__ wv2_w, const float* __restrict__ wv2_b,
    float* __restrict__ qkP, unsigned* __restrict__ mvP)
{
    const int pos = blockIdx.x * 256 + threadIdx.x;
    const int row = rowv[pos];
    const int col = colv[pos];
    const uint4* eap = (const uint4*)(ea_bf + (size_t)pos * 32);
    const uint4* hkp = (const uint4*)(hk_bf + (size_t)col * 64);
    const uint4* gp  = (const uint4*)(g_bf  + (size_t)row * 64);
    const uint4* hvp = (const uint4*)(hv_bf + (size_t)col * 64);
    const float4 c0v = *(const float4*)(c0_in + (size_t)row * NHD);

    float acc[32], t1[32];

    // ======== K path: MLP1 ========
    #pragma unroll
    for (int k = 0; k < 32; ++k) acc[k] = wk1_b[k];
    #pragma unroll
    for (int cc = 0; cc < 8; ++cc) {
        const uint4 u = eap[cc];
        float f[8];
        unp2(u.x, f[0], f[1]); unp2(u.y, f[2], f[3]);
        unp2(u.z, f[4], f[5]); unp2(u.w, f[6], f[7]);
        const float* w = wk1_w + cc * 8;
        #pragma unroll
        for (int k = 0; k < 32; ++k) {
            #pragma unroll
            for (int c = 0; c < 8; ++c)
                acc[k] = fmaf(f[c], w[(size_t)k * ECD + c], acc[k]);
        }
    }
    #pragma unroll
    for (int k = 0; k < 32; ++k) t1[k] = ssp_f(acc[k]);
    #pragma unroll
    for (int k = 0; k < 32; ++k) acc[k] = wk2_b[k];
    #pragma unroll
    for (int c = 0; c < 32; ++c) {
        #pragma unroll
        for (int k = 0; k < 32; ++k)
            acc[k] = fmaf(t1[c], wk2_w[(size_t)k * HH + c], acc[k]);
    }

    // qk[h] = c0[h] + sum_k Wk[k] * hk[col,h,k] * g[row,h,k]
    #pragma unroll
    for (int h = 0; h < NHD; ++h) {
        float s = 0.f;
        #pragma unroll
        for (int q = 0; q < 4; ++q) {
            const uint4 ku = hkp[h * 4 + q];
            const uint4 gu = gp[h * 4 + q];
            float ka, kb, ga, gb;
            unp2(ku.x, ka, kb); unp2(gu.x, ga, gb);
            s = fmaf(acc[q * 8 + 0] * ka, ga, s);
            s = fmaf(acc[q * 8 + 1] * kb, gb, s);
            unp2(ku.y, ka, kb); unp2(gu.y, ga, gb);
            s = fmaf(acc[q * 8 + 2] * ka, ga, s);
            s = fmaf(acc[q * 8 + 3] * kb, gb, s);
            unp2(ku.z, ka, kb); unp2(gu.z, ga, gb);
            s = fmaf(acc[q * 8 + 4] * ka, ga, s);
            s = fmaf(acc[q * 8 + 5] * kb, gb, s);
            unp2(ku.w, ka, kb); unp2(gu.w, ga, gb);
            s = fmaf(acc[q * 8 + 6] * ka, ga, s);
            s = fmaf(acc[q * 8 + 7] * kb, gb, s);
        }
        const float c0h = (h == 0) ? c0v.x : (h == 1) ? c0v.y : (h == 2) ? c0v.z : c0v.w;
        qkP[(size_t)h * EE + pos] = s + c0h;
    }

    // ======== V path: MLP1 ========
    #pragma unroll
    for (int k = 0; k < 32; ++k) acc[k] = wv1_b[k];
    #pragma unroll
    for (int cc = 0; cc < 8; ++cc) {
        const uint4 u = eap[cc];
        float f[8];
        unp2(u.x, f[0], f[1]); unp2(u.y, f[2], f[3]);
        unp2(u.z, f[4], f[5]); unp2(u.w, f[6], f[7]);
        const float* w = wv1_w + cc * 8;
        #pragma unroll
        for (int k = 0; k < 32; ++k) {
            #pragma unroll
            for (int c = 0; c < 8; ++c)
                acc[k] = fmaf(f[c], w[(size_t)k * ECD + c], acc[k]);
        }
    }
    #pragma unroll
    for (int k = 0; k < 32; ++k) t1[k] = ssp_f(acc[k]);
    #pragma unroll
    for (int k = 0; k < 32; ++k) acc[k] = wv2_b[k];
    #pragma unroll
    for (int c = 0; c < 32; ++c) {
        #pragma unroll
        for (int k = 0; k < 32; ++k)
            acc[k] = fmaf(t1[c], wv2_w[(size_t)k * HH + c], acc[k]);
    }

    // mv[h,d] = Wv[d] * hv[col,h,d]  (bf16 packed, CSR-ordered)
    #pragma unroll
    for (int h = 0; h < NHD; ++h) {
        uint4 o[4];
        #pragma unroll
        for (int q = 0; q < 4; ++q) {
            const uint4 vu = hvp[h * 4 + q];
            float va, vb;
            unsigned r[4];
            unp2(vu.x, va, vb);
            r[0] = pk2(acc[q * 8 + 0] * va, acc[q * 8 + 1] * vb);
            unp2(vu.y, va, vb);
            r[1] = pk2(acc[q * 8 + 2] * va, acc[q * 8 + 3] * vb);
            unp2(vu.z, va, vb);
            r[2] = pk2(acc[q * 8 + 4] * va, acc[q * 8 + 5] * vb);
            unp2(vu.w, va, vb);
            r[3] = pk2(acc[q * 8 + 6] * va, acc[q * 8 + 7] * vb);
            o[q].x = r[0]; o[q].y = r[1]; o[q].z = r[2]; o[q].w = r[3];
        }
        uint4* mb = (uint4*)(mvP + (size_t)pos * 64 + h * 16);
        mb[0] = o[0]; mb[1] = o[1]; mb[2] = o[2]; mb[3] = o[3];
    }
}

// ---------------- K3: per-node softmax + aggregate + LN2 + out ----------------
__global__ __launch_bounds__(128) void k_node_fin(
    const float* __restrict__ x, const float* __restrict__ qkP,
    const unsigned short* __restrict__ mv,
    const int* __restrict__ base, const int* __restrict__ deg,
    const float* __restrict__ wvl_w, const float* __restrict__ wvl_b,
    const float* __restrict__ out_w, const float* __restrict__ out_b,
    const float* __restrict__ ln2_g, const float* __restrict__ ln2_b,
    float* __restrict__ out)
{
    const int n = blockIdx.x;
    const int t = threadIdx.x;
    const int h = t >> 5, j = t & 31;
    const int b0 = base[n];
    const int dn = deg[n];
    __shared__ float su[HD];
    __shared__ float sS[HD];
    __shared__ float red[4];

    const float* qkh = qkP + (size_t)h * EE + b0;

    float mh = -3.0e38f;
    for (int i = j; i < dn; i += 32) mh = fmaxf(mh, qkh[i]);
    #pragma unroll
    for (int off = 16; off; off >>= 1) mh = fmaxf(mh, __shfl_xor(mh, off, 32));

    float den = 0.f;
    for (int i = j; i < dn; i += 32) den += __expf(qkh[i] - mh);
    #pragma unroll
    for (int off = 16; off; off >>= 1) den += __shfl_xor(den, off, 32);

    float u = 0.f;
    const unsigned short* mvp = mv + (size_t)b0 * HD + t;
    for (int i = 0; i < dn; ++i)
        u = fmaf(__expf(qkh[i] - mh), bf2f(mvp[(size_t)i * HD]), u);
    u = (dn > 0 && den > 0.f) ? u / den : 0.f;
    su[t] = u;
    __syncthreads();

    float ag = 0.f;
    if (dn > 0) {
        ag = wvl_b[j];
        const float4* wr = (const float4*)(wvl_w + (size_t)j * HH);
        const float* uh = su + h * HH;
        #pragma unroll
        for (int d4 = 0; d4 < 8; ++d4) {
            const float4 w = wr[d4];
            ag = fmaf(uh[d4 * 4 + 0], w.x, ag);
            ag = fmaf(uh[d4 * 4 + 1], w.y, ag);
            ag = fmaf(uh[d4 * 4 + 2], w.z, ag);
            ag = fmaf(uh[d4 * 4 + 3], w.w, ag);
        }
    }

    const float x2 = ag + x[(size_t)n * HD + t];

    float s1 = x2, s2 = x2 * x2;
    #pragma unroll
    for (int off = 32; off; off >>= 1) {
        s1 += __shfl_down(s1, off);
        s2 += __shfl_down(s2, off);
    }
    const int wid = t >> 6;
    if ((t & 63) == 0) { red[wid * 2] = s1; red[wid * 2 + 1] = s2; }
    __syncthreads();
    const float mean = (red[0] + red[2]) * (1.0f / HD);
    const float var  = (red[1] + red[3]) * (1.0f / HD) - mean * mean;
    const float rstd = rsqrtf(var + 1e-5f);
    const float y2 = (x2 - mean) * rstd * ln2_g[t] + ln2_b[t];
    sS[t] = ssp_f(y2);
    __syncthreads();

    float accum = out_b[t] + x2;
    const float4* wrow = (const float4*)(out_w + (size_t)t * HD);
    #pragma unroll
    for (int d4 = 0; d4 < 32; ++d4) {
        const float4 w = wrow[d4];
        accum = fmaf(sS[d4 * 4 + 0], w.x, accum);
        accum = fmaf(sS[d4 * 4 + 1], w.y, accum);
        accum = fmaf(sS[d4 * 4 + 2], w.z, accum);
        accum = fmaf(sS[d4 * 4 + 3], w.w, accum);
    }
    out[(size_t)n * HD + t] = accum;
}

extern "C" void kernel_launch(void* const* d_in, const int* in_sizes, int n_in,
                              void* d_out, int out_size, void* d_ws, size_t ws_size,
                              hipStream_t stream) {
    const float* x         = (const float*)d_in[0];
    const float* edge_attr = (const float*)d_in[1];
    const int*   edge_index= (const int*)  d_in[2];
    const float* k_w   = (const float*)d_in[3];
    const float* q_w   = (const float*)d_in[4];
    const float* v_w   = (const float*)d_in[5];
    const float* wk1_w = (const float*)d_in[6];
    const float* wk1_b = (const float*)d_in[7];
    const float* wk2_w = (const float*)d_in[8];
    const float* wk2_b = (const float*)d_in[9];
    const float* wkl_w = (const float*)d_in[10];
    const float* wkl_b = (const float*)d_in[11];
    const float* wv1_w = (const float*)d_in[12];
    const float* wv1_b = (const float*)d_in[13];
    const float* wv2_w = (const float*)d_in[14];
    const float* wv2_b = (const float*)d_in[15];
    const float* wvl_w = (const float*)d_in[16];
    const float* wvl_b = (const float*)d_in[17];
    const float* out_w = (const float*)d_in[18];
    const float* out_b = (const float*)d_in[19];
    const float* ln1_g = (const float*)d_in[20];
    const float* ln1_b = (const float*)d_in[21];
    const float* ln2_g = (const float*)d_in[22];
    const float* ln2_b = (const float*)d_in[23];

    char* ws = (char*)d_ws;
    unsigned* hk_bf = (unsigned*)ws;            ws += (size_t)NN * 64 * 4;
    unsigned* hv_bf = (unsigned*)ws;            ws += (size_t)NN * 64 * 4;
    unsigned* g_bf  = (unsigned*)ws;            ws += (size_t)NN * 64 * 4;
    float* c0  = (float*)ws;                    ws += (size_t)NN * NHD * 4;
    float* qkP = (float*)ws;                    ws += (size_t)NHD * EE * 4;
    unsigned* mvP = (unsigned*)ws;              ws += (size_t)EE * 64 * 4;
    unsigned* ea_bf = (unsigned*)ws;            ws += (size_t)EE * 32 * 4;
    int* deg    = (int*)ws;                     ws += (size_t)NN * 4;
    int* base   = (int*)ws;                     ws += (size_t)NN * 4;
    int* cursor = (int*)ws;                     ws += (size_t)NN * 4;
    int* bsum   = (int*)ws;                     ws += (size_t)SCAN_B * 4;
    int* eidx   = (int*)ws;                     ws += (size_t)EE * 4;
    int* rowv   = (int*)ws;                     ws += (size_t)EE * 4;
    int* colv   = (int*)ws;                     ws += (size_t)EE * 4;

    (void)hipMemsetAsync(deg, 0, (size_t)NN * 4, stream);

    k_node_prep<<<NN, 128, 0, stream>>>(x, k_w, q_w, v_w, wkl_w, wkl_b,
        ln1_g, ln1_b, hk_bf, hv_bf, g_bf, c0);
    k_deg<<<1024, 256, 0, stream>>>(edge_index, deg);
    k_scan_block<<<NBLK, SCAN_B, 0, stream>>>(deg, base, bsum);
    k_scan_top<<<1, SCAN_B, 0, stream>>>(bsum);
    k_scan_add<<<NBLK, SCAN_B, 0, stream>>>(base, bsum, cursor);
    k_scatter<<<1024, 256, 0, stream>>>(edge_index, cursor, eidx, rowv, colv);
    k_ea_csr<<<EE * 32 / 256, 256, 0, stream>>>(edge_attr, eidx, ea_bf);
    k_edge_all<<<EE / 256, 256, 0, stream>>>(ea_bf, rowv, colv,
        hk_bf, hv_bf, g_bf, c0,
        wk1_w, wk1_b, wk2_w, wk2_b, wv1_w, wv1_b, wv2_w, wv2_b, qkP, mvP);
    k_node_fin<<<NN, 128, 0, stream>>>(x, qkP, (const unsigned short*)mvP,
        base, deg, wvl_w, wvl_b, out_w, out_b, ln2_g, ln2_b, (float*)d_out);
}

// Round 6
// 1430.010 us; speedup vs baseline: 2.1863x; 1.0316x over previous
//
#include <hip/hip_runtime.h>
#include <math.h>

#define NN 50000
#define EE 640000
#define HD 128
#define ECD 64
#define NHD 4
#define HH 32
#define SCAN_B 256
#define NBLK ((NN + SCAN_B - 1) / SCAN_B)   // 196
#define TILE 64

__device__ __forceinline__ float ssp_f(float v) {
    return fmaxf(v, 0.0f) + log1pf(__expf(-fabsf(v))) - 0.69314718055994531f;
}
__device__ __forceinline__ unsigned f2bf_u(float f) {
    unsigned u = __float_as_uint(f);
    unsigned r = ((u >> 16) & 1u) + 0x7FFFu;
    return (u + r) >> 16;
}
__device__ __forceinline__ unsigned pk2(float a, float b) {
    return f2bf_u(a) | (f2bf_u(b) << 16);
}
__device__ __forceinline__ void unp2(unsigned u, float& a, float& b) {
    a = __uint_as_float(u << 16);
    b = __uint_as_float(u & 0xffff0000u);
}

// ---------------- K1: LN1 + projections + g/c0 precompute (bf16 packed out) ----
__global__ __launch_bounds__(128) void k_node_prep(
    const float* __restrict__ x, const float* __restrict__ k_w,
    const float* __restrict__ q_w, const float* __restrict__ v_w,
    const float* __restrict__ wkl_w, const float* __restrict__ wkl_b,
    const float* __restrict__ ln1_g, const float* __restrict__ ln1_b,
    unsigned* __restrict__ hk_bf, unsigned* __restrict__ hv_bf,
    unsigned* __restrict__ g_bf, float* __restrict__ c0_out)
{
    const int n = blockIdx.x;
    const int t = threadIdx.x;
    __shared__ float sy[HD];
    __shared__ float sk[HD], sv[HD], sg[HD];
    __shared__ float red[4];

    float xv = x[(size_t)n * HD + t];
    float s1 = xv, s2 = xv * xv;
    #pragma unroll
    for (int off = 32; off; off >>= 1) {
        s1 += __shfl_down(s1, off);
        s2 += __shfl_down(s2, off);
    }
    const int wid = t >> 6;
    if ((t & 63) == 0) { red[wid * 2] = s1; red[wid * 2 + 1] = s2; }
    __syncthreads();
    const float mean = (red[0] + red[2]) * (1.0f / HD);
    const float var  = (red[1] + red[3]) * (1.0f / HD) - mean * mean;
    const float rstd = rsqrtf(var + 1e-5f);
    const float y = (xv - mean) * rstd * ln1_g[t] + ln1_b[t];
    sy[t] = y;
    __syncthreads();

    const int h = t >> 5, k = t & 31;
    const float* syh = sy + h * HH;
    const float* kw = k_w + (size_t)(h * HH + k) * HH;
    const float* qw = q_w + (size_t)(h * HH + k) * HH;
    const float* vw = v_w + (size_t)(h * HH + k) * HH;
    float ak = 0.f, aq = 0.f, av = 0.f;
    #pragma unroll
    for (int d = 0; d < HH; ++d) {
        const float yv = syh[d];
        ak = fmaf(yv, kw[d], ak);
        aq = fmaf(yv, qw[d], aq);
        av = fmaf(yv, vw[d], av);
    }
    sk[t] = ak;
    sv[t] = av;

    __syncthreads();            // everyone done with sy
    sy[t] = aq;                 // stage h_q in LDS
    __syncthreads();

    // g[n,h,k] = sum_j hq[h,j] * wkl_w[j*32+k]
    float gv = 0.f;
    const float* sq = sy + h * HH;
    #pragma unroll
    for (int j = 0; j < HH; ++j) gv = fmaf(sq[j], wkl_w[j * HH + k], gv);
    sg[t] = gv;

    // c0[n,h] = sum_j hq[h,j] * wkl_b[j]
    float p = aq * wkl_b[k];
    #pragma unroll
    for (int off = 16; off; off >>= 1) p += __shfl_xor(p, off, 32);
    if (k == 0) c0_out[n * NHD + h] = p;

    __syncthreads();
    if (t < 64) {
        hk_bf[(size_t)n * 64 + t] = pk2(sk[2 * t], sk[2 * t + 1]);
        hv_bf[(size_t)n * 64 + t] = pk2(sv[2 * t], sv[2 * t + 1]);
        g_bf [(size_t)n * 64 + t] = pk2(sg[2 * t], sg[2 * t + 1]);
    }
}

// ---------------- CSR build ----------------
__global__ __launch_bounds__(256) void k_deg(
    const int* __restrict__ edge_index, int* __restrict__ deg)
{
    for (int e = blockIdx.x * blockDim.x + threadIdx.x; e < EE;
         e += gridDim.x * blockDim.x)
        atomicAdd(&deg[edge_index[e]], 1);
}

__global__ __launch_bounds__(SCAN_B) void k_scan_block(
    const int* __restrict__ deg, int* __restrict__ base, int* __restrict__ bsum)
{
    const int i = blockIdx.x * SCAN_B + threadIdx.x;
    const int v = (i < NN) ? deg[i] : 0;
    __shared__ int s[SCAN_B];
    s[threadIdx.x] = v;
    __syncthreads();
    for (int off = 1; off < SCAN_B; off <<= 1) {
        int t = (threadIdx.x >= off) ? s[threadIdx.x - off] : 0;
        __syncthreads();
        s[threadIdx.x] += t;
        __syncthreads();
    }
    if (i < NN) base[i] = s[threadIdx.x] - v;
    if (threadIdx.x == SCAN_B - 1) bsum[blockIdx.x] = s[SCAN_B - 1];
}

__global__ __launch_bounds__(SCAN_B) void k_scan_top(int* __restrict__ bsum)
{
    const int i = threadIdx.x;
    const int v = (i < NBLK) ? bsum[i] : 0;
    __shared__ int s[SCAN_B];
    s[i] = v;
    __syncthreads();
    for (int off = 1; off < SCAN_B; off <<= 1) {
        int t = (i >= off) ? s[i - off] : 0;
        __syncthreads();
        s[i] += t;
        __syncthreads();
    }
    if (i < NBLK) bsum[i] = s[i] - v;
}

__global__ __launch_bounds__(SCAN_B) void k_scan_add(
    int* __restrict__ base, const int* __restrict__ bsum, int* __restrict__ cursor)
{
    const int i = blockIdx.x * SCAN_B + threadIdx.x;
    if (i < NN) {
        const int b = base[i] + bsum[i >> 8];
        base[i] = b;
        cursor[i] = b;
    }
}

__global__ __launch_bounds__(256) void k_scatter(
    const int* __restrict__ edge_index, int* __restrict__ cursor,
    int* __restrict__ eidx, int* __restrict__ rowv, int* __restrict__ colv)
{
    for (int e = blockIdx.x * blockDim.x + threadIdx.x; e < EE;
         e += gridDim.x * blockDim.x) {
        const int r = edge_index[e];
        const int pos = atomicAdd(&cursor[r], 1);
        eidx[pos] = e;
        rowv[pos] = r;
        colv[pos] = edge_index[EE + e];
    }
}

// ---------------- ea -> bf16, permuted to CSR order ----------------
__global__ __launch_bounds__(256) void k_ea_csr(
    const float* __restrict__ ea, const int* __restrict__ eidx,
    unsigned* __restrict__ ea_bf)
{
    const int i = blockIdx.x * 256 + threadIdx.x;
    const int pos = i >> 5, u = i & 31;
    const int e = eidx[pos];
    const float2 v = *(const float2*)(ea + (size_t)e * ECD + u * 2);
    ea_bf[(size_t)pos * 32 + u] = pk2(v.x, v.y);
}

// ---------------- K2: edge kernel, lane-per-edge, all bf16 inputs ----------
__global__ __launch_bounds__(256) void k_edge_all(
    const unsigned* __restrict__ ea_bf,
    const int* __restrict__ rowv, const int* __restrict__ colv,
    const unsigned* __restrict__ hk_bf, const unsigned* __restrict__ hv_bf,
    const unsigned* __restrict__ g_bf, const float* __restrict__ c0_in,
    const float* __restrict__ wk1_w, const float* __restrict__ wk1_b,
    const float* __restrict__ wk2_w, const float* __restrict__ wk2_b,
    const float* __restrict__ wv1_w, const float* __restrict__ wv1_b,
    const float* __restrict__ wv2_w, const float* __restrict__ wv2_b,
    float* __restrict__ qkP, unsigned* __restrict__ mvP)
{
    const int pos = blockIdx.x * 256 + threadIdx.x;
    const int row = rowv[pos];
    const int col = colv[pos];
    const uint4* eap = (const uint4*)(ea_bf + (size_t)pos * 32);
    const uint4* hkp = (const uint4*)(hk_bf + (size_t)col * 64);
    const uint4* gp  = (const uint4*)(g_bf  + (size_t)row * 64);
    const uint4* hvp = (const uint4*)(hv_bf + (size_t)col * 64);
    const float4 c0v = *(const float4*)(c0_in + (size_t)row * NHD);

    float acc[32], t1[32];

    // ======== K path: MLP1 ========
    #pragma unroll
    for (int k = 0; k < 32; ++k) acc[k] = wk1_b[k];
    #pragma unroll
    for (int cc = 0; cc < 8; ++cc) {
        const uint4 u = eap[cc];
        float f[8];
        unp2(u.x, f[0], f[1]); unp2(u.y, f[2], f[3]);
        unp2(u.z, f[4], f[5]); unp2(u.w, f[6], f[7]);
        const float* w = wk1_w + cc * 8;
        #pragma unroll
        for (int k = 0; k < 32; ++k) {
            #pragma unroll
            for (int c = 0; c < 8; ++c)
                acc[k] = fmaf(f[c], w[(size_t)k * ECD + c], acc[k]);
        }
    }
    #pragma unroll
    for (int k = 0; k < 32; ++k) t1[k] = ssp_f(acc[k]);
    #pragma unroll
    for (int k = 0; k < 32; ++k) acc[k] = wk2_b[k];
    #pragma unroll
    for (int c = 0; c < 32; ++c) {
        #pragma unroll
        for (int k = 0; k < 32; ++k)
            acc[k] = fmaf(t1[c], wk2_w[(size_t)k * HH + c], acc[k]);
    }

    // qk[h] = c0[h] + sum_k Wk[k] * hk[col,h,k] * g[row,h,k]
    #pragma unroll
    for (int h = 0; h < NHD; ++h) {
        float s = 0.f;
        #pragma unroll
        for (int q = 0; q < 4; ++q) {
            const uint4 ku = hkp[h * 4 + q];
            const uint4 gu = gp[h * 4 + q];
            float ka, kb, ga, gb;
            unp2(ku.x, ka, kb); unp2(gu.x, ga, gb);
            s = fmaf(acc[q * 8 + 0] * ka, ga, s);
            s = fmaf(acc[q * 8 + 1] * kb, gb, s);
            unp2(ku.y, ka, kb); unp2(gu.y, ga, gb);
            s = fmaf(acc[q * 8 + 2] * ka, ga, s);
            s = fmaf(acc[q * 8 + 3] * kb, gb, s);
            unp2(ku.z, ka, kb); unp2(gu.z, ga, gb);
            s = fmaf(acc[q * 8 + 4] * ka, ga, s);
            s = fmaf(acc[q * 8 + 5] * kb, gb, s);
            unp2(ku.w, ka, kb); unp2(gu.w, ga, gb);
            s = fmaf(acc[q * 8 + 6] * ka, ga, s);
            s = fmaf(acc[q * 8 + 7] * kb, gb, s);
        }
        const float c0h = (h == 0) ? c0v.x : (h == 1) ? c0v.y : (h == 2) ? c0v.z : c0v.w;
        qkP[(size_t)h * EE + pos] = s + c0h;
    }

    // ======== V path: MLP1 ========
    #pragma unroll
    for (int k = 0; k < 32; ++k) acc[k] = wv1_b[k];
    #pragma unroll
    for (int cc = 0; cc < 8; ++cc) {
        const uint4 u = eap[cc];
        float f[8];
        unp2(u.x, f[0], f[1]); unp2(u.y, f[2], f[3]);
        unp2(u.z, f[4], f[5]); unp2(u.w, f[6], f[7]);
        const float* w = wv1_w + cc * 8;
        #pragma unroll
        for (int k = 0; k < 32; ++k) {
            #pragma unroll
            for (int c = 0; c < 8; ++c)
                acc[k] = fmaf(f[c], w[(size_t)k * ECD + c], acc[k]);
        }
    }
    #pragma unroll
    for (int k = 0; k < 32; ++k) t1[k] = ssp_f(acc[k]);
    #pragma unroll
    for (int k = 0; k < 32; ++k) acc[k] = wv2_b[k];
    #pragma unroll
    for (int c = 0; c < 32; ++c) {
        #pragma unroll
        for (int k = 0; k < 32; ++k)
            acc[k] = fmaf(t1[c], wv2_w[(size_t)k * HH + c], acc[k]);
    }

    // mv[h,d] = Wv[d] * hv[col,h,d]  (bf16 packed, CSR-ordered)
    #pragma unroll
    for (int h = 0; h < NHD; ++h) {
        uint4 o[4];
        #pragma unroll
        for (int q = 0; q < 4; ++q) {
            const uint4 vu = hvp[h * 4 + q];
            float va, vb;
            unsigned r[4];
            unp2(vu.x, va, vb);
            r[0] = pk2(acc[q * 8 + 0] * va, acc[q * 8 + 1] * vb);
            unp2(vu.y, va, vb);
            r[1] = pk2(acc[q * 8 + 2] * va, acc[q * 8 + 3] * vb);
            unp2(vu.z, va, vb);
            r[2] = pk2(acc[q * 8 + 4] * va, acc[q * 8 + 5] * vb);
            unp2(vu.w, va, vb);
            r[3] = pk2(acc[q * 8 + 6] * va, acc[q * 8 + 7] * vb);
            o[q].x = r[0]; o[q].y = r[1]; o[q].z = r[2]; o[q].w = r[3];
        }
        uint4* mb = (uint4*)(mvP + (size_t)pos * 64 + h * 16);
        mb[0] = o[0]; mb[1] = o[1]; mb[2] = o[2]; mb[3] = o[3];
    }
}

// ---------------- K3: per-node softmax + aggregate + LN2 + out ----------------
// 128 threads. Aggregation: 8 edge-slots x 16 d-parts, uint4 (8 bf16) per load.
__global__ __launch_bounds__(128) void k_node_fin(
    const float* __restrict__ x, const float* __restrict__ qkP,
    const unsigned* __restrict__ mv32,
    const int* __restrict__ base, const int* __restrict__ deg,
    const float* __restrict__ wvl_w, const float* __restrict__ wvl_b,
    const float* __restrict__ out_w, const float* __restrict__ out_b,
    const float* __restrict__ ln2_g, const float* __restrict__ ln2_b,
    float* __restrict__ out)
{
    const int n = blockIdx.x;
    const int t = threadIdx.x;
    const int h = t >> 5, j = t & 31;
    const int b0 = base[n];
    const int dn = deg[n];
    __shared__ float sw[NHD][TILE];
    __shared__ float sacc[8][HD];
    __shared__ float su[HD];
    __shared__ float sS[HD];
    __shared__ float red[4];

    const float* qkh = qkP + (size_t)h * EE + b0;

    // per-head max
    float mh = -3.0e38f;
    for (int i = j; i < dn; i += 32) mh = fmaxf(mh, qkh[i]);
    #pragma unroll
    for (int off = 16; off; off >>= 1) mh = fmaxf(mh, __shfl_xor(mh, off, 32));

    // denominator
    float den = 0.f;
    for (int i = j; i < dn; i += 32) den += __expf(qkh[i] - mh);
    #pragma unroll
    for (int off = 16; off; off >>= 1) den += __shfl_xor(den, off, 32);
    const float rden = (dn > 0 && den > 0.f) ? 1.0f / den : 0.f;

    // chunked weighted aggregation
    const int slot = t >> 4;          // 8 edge slots
    const int dp = t & 15;            // covers d = dp*8 .. dp*8+7
    const int hh = dp >> 2;           // head of those elements
    float acc[8] = {0.f, 0.f, 0.f, 0.f, 0.f, 0.f, 0.f, 0.f};
    for (int c = 0; c < dn; c += TILE) {
        const int tn = (dn - c < TILE) ? (dn - c) : TILE;
        __syncthreads();              // protect sw from previous chunk readers
        for (int i = j; i < tn; i += 32)
            sw[h][i] = __expf(qkh[c + i] - mh) * rden;
        __syncthreads();
        for (int i = slot; i < tn; i += 8) {
            const float w = sw[hh][i];
            const uint4 v = *(const uint4*)(mv32 + (size_t)(b0 + c + i) * 64 + dp * 4);
            float a, b;
            unp2(v.x, a, b); acc[0] = fmaf(w, a, acc[0]); acc[1] = fmaf(w, b, acc[1]);
            unp2(v.y, a, b); acc[2] = fmaf(w, a, acc[2]); acc[3] = fmaf(w, b, acc[3]);
            unp2(v.z, a, b); acc[4] = fmaf(w, a, acc[4]); acc[5] = fmaf(w, b, acc[5]);
            unp2(v.w, a, b); acc[6] = fmaf(w, a, acc[6]); acc[7] = fmaf(w, b, acc[7]);
        }
    }
    #pragma unroll
    for (int q = 0; q < 8; ++q) sacc[slot][dp * 8 + q] = acc[q];
    __syncthreads();
    float u = 0.f;
    #pragma unroll
    for (int s = 0; s < 8; ++s) u += sacc[s][t];
    su[t] = u;
    __syncthreads();

    // wvl matmul (0 if no edges), residual
    float ag = 0.f;
    if (dn > 0) {
        ag = wvl_b[j];
        const float4* wr = (const float4*)(wvl_w + (size_t)j * HH);
        const float* uh = su + h * HH;
        #pragma unroll
        for (int d4 = 0; d4 < 8; ++d4) {
            const float4 w = wr[d4];
            ag = fmaf(uh[d4 * 4 + 0], w.x, ag);
            ag = fmaf(uh[d4 * 4 + 1], w.y, ag);
            ag = fmaf(uh[d4 * 4 + 2], w.z, ag);
            ag = fmaf(uh[d4 * 4 + 3], w.w, ag);
        }
    }

    const float x2 = ag + x[(size_t)n * HD + t];

    float s1 = x2, s2 = x2 * x2;
    #pragma unroll
    for (int off = 32; off; off >>= 1) {
        s1 += __shfl_down(s1, off);
        s2 += __shfl_down(s2, off);
    }
    const int wid = t >> 6;
    if ((t & 63) == 0) { red[wid * 2] = s1; red[wid * 2 + 1] = s2; }
    __syncthreads();
    const float mean = (red[0] + red[2]) * (1.0f / HD);
    const float var  = (red[1] + red[3]) * (1.0f / HD) - mean * mean;
    const float rstd = rsqrtf(var + 1e-5f);
    const float y2 = (x2 - mean) * rstd * ln2_g[t] + ln2_b[t];
    sS[t] = ssp_f(y2);
    __syncthreads();

    float accum = out_b[t] + x2;
    const float4* wrow = (const float4*)(out_w + (size_t)t * HD);
    #pragma unroll
    for (int d4 = 0; d4 < 32; ++d4) {
        const float4 w = wrow[d4];
        accum = fmaf(sS[d4 * 4 + 0], w.x, accum);
        accum = fmaf(sS[d4 * 4 + 1], w.y, accum);
        accum = fmaf(sS[d4 * 4 + 2], w.z, accum);
        accum = fmaf(sS[d4 * 4 + 3], w.w, accum);
    }
    out[(size_t)n * HD + t] = accum;
}

extern "C" void kernel_launch(void* const* d_in, const int* in_sizes, int n_in,
                              void* d_out, int out_size, void* d_ws, size_t ws_size,
                              hipStream_t stream) {
    const float* x         = (const float*)d_in[0];
    const float* edge_attr = (const float*)d_in[1];
    const int*   edge_index= (const int*)  d_in[2];
    const float* k_w   = (const float*)d_in[3];
    const float* q_w   = (const float*)d_in[4];
    const float* v_w   = (const float*)d_in[5];
    const float* wk1_w = (const float*)d_in[6];
    const float* wk1_b = (const float*)d_in[7];
    const float* wk2_w = (const float*)d_in[8];
    const float* wk2_b = (const float*)d_in[9];
    const float* wkl_w = (const float*)d_in[10];
    const float* wkl_b = (const float*)d_in[11];
    const float* wv1_w = (const float*)d_in[12];
    const float* wv1_b = (const float*)d_in[13];
    const float* wv2_w = (const float*)d_in[14];
    const float* wv2_b = (const float*)d_in[15];
    const float* wvl_w = (const float*)d_in[16];
    const float* wvl_b = (const float*)d_in[17];
    const float* out_w = (const float*)d_in[18];
    const float* out_b = (const float*)d_in[19];
    const float* ln1_g = (const float*)d_in[20];
    const float* ln1_b = (const float*)d_in[21];
    const float* ln2_g = (const float*)d_in[22];
    const float* ln2_b = (const float*)d_in[23];

    char* ws = (char*)d_ws;
    unsigned* hk_bf = (unsigned*)ws;            ws += (size_t)NN * 64 * 4;
    unsigned* hv_bf = (unsigned*)ws;            ws += (size_t)NN * 64 * 4;
    unsigned* g_bf  = (unsigned*)ws;            ws += (size_t)NN * 64 * 4;
    float* c0  = (float*)ws;                    ws += (size_t)NN * NHD * 4;
    float* qkP = (float*)ws;                    ws += (size_t)NHD * EE * 4;
    unsigned* mvP = (unsigned*)ws;              ws += (size_t)EE * 64 * 4;
    unsigned* ea_bf = (unsigned*)ws;            ws += (size_t)EE * 32 * 4;
    int* deg    = (int*)ws;                     ws += (size_t)NN * 4;
    int* base   = (int*)ws;                     ws += (size_t)NN * 4;
    int* cursor = (int*)ws;                     ws += (size_t)NN * 4;
    int* bsum   = (int*)ws;                     ws += (size_t)SCAN_B * 4;
    int* eidx   = (int*)ws;                     ws += (size_t)EE * 4;
    int* rowv   = (int*)ws;                     ws += (size_t)EE * 4;
    int* colv   = (int*)ws;                     ws += (size_t)EE * 4;

    (void)hipMemsetAsync(deg, 0, (size_t)NN * 4, stream);

    k_node_prep<<<NN, 128, 0, stream>>>(x, k_w, q_w, v_w, wkl_w, wkl_b,
        ln1_g, ln1_b, hk_bf, hv_bf, g_bf, c0);
    k_deg<<<1024, 256, 0, stream>>>(edge_index, deg);
    k_scan_block<<<NBLK, SCAN_B, 0, stream>>>(deg, base, bsum);
    k_scan_top<<<1, SCAN_B, 0, stream>>>(bsum);
    k_scan_add<<<NBLK, SCAN_B, 0, stream>>>(base, bsum, cursor);
    k_scatter<<<1024, 256, 0, stream>>>(edge_index, cursor, eidx, rowv, colv);
    k_ea_csr<<<EE * 32 / 256, 256, 0, stream>>>(edge_attr, eidx, ea_bf);
    k_edge_all<<<EE / 256, 256, 0, stream>>>(ea_bf, rowv, colv,
        hk_bf, hv_bf, g_bf, c0,
        wk1_w, wk1_b, wk2_w, wk2_b, wv1_w, wv1_b, wv2_w, wv2_b, qkP, mvP);
    k_node_fin<<<NN, 128, 0, stream>>>(x, qkP, mvP,
        base, deg, wvl_w, wvl_b, out_w, out_b, ln2_g, ln2_b, (float*)d_out);
}

// Round 7
// 1029.311 us; speedup vs baseline: 3.0374x; 1.3893x over previous
//
#include <hip/hip_runtime.h>
#include <math.h>

#define NN 50000
#define EE 640000
#define HD 128
#define ECD 64
#define NHD 4
#define HH 32
#define SCAN_B 256
#define NBLK ((NN + SCAN_B - 1) / SCAN_B)   // 196

__device__ __forceinline__ float ssp_f(float v) {
    return fmaxf(v, 0.0f) + log1pf(__expf(-fabsf(v))) - 0.69314718055994531f;
}
__device__ __forceinline__ unsigned f2bf_u(float f) {
    unsigned u = __float_as_uint(f);
    unsigned r = ((u >> 16) & 1u) + 0x7FFFu;
    return (u + r) >> 16;
}
__device__ __forceinline__ unsigned pk2(float a, float b) {
    return f2bf_u(a) | (f2bf_u(b) << 16);
}
__device__ __forceinline__ void unp2(unsigned u, float& a, float& b) {
    a = __uint_as_float(u << 16);
    b = __uint_as_float(u & 0xffff0000u);
}

// ---------------- K1: LN1 + projections + g/c0 (wave-per-node, persistent) ----
__global__ __launch_bounds__(256) void k_node_prep(
    const float* __restrict__ x, const float* __restrict__ k_w,
    const float* __restrict__ q_w, const float* __restrict__ v_w,
    const float* __restrict__ wkl_w, const float* __restrict__ wkl_b,
    const float* __restrict__ ln1_g, const float* __restrict__ ln1_b,
    unsigned* __restrict__ hk_bf, unsigned* __restrict__ hv_bf,
    unsigned* __restrict__ g_bf, float* __restrict__ c0_out)
{
    __shared__ float wklT[HH * 36];     // transposed, padded stride 36
    __shared__ float ybuf[4][HD];
    for (int idx = threadIdx.x; idx < HH * HH; idx += 256)
        wklT[(idx & 31) * 36 + (idx >> 5)] = wkl_w[idx];
    __syncthreads();   // only barrier; persistent loop below is barrier-free

    const int w = threadIdx.x >> 6, l = threadIdx.x & 63;
    const int h = l >> 4, i16 = l & 15;
    const int t0 = 2 * l;
    const float2 lg2 = *(const float2*)(ln1_g + t0);
    const float2 lb2 = *(const float2*)(ln1_b + t0);
    const float2 wb2 = *(const float2*)(wkl_b + 2 * i16);
    float* yb = ybuf[w];

    for (int n = blockIdx.x * 4 + w; n < NN; n += 1024 * 4) {
        const float2 xv = *(const float2*)(x + (size_t)n * HD + t0);
        float s1 = xv.x + xv.y;
        float s2 = xv.x * xv.x + xv.y * xv.y;
        #pragma unroll
        for (int off = 1; off < 64; off <<= 1) {
            s1 += __shfl_xor(s1, off);
            s2 += __shfl_xor(s2, off);
        }
        const float mean = s1 * (1.0f / HD);
        const float var  = s2 * (1.0f / HD) - mean * mean;
        const float rstd = rsqrtf(var + 1e-5f);
        const float y0 = (xv.x - mean) * rstd * lg2.x + lb2.x;
        const float y1 = (xv.y - mean) * rstd * lg2.y + lb2.y;
        *(float2*)(yb + t0) = make_float2(y0, y1);

        float yr[32];
        {
            const float4* yp = (const float4*)(yb + h * HH);
            #pragma unroll
            for (int q = 0; q < 8; ++q) {
                const float4 v = yp[q];
                yr[q*4+0] = v.x; yr[q*4+1] = v.y; yr[q*4+2] = v.z; yr[q*4+3] = v.w;
            }
        }
        float ak0=0,ak1=0,aq0=0,aq1=0,av0=0,av1=0;
        {
            const float4* kr0 = (const float4*)(k_w + (size_t)t0 * HH);
            const float4* kr1 = (const float4*)(k_w + (size_t)(t0+1) * HH);
            const float4* qr0 = (const float4*)(q_w + (size_t)t0 * HH);
            const float4* qr1 = (const float4*)(q_w + (size_t)(t0+1) * HH);
            const float4* vr0 = (const float4*)(v_w + (size_t)t0 * HH);
            const float4* vr1 = (const float4*)(v_w + (size_t)(t0+1) * HH);
            #pragma unroll
            for (int q = 0; q < 8; ++q) {
                const float4 a = kr0[q], b = kr1[q], c = qr0[q], d = qr1[q];
                const float4 e = vr0[q], f = vr1[q];
                ak0 = fmaf(yr[q*4+0], a.x, ak0); ak0 = fmaf(yr[q*4+1], a.y, ak0);
                ak0 = fmaf(yr[q*4+2], a.z, ak0); ak0 = fmaf(yr[q*4+3], a.w, ak0);
                ak1 = fmaf(yr[q*4+0], b.x, ak1); ak1 = fmaf(yr[q*4+1], b.y, ak1);
                ak1 = fmaf(yr[q*4+2], b.z, ak1); ak1 = fmaf(yr[q*4+3], b.w, ak1);
                aq0 = fmaf(yr[q*4+0], c.x, aq0); aq0 = fmaf(yr[q*4+1], c.y, aq0);
                aq0 = fmaf(yr[q*4+2], c.z, aq0); aq0 = fmaf(yr[q*4+3], c.w, aq0);
                aq1 = fmaf(yr[q*4+0], d.x, aq1); aq1 = fmaf(yr[q*4+1], d.y, aq1);
                aq1 = fmaf(yr[q*4+2], d.z, aq1); aq1 = fmaf(yr[q*4+3], d.w, aq1);
                av0 = fmaf(yr[q*4+0], e.x, av0); av0 = fmaf(yr[q*4+1], e.y, av0);
                av0 = fmaf(yr[q*4+2], e.z, av0); av0 = fmaf(yr[q*4+3], e.w, av0);
                av1 = fmaf(yr[q*4+0], f.x, av1); av1 = fmaf(yr[q*4+1], f.y, av1);
                av1 = fmaf(yr[q*4+2], f.z, av1); av1 = fmaf(yr[q*4+3], f.w, av1);
            }
        }
        hk_bf[(size_t)n * 64 + l] = pk2(ak0, ak1);
        hv_bf[(size_t)n * 64 + l] = pk2(av0, av1);

        // stage h_q (yb fully consumed into yr above; same-wave ordering)
        *(float2*)(yb + t0) = make_float2(aq0, aq1);
        float hqr[32];
        {
            const float4* hp = (const float4*)(yb + h * HH);
            #pragma unroll
            for (int q = 0; q < 8; ++q) {
                const float4 v = hp[q];
                hqr[q*4+0] = v.x; hqr[q*4+1] = v.y; hqr[q*4+2] = v.z; hqr[q*4+3] = v.w;
            }
        }
        // c0[n,h] = sum_k hq[h,k] * wkl_b[k]
        float p = aq0 * wb2.x + aq1 * wb2.y;
        #pragma unroll
        for (int off = 1; off < 16; off <<= 1) p += __shfl_xor(p, off);
        if (i16 == 0) c0_out[n * NHD + h] = p;

        // g[h,k] = sum_j hq[h,j] * wkl_w[j,k]  (wklT rows, padded stride)
        const int k0 = 2 * i16;
        float g0 = 0.f, g1 = 0.f;
        {
            const float4* w0 = (const float4*)(wklT + k0 * 36);
            const float4* w1 = (const float4*)(wklT + (k0 + 1) * 36);
            #pragma unroll
            for (int q = 0; q < 8; ++q) {
                const float4 a = w0[q], b = w1[q];
                g0 = fmaf(hqr[q*4+0], a.x, g0); g0 = fmaf(hqr[q*4+1], a.y, g0);
                g0 = fmaf(hqr[q*4+2], a.z, g0); g0 = fmaf(hqr[q*4+3], a.w, g0);
                g1 = fmaf(hqr[q*4+0], b.x, g1); g1 = fmaf(hqr[q*4+1], b.y, g1);
                g1 = fmaf(hqr[q*4+2], b.z, g1); g1 = fmaf(hqr[q*4+3], b.w, g1);
            }
        }
        g_bf[(size_t)n * 64 + l] = pk2(g0, g1);
    }
}

// ---------------- CSR build ----------------
__global__ __launch_bounds__(256) void k_deg(
    const int* __restrict__ edge_index, int* __restrict__ deg)
{
    for (int e = blockIdx.x * blockDim.x + threadIdx.x; e < EE;
         e += gridDim.x * blockDim.x)
        atomicAdd(&deg[edge_index[e]], 1);
}

__global__ __launch_bounds__(SCAN_B) void k_scan_block(
    const int* __restrict__ deg, int* __restrict__ base, int* __restrict__ bsum)
{
    const int i = blockIdx.x * SCAN_B + threadIdx.x;
    const int v = (i < NN) ? deg[i] : 0;
    __shared__ int s[SCAN_B];
    s[threadIdx.x] = v;
    __syncthreads();
    for (int off = 1; off < SCAN_B; off <<= 1) {
        int t = (threadIdx.x >= off) ? s[threadIdx.x - off] : 0;
        __syncthreads();
        s[threadIdx.x] += t;
        __syncthreads();
    }
    if (i < NN) base[i] = s[threadIdx.x] - v;
    if (threadIdx.x == SCAN_B - 1) bsum[blockIdx.x] = s[SCAN_B - 1];
}

__global__ __launch_bounds__(SCAN_B) void k_scan_top(int* __restrict__ bsum)
{
    const int i = threadIdx.x;
    const int v = (i < NBLK) ? bsum[i] : 0;
    __shared__ int s[SCAN_B];
    s[i] = v;
    __syncthreads();
    for (int off = 1; off < SCAN_B; off <<= 1) {
        int t = (i >= off) ? s[i - off] : 0;
        __syncthreads();
        s[i] += t;
        __syncthreads();
    }
    if (i < NBLK) bsum[i] = s[i] - v;
}

__global__ __launch_bounds__(SCAN_B) void k_scan_add(
    int* __restrict__ base, const int* __restrict__ bsum, int* __restrict__ cursor)
{
    const int i = blockIdx.x * SCAN_B + threadIdx.x;
    if (i < NN) {
        const int b = base[i] + bsum[i >> 8];
        base[i] = b;
        cursor[i] = b;
    }
}

__global__ __launch_bounds__(256) void k_scatter(
    const int* __restrict__ edge_index, int* __restrict__ cursor,
    int* __restrict__ eidx, int* __restrict__ rowv, int* __restrict__ colv)
{
    for (int e = blockIdx.x * blockDim.x + threadIdx.x; e < EE;
         e += gridDim.x * blockDim.x) {
        const int r = edge_index[e];
        const int pos = atomicAdd(&cursor[r], 1);
        eidx[pos] = e;
        rowv[pos] = r;
        colv[pos] = edge_index[EE + e];
    }
}

// ---------------- ea -> bf16, permuted to CSR order (grid-stride) ----------
__global__ __launch_bounds__(256) void k_ea_csr(
    const float* __restrict__ ea, const int* __restrict__ eidx,
    unsigned* __restrict__ ea_bf)
{
    for (int i = blockIdx.x * 256 + threadIdx.x; i < EE * 32;
         i += 2048 * 256) {
        const int pos = i >> 5, u = i & 31;
        const int e = eidx[pos];
        const float2 v = *(const float2*)(ea + (size_t)e * ECD + u * 2);
        ea_bf[(size_t)pos * 32 + u] = pk2(v.x, v.y);
    }
}

// ---------------- K2: edge kernel, lane-per-edge (qk + Wv only) -------------
__global__ __launch_bounds__(256) void k_edge_all(
    const unsigned* __restrict__ ea_bf,
    const int* __restrict__ rowv, const int* __restrict__ colv,
    const unsigned* __restrict__ hk_bf,
    const unsigned* __restrict__ g_bf, const float* __restrict__ c0_in,
    const float* __restrict__ wk1_w, const float* __restrict__ wk1_b,
    const float* __restrict__ wk2_w, const float* __restrict__ wk2_b,
    const float* __restrict__ wv1_w, const float* __restrict__ wv1_b,
    const float* __restrict__ wv2_w, const float* __restrict__ wv2_b,
    float* __restrict__ qkP, unsigned* __restrict__ wvP)
{
    const int pos = blockIdx.x * 256 + threadIdx.x;
    const int row = rowv[pos];
    const int col = colv[pos];
    const uint4* eap = (const uint4*)(ea_bf + (size_t)pos * 32);
    const uint4* hkp = (const uint4*)(hk_bf + (size_t)col * 64);
    const uint4* gp  = (const uint4*)(g_bf  + (size_t)row * 64);
    const float4 c0v = *(const float4*)(c0_in + (size_t)row * NHD);

    float acc[32], t1[32];

    // ======== K path: MLP1 ========
    #pragma unroll
    for (int k = 0; k < 32; ++k) acc[k] = wk1_b[k];
    #pragma unroll
    for (int cc = 0; cc < 8; ++cc) {
        const uint4 u = eap[cc];
        float f[8];
        unp2(u.x, f[0], f[1]); unp2(u.y, f[2], f[3]);
        unp2(u.z, f[4], f[5]); unp2(u.w, f[6], f[7]);
        const float* w = wk1_w + cc * 8;
        #pragma unroll
        for (int k = 0; k < 32; ++k) {
            #pragma unroll
            for (int c = 0; c < 8; ++c)
                acc[k] = fmaf(f[c], w[(size_t)k * ECD + c], acc[k]);
        }
    }
    #pragma unroll
    for (int k = 0; k < 32; ++k) t1[k] = ssp_f(acc[k]);
    #pragma unroll
    for (int k = 0; k < 32; ++k) acc[k] = wk2_b[k];
    #pragma unroll
    for (int c = 0; c < 32; ++c) {
        #pragma unroll
        for (int k = 0; k < 32; ++k)
            acc[k] = fmaf(t1[c], wk2_w[(size_t)k * HH + c], acc[k]);
    }

    // qk[h] = c0[h] + sum_k Wk[k] * hk[col,h,k] * g[row,h,k]
    #pragma unroll
    for (int h = 0; h < NHD; ++h) {
        float s = 0.f;
        #pragma unroll
        for (int q = 0; q < 4; ++q) {
            const uint4 ku = hkp[h * 4 + q];
            const uint4 gu = gp[h * 4 + q];
            float ka, kb, ga, gb;
            unp2(ku.x, ka, kb); unp2(gu.x, ga, gb);
            s = fmaf(acc[q * 8 + 0] * ka, ga, s);
            s = fmaf(acc[q * 8 + 1] * kb, gb, s);
            unp2(ku.y, ka, kb); unp2(gu.y, ga, gb);
            s = fmaf(acc[q * 8 + 2] * ka, ga, s);
            s = fmaf(acc[q * 8 + 3] * kb, gb, s);
            unp2(ku.z, ka, kb); unp2(gu.z, ga, gb);
            s = fmaf(acc[q * 8 + 4] * ka, ga, s);
            s = fmaf(acc[q * 8 + 5] * kb, gb, s);
            unp2(ku.w, ka, kb); unp2(gu.w, ga, gb);
            s = fmaf(acc[q * 8 + 6] * ka, ga, s);
            s = fmaf(acc[q * 8 + 7] * kb, gb, s);
        }
        const float c0h = (h == 0) ? c0v.x : (h == 1) ? c0v.y : (h == 2) ? c0v.z : c0v.w;
        qkP[(size_t)h * EE + pos] = s + c0h;
    }

    // ======== V path: MLP1+MLP2 -> Wv (bf16, 64 B/edge) ========
    #pragma unroll
    for (int k = 0; k < 32; ++k) acc[k] = wv1_b[k];
    #pragma unroll
    for (int cc = 0; cc < 8; ++cc) {
        const uint4 u = eap[cc];
        float f[8];
        unp2(u.x, f[0], f[1]); unp2(u.y, f[2], f[3]);
        unp2(u.z, f[4], f[5]); unp2(u.w, f[6], f[7]);
        const float* w = wv1_w + cc * 8;
        #pragma unroll
        for (int k = 0; k < 32; ++k) {
            #pragma unroll
            for (int c = 0; c < 8; ++c)
                acc[k] = fmaf(f[c], w[(size_t)k * ECD + c], acc[k]);
        }
    }
    #pragma unroll
    for (int k = 0; k < 32; ++k) t1[k] = ssp_f(acc[k]);
    #pragma unroll
    for (int k = 0; k < 32; ++k) acc[k] = wv2_b[k];
    #pragma unroll
    for (int c = 0; c < 32; ++c) {
        #pragma unroll
        for (int k = 0; k < 32; ++k)
            acc[k] = fmaf(t1[c], wv2_w[(size_t)k * HH + c], acc[k]);
    }
    #pragma unroll
    for (int q = 0; q < 4; ++q) {
        uint4 o;
        o.x = pk2(acc[q * 8 + 0], acc[q * 8 + 1]);
        o.y = pk2(acc[q * 8 + 2], acc[q * 8 + 3]);
        o.z = pk2(acc[q * 8 + 4], acc[q * 8 + 5]);
        o.w = pk2(acc[q * 8 + 6], acc[q * 8 + 7]);
        *(uint4*)(wvP + (size_t)pos * 16 + q * 4) = o;
    }
}

// ---------------- K3: wave-per-node softmax+aggregate+LN2+out (persistent) --
__global__ __launch_bounds__(256) void k_node_fin(
    const float* __restrict__ x, const float* __restrict__ qkP,
    const unsigned* __restrict__ wvP, const unsigned* __restrict__ hv_bf,
    const int* __restrict__ colv,
    const int* __restrict__ base, const int* __restrict__ deg,
    const float* __restrict__ wvl_w, const float* __restrict__ wvl_b,
    const float* __restrict__ out_w, const float* __restrict__ out_b,
    const float* __restrict__ ln2_g, const float* __restrict__ ln2_b,
    float* __restrict__ out)
{
    __shared__ float su[4][HD];
    const int w = threadIdx.x >> 6, l = threadIdx.x & 63;
    const int h = l >> 4, i = l & 15;
    const int t0 = 2 * l;
    const float2 lg2 = *(const float2*)(ln2_g + t0);
    const float2 lb2 = *(const float2*)(ln2_b + t0);
    const float2 ob2 = *(const float2*)(out_b + t0);
    const int j0 = 2 * i;
    float* sb = su[w];

    for (int n = blockIdx.x * 4 + w; n < NN; n += 2048 * 4) {
        const int b0 = base[n];
        const int dn = deg[n];
        const float2 xv = *(const float2*)(x + (size_t)n * HD + t0);

        float acc0 = 0.f, acc1 = 0.f;
        if (dn > 0) {
            const float* qkh = qkP + (size_t)h * EE + b0;
            const int emax = b0 + dn - 1;
            // pass 1: max over 16-lane group
            float m = -3.0e38f;
            for (int c = i; c < dn; c += 16) m = fmaxf(m, qkh[c]);
            #pragma unroll
            for (int off = 1; off < 16; off <<= 1)
                m = fmaxf(m, __shfl_xor(m, off));
            // pass 2: denom
            float den = 0.f;
            for (int c = i; c < dn; c += 16) den += __expf(qkh[c] - m);
            #pragma unroll
            for (int off = 1; off < 16; off <<= 1) den += __shfl_xor(den, off);
            const float rden = (den > 0.f) ? 1.0f / den : 0.f;
            // pass 3: aggregate in chunks of 16 edges
            for (int c0 = 0; c0 < dn; c0 += 16) {
                const int tn = (dn - c0 < 16) ? (dn - c0) : 16;
                float ex = 0.f; int cq = 0;
                if (i < tn) {
                    ex = __expf(qkh[c0 + i] - m) * rden;
                    cq = colv[b0 + c0 + i];
                }
                const int t4 = (tn + 3) & ~3;
                for (int i2 = 0; i2 < t4; i2 += 4) {
                    #pragma unroll
                    for (int u = 0; u < 4; ++u) {
                        const int src = (l & 48) | (i2 + u);
                        const float wgt = __shfl(ex, src);
                        const int ce = __shfl(cq, src);
                        int ep = b0 + c0 + i2 + u;
                        ep = (ep > emax) ? emax : ep;
                        const unsigned hvv = hv_bf[(size_t)ce * 64 + l];
                        const unsigned wvv = wvP[(size_t)ep * 16 + i];
                        float ha, hb, wa, wb;
                        unp2(hvv, ha, hb); unp2(wvv, wa, wb);
                        acc0 = fmaf(wgt, wa * ha, acc0);
                        acc1 = fmaf(wgt, wb * hb, acc1);
                    }
                }
            }
        }

        // stage u, read head slice (same-wave LDS, no barrier)
        *(float2*)(sb + t0) = make_float2(acc0, acc1);
        float uh[32];
        {
            const float4* up = (const float4*)(sb + h * HH);
            #pragma unroll
            for (int q = 0; q < 8; ++q) {
                const float4 v = up[q];
                uh[q*4+0] = v.x; uh[q*4+1] = v.y; uh[q*4+2] = v.z; uh[q*4+3] = v.w;
            }
        }
        float ag0 = 0.f, ag1 = 0.f;
        if (dn > 0) {
            const float2 wb = *(const float2*)(wvl_b + j0);
            ag0 = wb.x; ag1 = wb.y;
            const float4* r0 = (const float4*)(wvl_w + (size_t)j0 * HH);
            const float4* r1 = (const float4*)(wvl_w + (size_t)(j0 + 1) * HH);
            #pragma unroll
            for (int q = 0; q < 8; ++q) {
                const float4 a = r0[q], b = r1[q];
                ag0 = fmaf(uh[q*4+0], a.x, ag0); ag0 = fmaf(uh[q*4+1], a.y, ag0);
                ag0 = fmaf(uh[q*4+2], a.z, ag0); ag0 = fmaf(uh[q*4+3], a.w, ag0);
                ag1 = fmaf(uh[q*4+0], b.x, ag1); ag1 = fmaf(uh[q*4+1], b.y, ag1);
                ag1 = fmaf(uh[q*4+2], b.z, ag1); ag1 = fmaf(uh[q*4+3], b.w, ag1);
            }
        }
        const float x20 = ag0 + xv.x;
        const float x21 = ag1 + xv.y;

        // LN2 (full-wave reduce)
        float s1 = x20 + x21, s2 = x20 * x20 + x21 * x21;
        #pragma unroll
        for (int off = 1; off < 64; off <<= 1) {
            s1 += __shfl_xor(s1, off);
            s2 += __shfl_xor(s2, off);
        }
        const float mean = s1 * (1.0f / HD);
        const float var  = s2 * (1.0f / HD) - mean * mean;
        const float rstd = rsqrtf(var + 1e-5f);
        const float ss0 = ssp_f((x20 - mean) * rstd * lg2.x + lb2.x);
        const float ss1 = ssp_f((x21 - mean) * rstd * lg2.y + lb2.y);

        // stage ssp vector (reuse sb; uh consumed)
        *(float2*)(sb + t0) = make_float2(ss0, ss1);
        float o0 = ob2.x + x20, o1 = ob2.y + x21;
        const float4* wr0 = (const float4*)(out_w + (size_t)t0 * HD);
        const float4* wr1 = (const float4*)(out_w + (size_t)(t0 + 1) * HD);
        #pragma unroll
        for (int c = 0; c < 4; ++c) {
            float sv[32];
            const float4* sp = (const float4*)(sb + c * 32);
            #pragma unroll
            for (int q = 0; q < 8; ++q) {
                const float4 v = sp[q];
                sv[q*4+0] = v.x; sv[q*4+1] = v.y; sv[q*4+2] = v.z; sv[q*4+3] = v.w;
            }
            #pragma unroll
            for (int q = 0; q < 8; ++q) {
                const float4 a = wr0[c * 8 + q], b = wr1[c * 8 + q];
                o0 = fmaf(sv[q*4+0], a.x, o0); o0 = fmaf(sv[q*4+1], a.y, o0);
                o0 = fmaf(sv[q*4+2], a.z, o0); o0 = fmaf(sv[q*4+3], a.w, o0);
                o1 = fmaf(sv[q*4+0], b.x, o1); o1 = fmaf(sv[q*4+1], b.y, o1);
                o1 = fmaf(sv[q*4+2], b.z, o1); o1 = fmaf(sv[q*4+3], b.w, o1);
            }
        }
        *(float2*)(out + (size_t)n * HD + t0) = make_float2(o0, o1);
    }
}

extern "C" void kernel_launch(void* const* d_in, const int* in_sizes, int n_in,
                              void* d_out, int out_size, void* d_ws, size_t ws_size,
                              hipStream_t stream) {
    const float* x         = (const float*)d_in[0];
    const float* edge_attr = (const float*)d_in[1];
    const int*   edge_index= (const int*)  d_in[2];
    const float* k_w   = (const float*)d_in[3];
    const float* q_w   = (const float*)d_in[4];
    const float* v_w   = (const float*)d_in[5];
    const float* wk1_w = (const float*)d_in[6];
    const float* wk1_b = (const float*)d_in[7];
    const float* wk2_w = (const float*)d_in[8];
    const float* wk2_b = (const float*)d_in[9];
    const float* wkl_w = (const float*)d_in[10];
    const float* wkl_b = (const float*)d_in[11];
    const float* wv1_w = (const float*)d_in[12];
    const float* wv1_b = (const float*)d_in[13];
    const float* wv2_w = (const float*)d_in[14];
    const float* wv2_b = (const float*)d_in[15];
    const float* wvl_w = (const float*)d_in[16];
    const float* wvl_b = (const float*)d_in[17];
    const float* out_w = (const float*)d_in[18];
    const float* out_b = (const float*)d_in[19];
    const float* ln1_g = (const float*)d_in[20];
    const float* ln1_b = (const float*)d_in[21];
    const float* ln2_g = (const float*)d_in[22];
    const float* ln2_b = (const float*)d_in[23];

    char* ws = (char*)d_ws;
    unsigned* hk_bf = (unsigned*)ws;            ws += (size_t)NN * 64 * 4;
    unsigned* hv_bf = (unsigned*)ws;            ws += (size_t)NN * 64 * 4;
    unsigned* g_bf  = (unsigned*)ws;            ws += (size_t)NN * 64 * 4;
    float* c0  = (float*)ws;                    ws += (size_t)NN * NHD * 4;
    float* qkP = (float*)ws;                    ws += (size_t)NHD * EE * 4;
    unsigned* wvP = (unsigned*)ws;              ws += (size_t)EE * 16 * 4;
    unsigned* ea_bf = (unsigned*)ws;            ws += (size_t)EE * 32 * 4;
    int* deg    = (int*)ws;                     ws += (size_t)NN * 4;
    int* base   = (int*)ws;                     ws += (size_t)NN * 4;
    int* cursor = (int*)ws;                     ws += (size_t)NN * 4;
    int* bsum   = (int*)ws;                     ws += (size_t)SCAN_B * 4;
    int* eidx   = (int*)ws;                     ws += (size_t)EE * 4;
    int* rowv   = (int*)ws;                     ws += (size_t)EE * 4;
    int* colv   = (int*)ws;                     ws += (size_t)EE * 4;

    (void)hipMemsetAsync(deg, 0, (size_t)NN * 4, stream);

    k_node_prep<<<1024, 256, 0, stream>>>(x, k_w, q_w, v_w, wkl_w, wkl_b,
        ln1_g, ln1_b, hk_bf, hv_bf, g_bf, c0);
    k_deg<<<1024, 256, 0, stream>>>(edge_index, deg);
    k_scan_block<<<NBLK, SCAN_B, 0, stream>>>(deg, base, bsum);
    k_scan_top<<<1, SCAN_B, 0, stream>>>(bsum);
    k_scan_add<<<NBLK, SCAN_B, 0, stream>>>(base, bsum, cursor);
    k_scatter<<<1024, 256, 0, stream>>>(edge_index, cursor, eidx, rowv, colv);
    k_ea_csr<<<2048, 256, 0, stream>>>(edge_attr, eidx, ea_bf);
    k_edge_all<<<EE / 256, 256, 0, stream>>>(ea_bf, rowv, colv,
        hk_bf, g_bf, c0,
        wk1_w, wk1_b, wk2_w, wk2_b, wv1_w, wv1_b, wv2_w, wv2_b, qkP, wvP);
    k_node_fin<<<2048, 256, 0, stream>>>(x, qkP, wvP, hv_bf, colv,
        base, deg, wvl_w, wvl_b, out_w, out_b, ln2_g, ln2_b, (float*)d_out);
}

// Round 8
// 758.073 us; speedup vs baseline: 4.1242x; 1.3578x over previous
//
#include <hip/hip_runtime.h>
#include <math.h>

#define NN 50000
#define EE 640000
#define HD 128
#define ECD 64
#define NHD 4
#define HH 32
#define SCAN_B 256
#define NBLK ((NN + SCAN_B - 1) / SCAN_B)   // 196
#define LSTR 33   // LDS row stride in floats (64 edges x 32 vals, +1 pad)

typedef short bf16x8 __attribute__((ext_vector_type(8)));
typedef float f32x4 __attribute__((ext_vector_type(4)));

__device__ __forceinline__ float ssp_f(float v) {
    return fmaxf(v, 0.0f) + log1pf(__expf(-fabsf(v))) - 0.69314718055994531f;
}
__device__ __forceinline__ unsigned f2bf_u(float f) {
    unsigned u = __float_as_uint(f);
    unsigned r = ((u >> 16) & 1u) + 0x7FFFu;
    return (u + r) >> 16;
}
__device__ __forceinline__ unsigned pk2(float a, float b) {
    return f2bf_u(a) | (f2bf_u(b) << 16);
}
__device__ __forceinline__ void unp2(unsigned u, float& a, float& b) {
    a = __uint_as_float(u << 16);
    b = __uint_as_float(u & 0xffff0000u);
}
__device__ __forceinline__ bf16x8 as_bf(uint4 u) {
    union { uint4 a; bf16x8 b; } c; c.a = u; return c.b;
}

// ---------------- K1: LN1 + projections + g/c0 (wave-per-node, persistent) ----
__global__ __launch_bounds__(256) void k_node_prep(
    const float* __restrict__ x, const float* __restrict__ k_w,
    const float* __restrict__ q_w, const float* __restrict__ v_w,
    const float* __restrict__ wkl_w, const float* __restrict__ wkl_b,
    const float* __restrict__ ln1_g, const float* __restrict__ ln1_b,
    unsigned* __restrict__ hk_bf, unsigned* __restrict__ hv_bf,
    unsigned* __restrict__ g_bf, float* __restrict__ c0_out)
{
    __shared__ float wklT[HH * 36];
    __shared__ float ybuf[4][HD];
    for (int idx = threadIdx.x; idx < HH * HH; idx += 256)
        wklT[(idx & 31) * 36 + (idx >> 5)] = wkl_w[idx];
    __syncthreads();

    const int w = threadIdx.x >> 6, l = threadIdx.x & 63;
    const int h = l >> 4, i16 = l & 15;
    const int t0 = 2 * l;
    const float2 lg2 = *(const float2*)(ln1_g + t0);
    const float2 lb2 = *(const float2*)(ln1_b + t0);
    const float2 wb2 = *(const float2*)(wkl_b + 2 * i16);
    float* yb = ybuf[w];

    for (int n = blockIdx.x * 4 + w; n < NN; n += 1024 * 4) {
        const float2 xv = *(const float2*)(x + (size_t)n * HD + t0);
        float s1 = xv.x + xv.y;
        float s2 = xv.x * xv.x + xv.y * xv.y;
        #pragma unroll
        for (int off = 1; off < 64; off <<= 1) {
            s1 += __shfl_xor(s1, off);
            s2 += __shfl_xor(s2, off);
        }
        const float mean = s1 * (1.0f / HD);
        const float var  = s2 * (1.0f / HD) - mean * mean;
        const float rstd = rsqrtf(var + 1e-5f);
        const float y0 = (xv.x - mean) * rstd * lg2.x + lb2.x;
        const float y1 = (xv.y - mean) * rstd * lg2.y + lb2.y;
        *(float2*)(yb + t0) = make_float2(y0, y1);

        float yr[32];
        {
            const float4* yp = (const float4*)(yb + h * HH);
            #pragma unroll
            for (int q = 0; q < 8; ++q) {
                const float4 v = yp[q];
                yr[q*4+0] = v.x; yr[q*4+1] = v.y; yr[q*4+2] = v.z; yr[q*4+3] = v.w;
            }
        }
        float ak0=0,ak1=0,aq0=0,aq1=0,av0=0,av1=0;
        {
            const float4* kr0 = (const float4*)(k_w + (size_t)t0 * HH);
            const float4* kr1 = (const float4*)(k_w + (size_t)(t0+1) * HH);
            const float4* qr0 = (const float4*)(q_w + (size_t)t0 * HH);
            const float4* qr1 = (const float4*)(q_w + (size_t)(t0+1) * HH);
            const float4* vr0 = (const float4*)(v_w + (size_t)t0 * HH);
            const float4* vr1 = (const float4*)(v_w + (size_t)(t0+1) * HH);
            #pragma unroll
            for (int q = 0; q < 8; ++q) {
                const float4 a = kr0[q], b = kr1[q], c = qr0[q], d = qr1[q];
                const float4 e = vr0[q], f = vr1[q];
                ak0 = fmaf(yr[q*4+0], a.x, ak0); ak0 = fmaf(yr[q*4+1], a.y, ak0);
                ak0 = fmaf(yr[q*4+2], a.z, ak0); ak0 = fmaf(yr[q*4+3], a.w, ak0);
                ak1 = fmaf(yr[q*4+0], b.x, ak1); ak1 = fmaf(yr[q*4+1], b.y, ak1);
                ak1 = fmaf(yr[q*4+2], b.z, ak1); ak1 = fmaf(yr[q*4+3], b.w, ak1);
                aq0 = fmaf(yr[q*4+0], c.x, aq0); aq0 = fmaf(yr[q*4+1], c.y, aq0);
                aq0 = fmaf(yr[q*4+2], c.z, aq0); aq0 = fmaf(yr[q*4+3], c.w, aq0);
                aq1 = fmaf(yr[q*4+0], d.x, aq1); aq1 = fmaf(yr[q*4+1], d.y, aq1);
                aq1 = fmaf(yr[q*4+2], d.z, aq1); aq1 = fmaf(yr[q*4+3], d.w, aq1);
                av0 = fmaf(yr[q*4+0], e.x, av0); av0 = fmaf(yr[q*4+1], e.y, av0);
                av0 = fmaf(yr[q*4+2], e.z, av0); av0 = fmaf(yr[q*4+3], e.w, av0);
                av1 = fmaf(yr[q*4+0], f.x, av1); av1 = fmaf(yr[q*4+1], f.y, av1);
                av1 = fmaf(yr[q*4+2], f.z, av1); av1 = fmaf(yr[q*4+3], f.w, av1);
            }
        }
        hk_bf[(size_t)n * 64 + l] = pk2(ak0, ak1);
        hv_bf[(size_t)n * 64 + l] = pk2(av0, av1);

        *(float2*)(yb + t0) = make_float2(aq0, aq1);
        float hqr[32];
        {
            const float4* hp = (const float4*)(yb + h * HH);
            #pragma unroll
            for (int q = 0; q < 8; ++q) {
                const float4 v = hp[q];
                hqr[q*4+0] = v.x; hqr[q*4+1] = v.y; hqr[q*4+2] = v.z; hqr[q*4+3] = v.w;
            }
        }
        float p = aq0 * wb2.x + aq1 * wb2.y;
        #pragma unroll
        for (int off = 1; off < 16; off <<= 1) p += __shfl_xor(p, off);
        if (i16 == 0) c0_out[n * NHD + h] = p;

        const int k0 = 2 * i16;
        float g0 = 0.f, g1 = 0.f;
        {
            const float4* w0 = (const float4*)(wklT + k0 * 36);
            const float4* w1 = (const float4*)(wklT + (k0 + 1) * 36);
            #pragma unroll
            for (int q = 0; q < 8; ++q) {
                const float4 a = w0[q], b = w1[q];
                g0 = fmaf(hqr[q*4+0], a.x, g0); g0 = fmaf(hqr[q*4+1], a.y, g0);
                g0 = fmaf(hqr[q*4+2], a.z, g0); g0 = fmaf(hqr[q*4+3], a.w, g0);
                g1 = fmaf(hqr[q*4+0], b.x, g1); g1 = fmaf(hqr[q*4+1], b.y, g1);
                g1 = fmaf(hqr[q*4+2], b.z, g1); g1 = fmaf(hqr[q*4+3], b.w, g1);
            }
        }
        g_bf[(size_t)n * 64 + l] = pk2(g0, g1);
    }
}

// ---------------- CSR build ----------------
__global__ __launch_bounds__(256) void k_deg(
    const int* __restrict__ edge_index, int* __restrict__ deg)
{
    for (int e = blockIdx.x * blockDim.x + threadIdx.x; e < EE;
         e += gridDim.x * blockDim.x)
        atomicAdd(&deg[edge_index[e]], 1);
}

__global__ __launch_bounds__(SCAN_B) void k_scan_block(
    const int* __restrict__ deg, int* __restrict__ base, int* __restrict__ bsum)
{
    const int i = blockIdx.x * SCAN_B + threadIdx.x;
    const int v = (i < NN) ? deg[i] : 0;
    __shared__ int s[SCAN_B];
    s[threadIdx.x] = v;
    __syncthreads();
    for (int off = 1; off < SCAN_B; off <<= 1) {
        int t = (threadIdx.x >= off) ? s[threadIdx.x - off] : 0;
        __syncthreads();
        s[threadIdx.x] += t;
        __syncthreads();
    }
    if (i < NN) base[i] = s[threadIdx.x] - v;
    if (threadIdx.x == SCAN_B - 1) bsum[blockIdx.x] = s[SCAN_B - 1];
}

__global__ __launch_bounds__(SCAN_B) void k_scan_top(int* __restrict__ bsum)
{
    const int i = threadIdx.x;
    const int v = (i < NBLK) ? bsum[i] : 0;
    __shared__ int s[SCAN_B];
    s[i] = v;
    __syncthreads();
    for (int off = 1; off < SCAN_B; off <<= 1) {
        int t = (i >= off) ? s[i - off] : 0;
        __syncthreads();
        s[i] += t;
        __syncthreads();
    }
    if (i < NBLK) bsum[i] = s[i] - v;
}

__global__ __launch_bounds__(SCAN_B) void k_scan_add(
    int* __restrict__ base, const int* __restrict__ bsum, int* __restrict__ cursor)
{
    const int i = blockIdx.x * SCAN_B + threadIdx.x;
    if (i < NN) {
        const int b = base[i] + bsum[i >> 8];
        base[i] = b;
        cursor[i] = b;
    }
}

__global__ __launch_bounds__(256) void k_scatter(
    const int* __restrict__ edge_index, int* __restrict__ cursor,
    int* __restrict__ eidx, int* __restrict__ rowv, int* __restrict__ colv)
{
    for (int e = blockIdx.x * blockDim.x + threadIdx.x; e < EE;
         e += gridDim.x * blockDim.x) {
        const int r = edge_index[e];
        const int pos = atomicAdd(&cursor[r], 1);
        eidx[pos] = e;
        rowv[pos] = r;
        colv[pos] = edge_index[EE + e];
    }
}

// ---------------- ea -> bf16, permuted to CSR order (grid-stride) ----------
__global__ __launch_bounds__(256) void k_ea_csr(
    const float* __restrict__ ea, const int* __restrict__ eidx,
    unsigned* __restrict__ ea_bf)
{
    for (int i = blockIdx.x * 256 + threadIdx.x; i < EE * 32;
         i += 2048 * 256) {
        const int pos = i >> 5, u = i & 31;
        const int e = eidx[pos];
        const float2 v = *(const float2*)(ea + (size_t)e * ECD + u * 2);
        ea_bf[(size_t)pos * 32 + u] = pk2(v.x, v.y);
    }
}

// ---------------- weight fragment packer (1 block) ----------------
// frag slots (each 64 lanes x uint4): 0-3 = MLP1-K (kt*2+nt), 4-5 = MLP2-K (nt),
// 6-9 = MLP1-V, 10-11 = MLP2-V.
// B-fragment convention: lane l, bf16 slot j (0..7):  B[k = kbase + (l>>4)*8 + j][n = nt*16 + (l&15)]
// where weights W[out][in] give B[k=in][n=out].
__global__ __launch_bounds__(256) void k_wfrag(
    const float* __restrict__ wk1_w, const float* __restrict__ wk2_w,
    const float* __restrict__ wv1_w, const float* __restrict__ wv2_w,
    uint4* __restrict__ frag)
{
    const int t = threadIdx.x;
    const int l = t & 63;
    const int lm = l & 15, lg = l >> 4;
    {
        const int f = t >> 6;          // 0..3
        const int kt = f >> 1, nt = f & 1;
        const int out = nt * 16 + lm;
        uint4 a, b;
        unsigned ra[4], rb[4];
        #pragma unroll
        for (int p = 0; p < 4; ++p) {
            const int in0 = kt * 32 + lg * 8 + 2 * p;
            ra[p] = pk2(wk1_w[(size_t)out * ECD + in0], wk1_w[(size_t)out * ECD + in0 + 1]);
            rb[p] = pk2(wv1_w[(size_t)out * ECD + in0], wv1_w[(size_t)out * ECD + in0 + 1]);
        }
        a.x = ra[0]; a.y = ra[1]; a.z = ra[2]; a.w = ra[3];
        b.x = rb[0]; b.y = rb[1]; b.z = rb[2]; b.w = rb[3];
        frag[f * 64 + l] = a;
        frag[(6 + f) * 64 + l] = b;
    }
    if (t < 128) {
        const int nt = t >> 6;
        const int out = nt * 16 + lm;
        uint4 a, b;
        unsigned ra[4], rb[4];
        #pragma unroll
        for (int p = 0; p < 4; ++p) {
            const int in0 = lg * 8 + 2 * p;
            ra[p] = pk2(wk2_w[(size_t)out * HH + in0], wk2_w[(size_t)out * HH + in0 + 1]);
            rb[p] = pk2(wv2_w[(size_t)out * HH + in0], wv2_w[(size_t)out * HH + in0 + 1]);
        }
        a.x = ra[0]; a.y = ra[1]; a.z = ra[2]; a.w = ra[3];
        b.x = rb[0]; b.y = rb[1]; b.z = rb[2]; b.w = rb[3];
        frag[(4 + nt) * 64 + l] = a;
        frag[(10 + nt) * 64 + l] = b;
    }
}

// ---------------- K2: MFMA edge kernel (wave = 64 edges) --------------------
__global__ __launch_bounds__(256) void k_edge_mfma(
    const unsigned* __restrict__ ea_bf,
    const int* __restrict__ rowv, const int* __restrict__ colv,
    const unsigned* __restrict__ hk_bf, const unsigned* __restrict__ g_bf,
    const float* __restrict__ c0_in, const uint4* __restrict__ frag,
    const float* __restrict__ wk1_b, const float* __restrict__ wk2_b,
    const float* __restrict__ wv1_b, const float* __restrict__ wv2_b,
    float* __restrict__ qkP, unsigned* __restrict__ wvP)
{
    __shared__ float lds[4][64 * LSTR];
    const int w = threadIdx.x >> 6, l = threadIdx.x & 63;
    const int lm = l & 15, lg = l >> 4;
    float* L = lds[w];
    const int e0 = blockIdx.x * 256 + w * 64;
    const int pos = e0 + l;
    const int row = rowv[pos];
    const int col = colv[pos];

    // A fragments of ea, reused by both MLP1s. lane: rows (e0+mt*16+lm), k-slots lg*8+j
    uint4 eaf[4][2];
    #pragma unroll
    for (int mt = 0; mt < 4; ++mt)
        #pragma unroll
        for (int kt = 0; kt < 2; ++kt)
            eaf[mt][kt] = *(const uint4*)(ea_bf +
                (size_t)(e0 + mt * 16 + lm) * 32 + kt * 16 + lg * 4);

    // ================= K path =================
    {
        const float b1a = wk1_b[lm], b1b = wk1_b[16 + lm];
        f32x4 acc[4][2];
        #pragma unroll
        for (int mt = 0; mt < 4; ++mt) {
            acc[mt][0] = f32x4{b1a, b1a, b1a, b1a};
            acc[mt][1] = f32x4{b1b, b1b, b1b, b1b};
        }
        const uint4 f00 = frag[0 * 64 + l], f01 = frag[1 * 64 + l];
        const uint4 f10 = frag[2 * 64 + l], f11 = frag[3 * 64 + l];
        #pragma unroll
        for (int mt = 0; mt < 4; ++mt) {
            acc[mt][0] = __builtin_amdgcn_mfma_f32_16x16x32_bf16(as_bf(eaf[mt][0]), as_bf(f00), acc[mt][0], 0, 0, 0);
            acc[mt][1] = __builtin_amdgcn_mfma_f32_16x16x32_bf16(as_bf(eaf[mt][0]), as_bf(f01), acc[mt][1], 0, 0, 0);
            acc[mt][0] = __builtin_amdgcn_mfma_f32_16x16x32_bf16(as_bf(eaf[mt][1]), as_bf(f10), acc[mt][0], 0, 0, 0);
            acc[mt][1] = __builtin_amdgcn_mfma_f32_16x16x32_bf16(as_bf(eaf[mt][1]), as_bf(f11), acc[mt][1], 0, 0, 0);
        }
        // ssp + stage t1 (D: row=edge=mt*16+lg*4+r, col=out=nt*16+lm)
        #pragma unroll
        for (int mt = 0; mt < 4; ++mt)
            #pragma unroll
            for (int nt = 0; nt < 2; ++nt)
                #pragma unroll
                for (int r = 0; r < 4; ++r)
                    L[(mt * 16 + lg * 4 + r) * LSTR + nt * 16 + lm] = ssp_f(acc[mt][nt][r]);

        // MLP2-K
        const float b2a = wk2_b[lm], b2b = wk2_b[16 + lm];
        f32x4 acc2[4][2];
        const uint4 f20 = frag[4 * 64 + l], f21 = frag[5 * 64 + l];
        #pragma unroll
        for (int mt = 0; mt < 4; ++mt) {
            acc2[mt][0] = f32x4{b2a, b2a, b2a, b2a};
            acc2[mt][1] = f32x4{b2b, b2b, b2b, b2b};
            float av[8];
            #pragma unroll
            for (int j = 0; j < 8; ++j)
                av[j] = L[(mt * 16 + lm) * LSTR + lg * 8 + j];
            uint4 a2;
            a2.x = pk2(av[0], av[1]); a2.y = pk2(av[2], av[3]);
            a2.z = pk2(av[4], av[5]); a2.w = pk2(av[6], av[7]);
            acc2[mt][0] = __builtin_amdgcn_mfma_f32_16x16x32_bf16(as_bf(a2), as_bf(f20), acc2[mt][0], 0, 0, 0);
            acc2[mt][1] = __builtin_amdgcn_mfma_f32_16x16x32_bf16(as_bf(a2), as_bf(f21), acc2[mt][1], 0, 0, 0);
        }
        // stage Wk (f32)
        #pragma unroll
        for (int mt = 0; mt < 4; ++mt)
            #pragma unroll
            for (int nt = 0; nt < 2; ++nt)
                #pragma unroll
                for (int r = 0; r < 4; ++r)
                    L[(mt * 16 + lg * 4 + r) * LSTR + nt * 16 + lm] = acc2[mt][nt][r];
    }

    // per-edge Wk into registers
    float wk[32];
    #pragma unroll
    for (int j = 0; j < 32; ++j) wk[j] = L[l * LSTR + j];

    // qk[h] = c0[h] + sum_k Wk[k] * hk[col,h,k] * g[row,h,k]
    {
        const uint4* hkp = (const uint4*)(hk_bf + (size_t)col * 64);
        const uint4* gp  = (const uint4*)(g_bf  + (size_t)row * 64);
        const float4 c0v = *(const float4*)(c0_in + (size_t)row * NHD);
        #pragma unroll
        for (int h = 0; h < NHD; ++h) {
            float s = 0.f;
            #pragma unroll
            for (int q = 0; q < 4; ++q) {
                const uint4 ku = hkp[h * 4 + q];
                const uint4 gu = gp[h * 4 + q];
                float ka, kb, ga, gb;
                unp2(ku.x, ka, kb); unp2(gu.x, ga, gb);
                s = fmaf(wk[q * 8 + 0] * ka, ga, s);
                s = fmaf(wk[q * 8 + 1] * kb, gb, s);
                unp2(ku.y, ka, kb); unp2(gu.y, ga, gb);
                s = fmaf(wk[q * 8 + 2] * ka, ga, s);
                s = fmaf(wk[q * 8 + 3] * kb, gb, s);
                unp2(ku.z, ka, kb); unp2(gu.z, ga, gb);
                s = fmaf(wk[q * 8 + 4] * ka, ga, s);
                s = fmaf(wk[q * 8 + 5] * kb, gb, s);
                unp2(ku.w, ka, kb); unp2(gu.w, ga, gb);
                s = fmaf(wk[q * 8 + 6] * ka, ga, s);
                s = fmaf(wk[q * 8 + 7] * kb, gb, s);
            }
            const float c0h = (h == 0) ? c0v.x : (h == 1) ? c0v.y : (h == 2) ? c0v.z : c0v.w;
            qkP[(size_t)h * EE + pos] = s + c0h;
        }
    }

    // ================= V path =================
    {
        const float b1a = wv1_b[lm], b1b = wv1_b[16 + lm];
        f32x4 acc[4][2];
        #pragma unroll
        for (int mt = 0; mt < 4; ++mt) {
            acc[mt][0] = f32x4{b1a, b1a, b1a, b1a};
            acc[mt][1] = f32x4{b1b, b1b, b1b, b1b};
        }
        const uint4 f00 = frag[6 * 64 + l], f01 = frag[7 * 64 + l];
        const uint4 f10 = frag[8 * 64 + l], f11 = frag[9 * 64 + l];
        #pragma unroll
        for (int mt = 0; mt < 4; ++mt) {
            acc[mt][0] = __builtin_amdgcn_mfma_f32_16x16x32_bf16(as_bf(eaf[mt][0]), as_bf(f00), acc[mt][0], 0, 0, 0);
            acc[mt][1] = __builtin_amdgcn_mfma_f32_16x16x32_bf16(as_bf(eaf[mt][0]), as_bf(f01), acc[mt][1], 0, 0, 0);
            acc[mt][0] = __builtin_amdgcn_mfma_f32_16x16x32_bf16(as_bf(eaf[mt][1]), as_bf(f10), acc[mt][0], 0, 0, 0);
            acc[mt][1] = __builtin_amdgcn_mfma_f32_16x16x32_bf16(as_bf(eaf[mt][1]), as_bf(f11), acc[mt][1], 0, 0, 0);
        }
        #pragma unroll
        for (int mt = 0; mt < 4; ++mt)
            #pragma unroll
            for (int nt = 0; nt < 2; ++nt)
                #pragma unroll
                for (int r = 0; r < 4; ++r)
                    L[(mt * 16 + lg * 4 + r) * LSTR + nt * 16 + lm] = ssp_f(acc[mt][nt][r]);

        const float b2a = wv2_b[lm], b2b = wv2_b[16 + lm];
        f32x4 acc2[4][2];
        const uint4 f20 = frag[10 * 64 + l], f21 = frag[11 * 64 + l];
        #pragma unroll
        for (int mt = 0; mt < 4; ++mt) {
            acc2[mt][0] = f32x4{b2a, b2a, b2a, b2a};
            acc2[mt][1] = f32x4{b2b, b2b, b2b, b2b};
            float av[8];
            #pragma unroll
            for (int j = 0; j < 8; ++j)
                av[j] = L[(mt * 16 + lm) * LSTR + lg * 8 + j];
            uint4 a2;
            a2.x = pk2(av[0], av[1]); a2.y = pk2(av[2], av[3]);
            a2.z = pk2(av[4], av[5]); a2.w = pk2(av[6], av[7]);
            acc2[mt][0] = __builtin_amdgcn_mfma_f32_16x16x32_bf16(as_bf(a2), as_bf(f20), acc2[mt][0], 0, 0, 0);
            acc2[mt][1] = __builtin_amdgcn_mfma_f32_16x16x32_bf16(as_bf(a2), as_bf(f21), acc2[mt][1], 0, 0, 0);
        }
        #pragma unroll
        for (int mt = 0; mt < 4; ++mt)
            #pragma unroll
            for (int nt = 0; nt < 2; ++nt)
                #pragma unroll
                for (int r = 0; r < 4; ++r)
                    L[(mt * 16 + lg * 4 + r) * LSTR + nt * 16 + lm] = acc2[mt][nt][r];
    }

    // coalesced Wv pack+store: flat uint f = pos_rel*16 + i
    #pragma unroll
    for (int k = 0; k < 16; ++k) {
        const int f = k * 64 + l;
        const int pr = f >> 4, i = f & 15;
        wvP[(size_t)e0 * 16 + f] = pk2(L[pr * LSTR + 2 * i], L[pr * LSTR + 2 * i + 1]);
    }
}

// ---------------- K3: wave-per-node softmax+aggregate+LN2+out (persistent) --
__global__ __launch_bounds__(256) void k_node_fin(
    const float* __restrict__ x, const float* __restrict__ qkP,
    const unsigned* __restrict__ wvP, const unsigned* __restrict__ hv_bf,
    const int* __restrict__ colv,
    const int* __restrict__ base, const int* __restrict__ deg,
    const float* __restrict__ wvl_w, const float* __restrict__ wvl_b,
    const float* __restrict__ out_w, const float* __restrict__ out_b,
    const float* __restrict__ ln2_g, const float* __restrict__ ln2_b,
    float* __restrict__ out)
{
    __shared__ float su[4][HD];
    const int w = threadIdx.x >> 6, l = threadIdx.x & 63;
    const int h = l >> 4, i = l & 15;
    const int t0 = 2 * l;
    const float2 lg2 = *(const float2*)(ln2_g + t0);
    const float2 lb2 = *(const float2*)(ln2_b + t0);
    const float2 ob2 = *(const float2*)(out_b + t0);
    const int j0 = 2 * i;
    float* sb = su[w];

    for (int n = blockIdx.x * 4 + w; n < NN; n += 2048 * 4) {
        const int b0 = base[n];
        const int dn = deg[n];
        const float2 xv = *(const float2*)(x + (size_t)n * HD + t0);

        float acc0 = 0.f, acc1 = 0.f;
        if (dn > 0) {
            const float* qkh = qkP + (size_t)h * EE + b0;
            const int emax = b0 + dn - 1;
            float m = -3.0e38f;
            for (int c = i; c < dn; c += 16) m = fmaxf(m, qkh[c]);
            #pragma unroll
            for (int off = 1; off < 16; off <<= 1)
                m = fmaxf(m, __shfl_xor(m, off));
            float den = 0.f;
            for (int c = i; c < dn; c += 16) den += __expf(qkh[c] - m);
            #pragma unroll
            for (int off = 1; off < 16; off <<= 1) den += __shfl_xor(den, off);
            const float rden = (den > 0.f) ? 1.0f / den : 0.f;
            for (int c0 = 0; c0 < dn; c0 += 16) {
                const int tn = (dn - c0 < 16) ? (dn - c0) : 16;
                float ex = 0.f; int cq = 0;
                if (i < tn) {
                    ex = __expf(qkh[c0 + i] - m) * rden;
                    cq = colv[b0 + c0 + i];
                }
                const int t4 = (tn + 3) & ~3;
                for (int i2 = 0; i2 < t4; i2 += 4) {
                    #pragma unroll
                    for (int u = 0; u < 4; ++u) {
                        const int src = (l & 48) | (i2 + u);
                        const float wgt = __shfl(ex, src);
                        const int ce = __shfl(cq, src);
                        int ep = b0 + c0 + i2 + u;
                        ep = (ep > emax) ? emax : ep;
                        const unsigned hvv = hv_bf[(size_t)ce * 64 + l];
                        const unsigned wvv = wvP[(size_t)ep * 16 + i];
                        float ha, hb, wa, wb;
                        unp2(hvv, ha, hb); unp2(wvv, wa, wb);
                        acc0 = fmaf(wgt, wa * ha, acc0);
                        acc1 = fmaf(wgt, wb * hb, acc1);
                    }
                }
            }
        }

        *(float2*)(sb + t0) = make_float2(acc0, acc1);
        float uh[32];
        {
            const float4* up = (const float4*)(sb + h * HH);
            #pragma unroll
            for (int q = 0; q < 8; ++q) {
                const float4 v = up[q];
                uh[q*4+0] = v.x; uh[q*4+1] = v.y; uh[q*4+2] = v.z; uh[q*4+3] = v.w;
            }
        }
        float ag0 = 0.f, ag1 = 0.f;
        if (dn > 0) {
            const float2 wb = *(const float2*)(wvl_b + j0);
            ag0 = wb.x; ag1 = wb.y;
            const float4* r0 = (const float4*)(wvl_w + (size_t)j0 * HH);
            const float4* r1 = (const float4*)(wvl_w + (size_t)(j0 + 1) * HH);
            #pragma unroll
            for (int q = 0; q < 8; ++q) {
                const float4 a = r0[q], b = r1[q];
                ag0 = fmaf(uh[q*4+0], a.x, ag0); ag0 = fmaf(uh[q*4+1], a.y, ag0);
                ag0 = fmaf(uh[q*4+2], a.z, ag0); ag0 = fmaf(uh[q*4+3], a.w, ag0);
                ag1 = fmaf(uh[q*4+0], b.x, ag1); ag1 = fmaf(uh[q*4+1], b.y, ag1);
                ag1 = fmaf(uh[q*4+2], b.z, ag1); ag1 = fmaf(uh[q*4+3], b.w, ag1);
            }
        }
        const float x20 = ag0 + xv.x;
        const float x21 = ag1 + xv.y;

        float s1 = x20 + x21, s2 = x20 * x20 + x21 * x21;
        #pragma unroll
        for (int off = 1; off < 64; off <<= 1) {
            s1 += __shfl_xor(s1, off);
            s2 += __shfl_xor(s2, off);
        }
        const float mean = s1 * (1.0f / HD);
        const float var  = s2 * (1.0f / HD) - mean * mean;
        const float rstd = rsqrtf(var + 1e-5f);
        const float ss0 = ssp_f((x20 - mean) * rstd * lg2.x + lb2.x);
        const float ss1 = ssp_f((x21 - mean) * rstd * lg2.y + lb2.y);

        *(float2*)(sb + t0) = make_float2(ss0, ss1);
        float o0 = ob2.x + x20, o1 = ob2.y + x21;
        const float4* wr0 = (const float4*)(out_w + (size_t)t0 * HD);
        const float4* wr1 = (const float4*)(out_w + (size_t)(t0 + 1) * HD);
        #pragma unroll
        for (int c = 0; c < 4; ++c) {
            float sv[32];
            const float4* sp = (const float4*)(sb + c * 32);
            #pragma unroll
            for (int q = 0; q < 8; ++q) {
                const float4 v = sp[q];
                sv[q*4+0] = v.x; sv[q*4+1] = v.y; sv[q*4+2] = v.z; sv[q*4+3] = v.w;
            }
            #pragma unroll
            for (int q = 0; q < 8; ++q) {
                const float4 a = wr0[c * 8 + q], b = wr1[c * 8 + q];
                o0 = fmaf(sv[q*4+0], a.x, o0); o0 = fmaf(sv[q*4+1], a.y, o0);
                o0 = fmaf(sv[q*4+2], a.z, o0); o0 = fmaf(sv[q*4+3], a.w, o0);
                o1 = fmaf(sv[q*4+0], b.x, o1); o1 = fmaf(sv[q*4+1], b.y, o1);
                o1 = fmaf(sv[q*4+2], b.z, o1); o1 = fmaf(sv[q*4+3], b.w, o1);
            }
        }
        *(float2*)(out + (size_t)n * HD + t0) = make_float2(o0, o1);
    }
}

extern "C" void kernel_launch(void* const* d_in, const int* in_sizes, int n_in,
                              void* d_out, int out_size, void* d_ws, size_t ws_size,
                              hipStream_t stream) {
    const float* x         = (const float*)d_in[0];
    const float* edge_attr = (const float*)d_in[1];
    const int*   edge_index= (const int*)  d_in[2];
    const float* k_w   = (const float*)d_in[3];
    const float* q_w   = (const float*)d_in[4];
    const float* v_w   = (const float*)d_in[5];
    const float* wk1_w = (const float*)d_in[6];
    const float* wk1_b = (const float*)d_in[7];
    const float* wk2_w = (const float*)d_in[8];
    const float* wk2_b = (const float*)d_in[9];
    const float* wkl_w = (const float*)d_in[10];
    const float* wkl_b = (const float*)d_in[11];
    const float* wv1_w = (const float*)d_in[12];
    const float* wv1_b = (const float*)d_in[13];
    const float* wv2_w = (const float*)d_in[14];
    const float* wv2_b = (const float*)d_in[15];
    const float* wvl_w = (const float*)d_in[16];
    const float* wvl_b = (const float*)d_in[17];
    const float* out_w = (const float*)d_in[18];
    const float* out_b = (const float*)d_in[19];
    const float* ln1_g = (const float*)d_in[20];
    const float* ln1_b = (const float*)d_in[21];
    const float* ln2_g = (const float*)d_in[22];
    const float* ln2_b = (const float*)d_in[23];

    char* ws = (char*)d_ws;
    unsigned* hk_bf = (unsigned*)ws;            ws += (size_t)NN * 64 * 4;
    unsigned* hv_bf = (unsigned*)ws;            ws += (size_t)NN * 64 * 4;
    unsigned* g_bf  = (unsigned*)ws;            ws += (size_t)NN * 64 * 4;
    float* c0  = (float*)ws;                    ws += (size_t)NN * NHD * 4;
    float* qkP = (float*)ws;                    ws += (size_t)NHD * EE * 4;
    unsigned* wvP = (unsigned*)ws;              ws += (size_t)EE * 16 * 4;
    unsigned* ea_bf = (unsigned*)ws;            ws += (size_t)EE * 32 * 4;
    uint4* fragbuf = (uint4*)ws;                ws += (size_t)12 * 64 * 16;
    int* deg    = (int*)ws;                     ws += (size_t)NN * 4;
    int* base   = (int*)ws;                     ws += (size_t)NN * 4;
    int* cursor = (int*)ws;                     ws += (size_t)NN * 4;
    int* bsum   = (int*)ws;                     ws += (size_t)SCAN_B * 4;
    int* eidx   = (int*)ws;                     ws += (size_t)EE * 4;
    int* rowv   = (int*)ws;                     ws += (size_t)EE * 4;
    int* colv   = (int*)ws;                     ws += (size_t)EE * 4;

    (void)hipMemsetAsync(deg, 0, (size_t)NN * 4, stream);

    k_wfrag<<<1, 256, 0, stream>>>(wk1_w, wk2_w, wv1_w, wv2_w, fragbuf);
    k_node_prep<<<1024, 256, 0, stream>>>(x, k_w, q_w, v_w, wkl_w, wkl_b,
        ln1_g, ln1_b, hk_bf, hv_bf, g_bf, c0);
    k_deg<<<1024, 256, 0, stream>>>(edge_index, deg);
    k_scan_block<<<NBLK, SCAN_B, 0, stream>>>(deg, base, bsum);
    k_scan_top<<<1, SCAN_B, 0, stream>>>(bsum);
    k_scan_add<<<NBLK, SCAN_B, 0, stream>>>(base, bsum, cursor);
    k_scatter<<<1024, 256, 0, stream>>>(edge_index, cursor, eidx, rowv, colv);
    k_ea_csr<<<2048, 256, 0, stream>>>(edge_attr, eidx, ea_bf);
    k_edge_mfma<<<EE / 256, 256, 0, stream>>>(ea_bf, rowv, colv,
        hk_bf, g_bf, c0, fragbuf,
        wk1_b, wk2_b, wv1_b, wv2_b, qkP, wvP);
    k_node_fin<<<2048, 256, 0, stream>>>(x, qkP, wvP, hv_bf, colv,
        base, deg, wvl_w, wvl_b, out_w, out_b, ln2_g, ln2_b, (float*)d_out);
}

// Round 9
// 649.648 us; speedup vs baseline: 4.8126x; 1.1669x over previous
//
#include <hip/hip_runtime.h>
#include <math.h>

#define NN 50000
#define EE 640000
#define HD 128
#define ECD 64
#define NHD 4
#define HH 32
#define SCAN_B 256
#define NBLK ((NN + SCAN_B - 1) / SCAN_B)   // 196
#define LSTR 33   // LDS row stride in floats (64 edges x 32 vals, +1 pad)

typedef short bf16x8 __attribute__((ext_vector_type(8)));
typedef float f32x4 __attribute__((ext_vector_type(4)));

__device__ __forceinline__ float ssp_f(float v) {
    return fmaxf(v, 0.0f) + log1pf(__expf(-fabsf(v))) - 0.69314718055994531f;
}
__device__ __forceinline__ unsigned f2bf_u(float f) {
    unsigned u = __float_as_uint(f);
    unsigned r = ((u >> 16) & 1u) + 0x7FFFu;
    return (u + r) >> 16;
}
__device__ __forceinline__ unsigned pk2(float a, float b) {
    return f2bf_u(a) | (f2bf_u(b) << 16);
}
__device__ __forceinline__ void unp2(unsigned u, float& a, float& b) {
    a = __uint_as_float(u << 16);
    b = __uint_as_float(u & 0xffff0000u);
}
__device__ __forceinline__ bf16x8 as_bf(uint4 u) {
    union { uint4 a; bf16x8 b; } c; c.a = u; return c.b;
}

// ---------------- K1: LN1 + projections + g/c0 (wave-per-node, persistent) ----
__global__ __launch_bounds__(256) void k_node_prep(
    const float* __restrict__ x, const float* __restrict__ k_w,
    const float* __restrict__ q_w, const float* __restrict__ v_w,
    const float* __restrict__ wkl_w, const float* __restrict__ wkl_b,
    const float* __restrict__ ln1_g, const float* __restrict__ ln1_b,
    unsigned* __restrict__ hk_bf, unsigned* __restrict__ hv_bf,
    unsigned* __restrict__ g_bf, float* __restrict__ c0_out)
{
    __shared__ float wklT[HH * 36];
    __shared__ float ybuf[4][HD];
    for (int idx = threadIdx.x; idx < HH * HH; idx += 256)
        wklT[(idx & 31) * 36 + (idx >> 5)] = wkl_w[idx];
    __syncthreads();

    const int w = threadIdx.x >> 6, l = threadIdx.x & 63;
    const int h = l >> 4, i16 = l & 15;
    const int t0 = 2 * l;
    const float2 lg2 = *(const float2*)(ln1_g + t0);
    const float2 lb2 = *(const float2*)(ln1_b + t0);
    const float2 wb2 = *(const float2*)(wkl_b + 2 * i16);
    float* yb = ybuf[w];

    for (int n = blockIdx.x * 4 + w; n < NN; n += 1024 * 4) {
        const float2 xv = *(const float2*)(x + (size_t)n * HD + t0);
        float s1 = xv.x + xv.y;
        float s2 = xv.x * xv.x + xv.y * xv.y;
        #pragma unroll
        for (int off = 1; off < 64; off <<= 1) {
            s1 += __shfl_xor(s1, off);
            s2 += __shfl_xor(s2, off);
        }
        const float mean = s1 * (1.0f / HD);
        const float var  = s2 * (1.0f / HD) - mean * mean;
        const float rstd = rsqrtf(var + 1e-5f);
        const float y0 = (xv.x - mean) * rstd * lg2.x + lb2.x;
        const float y1 = (xv.y - mean) * rstd * lg2.y + lb2.y;
        *(float2*)(yb + t0) = make_float2(y0, y1);

        float yr[32];
        {
            const float4* yp = (const float4*)(yb + h * HH);
            #pragma unroll
            for (int q = 0; q < 8; ++q) {
                const float4 v = yp[q];
                yr[q*4+0] = v.x; yr[q*4+1] = v.y; yr[q*4+2] = v.z; yr[q*4+3] = v.w;
            }
        }
        float ak0=0,ak1=0,aq0=0,aq1=0,av0=0,av1=0;
        {
            const float4* kr0 = (const float4*)(k_w + (size_t)t0 * HH);
            const float4* kr1 = (const float4*)(k_w + (size_t)(t0+1) * HH);
            const float4* qr0 = (const float4*)(q_w + (size_t)t0 * HH);
            const float4* qr1 = (const float4*)(q_w + (size_t)(t0+1) * HH);
            const float4* vr0 = (const float4*)(v_w + (size_t)t0 * HH);
            const float4* vr1 = (const float4*)(v_w + (size_t)(t0+1) * HH);
            #pragma unroll
            for (int q = 0; q < 8; ++q) {
                const float4 a = kr0[q], b = kr1[q], c = qr0[q], d = qr1[q];
                const float4 e = vr0[q], f = vr1[q];
                ak0 = fmaf(yr[q*4+0], a.x, ak0); ak0 = fmaf(yr[q*4+1], a.y, ak0);
                ak0 = fmaf(yr[q*4+2], a.z, ak0); ak0 = fmaf(yr[q*4+3], a.w, ak0);
                ak1 = fmaf(yr[q*4+0], b.x, ak1); ak1 = fmaf(yr[q*4+1], b.y, ak1);
                ak1 = fmaf(yr[q*4+2], b.z, ak1); ak1 = fmaf(yr[q*4+3], b.w, ak1);
                aq0 = fmaf(yr[q*4+0], c.x, aq0); aq0 = fmaf(yr[q*4+1], c.y, aq0);
                aq0 = fmaf(yr[q*4+2], c.z, aq0); aq0 = fmaf(yr[q*4+3], c.w, aq0);
                aq1 = fmaf(yr[q*4+0], d.x, aq1); aq1 = fmaf(yr[q*4+1], d.y, aq1);
                aq1 = fmaf(yr[q*4+2], d.z, aq1); aq1 = fmaf(yr[q*4+3], d.w, aq1);
                av0 = fmaf(yr[q*4+0], e.x, av0); av0 = fmaf(yr[q*4+1], e.y, av0);
                av0 = fmaf(yr[q*4+2], e.z, av0); av0 = fmaf(yr[q*4+3], e.w, av0);
                av1 = fmaf(yr[q*4+0], f.x, av1); av1 = fmaf(yr[q*4+1], f.y, av1);
                av1 = fmaf(yr[q*4+2], f.z, av1); av1 = fmaf(yr[q*4+3], f.w, av1);
            }
        }
        hk_bf[(size_t)n * 64 + l] = pk2(ak0, ak1);
        hv_bf[(size_t)n * 64 + l] = pk2(av0, av1);

        *(float2*)(yb + t0) = make_float2(aq0, aq1);
        float hqr[32];
        {
            const float4* hp = (const float4*)(yb + h * HH);
            #pragma unroll
            for (int q = 0; q < 8; ++q) {
                const float4 v = hp[q];
                hqr[q*4+0] = v.x; hqr[q*4+1] = v.y; hqr[q*4+2] = v.z; hqr[q*4+3] = v.w;
            }
        }
        float p = aq0 * wb2.x + aq1 * wb2.y;
        #pragma unroll
        for (int off = 1; off < 16; off <<= 1) p += __shfl_xor(p, off);
        if (i16 == 0) c0_out[n * NHD + h] = p;

        const int k0 = 2 * i16;
        float g0 = 0.f, g1 = 0.f;
        {
            const float4* w0 = (const float4*)(wklT + k0 * 36);
            const float4* w1 = (const float4*)(wklT + (k0 + 1) * 36);
            #pragma unroll
            for (int q = 0; q < 8; ++q) {
                const float4 a = w0[q], b = w1[q];
                g0 = fmaf(hqr[q*4+0], a.x, g0); g0 = fmaf(hqr[q*4+1], a.y, g0);
                g0 = fmaf(hqr[q*4+2], a.z, g0); g0 = fmaf(hqr[q*4+3], a.w, g0);
                g1 = fmaf(hqr[q*4+0], b.x, g1); g1 = fmaf(hqr[q*4+1], b.y, g1);
                g1 = fmaf(hqr[q*4+2], b.z, g1); g1 = fmaf(hqr[q*4+3], b.w, g1);
            }
        }
        g_bf[(size_t)n * 64 + l] = pk2(g0, g1);
    }
}

// ---------------- CSR build ----------------
__global__ __launch_bounds__(256) void k_deg(
    const int* __restrict__ edge_index, int* __restrict__ deg)
{
    for (int e = blockIdx.x * blockDim.x + threadIdx.x; e < EE;
         e += gridDim.x * blockDim.x)
        atomicAdd(&deg[edge_index[e]], 1);
}

__global__ __launch_bounds__(SCAN_B) void k_scan_block(
    const int* __restrict__ deg, int* __restrict__ base, int* __restrict__ bsum)
{
    const int i = blockIdx.x * SCAN_B + threadIdx.x;
    const int v = (i < NN) ? deg[i] : 0;
    __shared__ int s[SCAN_B];
    s[threadIdx.x] = v;
    __syncthreads();
    for (int off = 1; off < SCAN_B; off <<= 1) {
        int t = (threadIdx.x >= off) ? s[threadIdx.x - off] : 0;
        __syncthreads();
        s[threadIdx.x] += t;
        __syncthreads();
    }
    if (i < NN) base[i] = s[threadIdx.x] - v;
    if (threadIdx.x == SCAN_B - 1) bsum[blockIdx.x] = s[SCAN_B - 1];
}

__global__ __launch_bounds__(SCAN_B) void k_scan_top(int* __restrict__ bsum)
{
    const int i = threadIdx.x;
    const int v = (i < NBLK) ? bsum[i] : 0;
    __shared__ int s[SCAN_B];
    s[i] = v;
    __syncthreads();
    for (int off = 1; off < SCAN_B; off <<= 1) {
        int t = (i >= off) ? s[i - off] : 0;
        __syncthreads();
        s[i] += t;
        __syncthreads();
    }
    if (i < NBLK) bsum[i] = s[i] - v;
}

__global__ __launch_bounds__(SCAN_B) void k_scan_add(
    int* __restrict__ base, const int* __restrict__ bsum, int* __restrict__ cursor)
{
    const int i = blockIdx.x * SCAN_B + threadIdx.x;
    if (i < NN) {
        const int b = base[i] + bsum[i >> 8];
        base[i] = b;
        cursor[i] = b;
    }
}

__global__ __launch_bounds__(256) void k_scatter(
    const int* __restrict__ edge_index, int* __restrict__ cursor,
    int* __restrict__ eidx, int* __restrict__ rowv, int* __restrict__ colv)
{
    for (int e = blockIdx.x * blockDim.x + threadIdx.x; e < EE;
         e += gridDim.x * blockDim.x) {
        const int r = edge_index[e];
        const int pos = atomicAdd(&cursor[r], 1);
        eidx[pos] = e;
        rowv[pos] = r;
        colv[pos] = edge_index[EE + e];
    }
}

// ---------------- ea -> bf16, permuted to CSR order (grid-stride) ----------
__global__ __launch_bounds__(256) void k_ea_csr(
    const float* __restrict__ ea, const int* __restrict__ eidx,
    unsigned* __restrict__ ea_bf)
{
    for (int i = blockIdx.x * 256 + threadIdx.x; i < EE * 32;
         i += 2048 * 256) {
        const int pos = i >> 5, u = i & 31;
        const int e = eidx[pos];
        const float2 v = *(const float2*)(ea + (size_t)e * ECD + u * 2);
        ea_bf[(size_t)pos * 32 + u] = pk2(v.x, v.y);
    }
}

// ---------------- weight fragment packer (1 block) ----------------
__global__ __launch_bounds__(256) void k_wfrag(
    const float* __restrict__ wk1_w, const float* __restrict__ wk2_w,
    const float* __restrict__ wv1_w, const float* __restrict__ wv2_w,
    uint4* __restrict__ frag)
{
    const int t = threadIdx.x;
    const int l = t & 63;
    const int lm = l & 15, lg = l >> 4;
    {
        const int f = t >> 6;          // 0..3
        const int kt = f >> 1, nt = f & 1;
        const int out = nt * 16 + lm;
        uint4 a, b;
        unsigned ra[4], rb[4];
        #pragma unroll
        for (int p = 0; p < 4; ++p) {
            const int in0 = kt * 32 + lg * 8 + 2 * p;
            ra[p] = pk2(wk1_w[(size_t)out * ECD + in0], wk1_w[(size_t)out * ECD + in0 + 1]);
            rb[p] = pk2(wv1_w[(size_t)out * ECD + in0], wv1_w[(size_t)out * ECD + in0 + 1]);
        }
        a.x = ra[0]; a.y = ra[1]; a.z = ra[2]; a.w = ra[3];
        b.x = rb[0]; b.y = rb[1]; b.z = rb[2]; b.w = rb[3];
        frag[f * 64 + l] = a;
        frag[(6 + f) * 64 + l] = b;
    }
    if (t < 128) {
        const int nt = t >> 6;
        const int out = nt * 16 + lm;
        uint4 a, b;
        unsigned ra[4], rb[4];
        #pragma unroll
        for (int p = 0; p < 4; ++p) {
            const int in0 = lg * 8 + 2 * p;
            ra[p] = pk2(wk2_w[(size_t)out * HH + in0], wk2_w[(size_t)out * HH + in0 + 1]);
            rb[p] = pk2(wv2_w[(size_t)out * HH + in0], wv2_w[(size_t)out * HH + in0 + 1]);
        }
        a.x = ra[0]; a.y = ra[1]; a.z = ra[2]; a.w = ra[3];
        b.x = rb[0]; b.y = rb[1]; b.z = rb[2]; b.w = rb[3];
        frag[(4 + nt) * 64 + l] = a;
        frag[(10 + nt) * 64 + l] = b;
    }
}

// ---------------- K2: MFMA edge kernel (wave = 64 edges) --------------------
__global__ __launch_bounds__(256) void k_edge_mfma(
    const unsigned* __restrict__ ea_bf,
    const int* __restrict__ rowv, const int* __restrict__ colv,
    const unsigned* __restrict__ hk_bf, const unsigned* __restrict__ g_bf,
    const float* __restrict__ c0_in, const uint4* __restrict__ frag,
    const float* __restrict__ wk1_b, const float* __restrict__ wk2_b,
    const float* __restrict__ wv1_b, const float* __restrict__ wv2_b,
    float* __restrict__ qkP, unsigned* __restrict__ wvP)
{
    __shared__ float lds[4][64 * LSTR];
    const int w = threadIdx.x >> 6, l = threadIdx.x & 63;
    const int lm = l & 15, lg = l >> 4;
    float* L = lds[w];
    const int e0 = blockIdx.x * 256 + w * 64;
    const int pos = e0 + l;
    const int row = rowv[pos];
    const int col = colv[pos];

    uint4 eaf[4][2];
    #pragma unroll
    for (int mt = 0; mt < 4; ++mt)
        #pragma unroll
        for (int kt = 0; kt < 2; ++kt)
            eaf[mt][kt] = *(const uint4*)(ea_bf +
                (size_t)(e0 + mt * 16 + lm) * 32 + kt * 16 + lg * 4);

    // ================= K path =================
    {
        const float b1a = wk1_b[lm], b1b = wk1_b[16 + lm];
        f32x4 acc[4][2];
        #pragma unroll
        for (int mt = 0; mt < 4; ++mt) {
            acc[mt][0] = f32x4{b1a, b1a, b1a, b1a};
            acc[mt][1] = f32x4{b1b, b1b, b1b, b1b};
        }
        const uint4 f00 = frag[0 * 64 + l], f01 = frag[1 * 64 + l];
        const uint4 f10 = frag[2 * 64 + l], f11 = frag[3 * 64 + l];
        #pragma unroll
        for (int mt = 0; mt < 4; ++mt) {
            acc[mt][0] = __builtin_amdgcn_mfma_f32_16x16x32_bf16(as_bf(eaf[mt][0]), as_bf(f00), acc[mt][0], 0, 0, 0);
            acc[mt][1] = __builtin_amdgcn_mfma_f32_16x16x32_bf16(as_bf(eaf[mt][0]), as_bf(f01), acc[mt][1], 0, 0, 0);
            acc[mt][0] = __builtin_amdgcn_mfma_f32_16x16x32_bf16(as_bf(eaf[mt][1]), as_bf(f10), acc[mt][0], 0, 0, 0);
            acc[mt][1] = __builtin_amdgcn_mfma_f32_16x16x32_bf16(as_bf(eaf[mt][1]), as_bf(f11), acc[mt][1], 0, 0, 0);
        }
        #pragma unroll
        for (int mt = 0; mt < 4; ++mt)
            #pragma unroll
            for (int nt = 0; nt < 2; ++nt)
                #pragma unroll
                for (int r = 0; r < 4; ++r)
                    L[(mt * 16 + lg * 4 + r) * LSTR + nt * 16 + lm] = ssp_f(acc[mt][nt][r]);

        const float b2a = wk2_b[lm], b2b = wk2_b[16 + lm];
        f32x4 acc2[4][2];
        const uint4 f20 = frag[4 * 64 + l], f21 = frag[5 * 64 + l];
        #pragma unroll
        for (int mt = 0; mt < 4; ++mt) {
            acc2[mt][0] = f32x4{b2a, b2a, b2a, b2a};
            acc2[mt][1] = f32x4{b2b, b2b, b2b, b2b};
            float av[8];
            #pragma unroll
            for (int j = 0; j < 8; ++j)
                av[j] = L[(mt * 16 + lm) * LSTR + lg * 8 + j];
            uint4 a2;
            a2.x = pk2(av[0], av[1]); a2.y = pk2(av[2], av[3]);
            a2.z = pk2(av[4], av[5]); a2.w = pk2(av[6], av[7]);
            acc2[mt][0] = __builtin_amdgcn_mfma_f32_16x16x32_bf16(as_bf(a2), as_bf(f20), acc2[mt][0], 0, 0, 0);
            acc2[mt][1] = __builtin_amdgcn_mfma_f32_16x16x32_bf16(as_bf(a2), as_bf(f21), acc2[mt][1], 0, 0, 0);
        }
        #pragma unroll
        for (int mt = 0; mt < 4; ++mt)
            #pragma unroll
            for (int nt = 0; nt < 2; ++nt)
                #pragma unroll
                for (int r = 0; r < 4; ++r)
                    L[(mt * 16 + lg * 4 + r) * LSTR + nt * 16 + lm] = acc2[mt][nt][r];
    }

    float wk[32];
    #pragma unroll
    for (int j = 0; j < 32; ++j) wk[j] = L[l * LSTR + j];

    {
        const uint4* hkp = (const uint4*)(hk_bf + (size_t)col * 64);
        const uint4* gp  = (const uint4*)(g_bf  + (size_t)row * 64);
        const float4 c0v = *(const float4*)(c0_in + (size_t)row * NHD);
        #pragma unroll
        for (int h = 0; h < NHD; ++h) {
            float s = 0.f;
            #pragma unroll
            for (int q = 0; q < 4; ++q) {
                const uint4 ku = hkp[h * 4 + q];
                const uint4 gu = gp[h * 4 + q];
                float ka, kb, ga, gb;
                unp2(ku.x, ka, kb); unp2(gu.x, ga, gb);
                s = fmaf(wk[q * 8 + 0] * ka, ga, s);
                s = fmaf(wk[q * 8 + 1] * kb, gb, s);
                unp2(ku.y, ka, kb); unp2(gu.y, ga, gb);
                s = fmaf(wk[q * 8 + 2] * ka, ga, s);
                s = fmaf(wk[q * 8 + 3] * kb, gb, s);
                unp2(ku.z, ka, kb); unp2(gu.z, ga, gb);
                s = fmaf(wk[q * 8 + 4] * ka, ga, s);
                s = fmaf(wk[q * 8 + 5] * kb, gb, s);
                unp2(ku.w, ka, kb); unp2(gu.w, ga, gb);
                s = fmaf(wk[q * 8 + 6] * ka, ga, s);
                s = fmaf(wk[q * 8 + 7] * kb, gb, s);
            }
            const float c0h = (h == 0) ? c0v.x : (h == 1) ? c0v.y : (h == 2) ? c0v.z : c0v.w;
            qkP[(size_t)h * EE + pos] = s + c0h;
        }
    }

    // ================= V path =================
    {
        const float b1a = wv1_b[lm], b1b = wv1_b[16 + lm];
        f32x4 acc[4][2];
        #pragma unroll
        for (int mt = 0; mt < 4; ++mt) {
            acc[mt][0] = f32x4{b1a, b1a, b1a, b1a};
            acc[mt][1] = f32x4{b1b, b1b, b1b, b1b};
        }
        const uint4 f00 = frag[6 * 64 + l], f01 = frag[7 * 64 + l];
        const uint4 f10 = frag[8 * 64 + l], f11 = frag[9 * 64 + l];
        #pragma unroll
        for (int mt = 0; mt < 4; ++mt) {
            acc[mt][0] = __builtin_amdgcn_mfma_f32_16x16x32_bf16(as_bf(eaf[mt][0]), as_bf(f00), acc[mt][0], 0, 0, 0);
            acc[mt][1] = __builtin_amdgcn_mfma_f32_16x16x32_bf16(as_bf(eaf[mt][0]), as_bf(f01), acc[mt][1], 0, 0, 0);
            acc[mt][0] = __builtin_amdgcn_mfma_f32_16x16x32_bf16(as_bf(eaf[mt][1]), as_bf(f10), acc[mt][0], 0, 0, 0);
            acc[mt][1] = __builtin_amdgcn_mfma_f32_16x16x32_bf16(as_bf(eaf[mt][1]), as_bf(f11), acc[mt][1], 0, 0, 0);
        }
        #pragma unroll
        for (int mt = 0; mt < 4; ++mt)
            #pragma unroll
            for (int nt = 0; nt < 2; ++nt)
                #pragma unroll
                for (int r = 0; r < 4; ++r)
                    L[(mt * 16 + lg * 4 + r) * LSTR + nt * 16 + lm] = ssp_f(acc[mt][nt][r]);

        const float b2a = wv2_b[lm], b2b = wv2_b[16 + lm];
        f32x4 acc2[4][2];
        const uint4 f20 = frag[10 * 64 + l], f21 = frag[11 * 64 + l];
        #pragma unroll
        for (int mt = 0; mt < 4; ++mt) {
            acc2[mt][0] = f32x4{b2a, b2a, b2a, b2a};
            acc2[mt][1] = f32x4{b2b, b2b, b2b, b2b};
            float av[8];
            #pragma unroll
            for (int j = 0; j < 8; ++j)
                av[j] = L[(mt * 16 + lm) * LSTR + lg * 8 + j];
            uint4 a2;
            a2.x = pk2(av[0], av[1]); a2.y = pk2(av[2], av[3]);
            a2.z = pk2(av[4], av[5]); a2.w = pk2(av[6], av[7]);
            acc2[mt][0] = __builtin_amdgcn_mfma_f32_16x16x32_bf16(as_bf(a2), as_bf(f20), acc2[mt][0], 0, 0, 0);
            acc2[mt][1] = __builtin_amdgcn_mfma_f32_16x16x32_bf16(as_bf(a2), as_bf(f21), acc2[mt][1], 0, 0, 0);
        }
        #pragma unroll
        for (int mt = 0; mt < 4; ++mt)
            #pragma unroll
            for (int nt = 0; nt < 2; ++nt)
                #pragma unroll
                for (int r = 0; r < 4; ++r)
                    L[(mt * 16 + lg * 4 + r) * LSTR + nt * 16 + lm] = acc2[mt][nt][r];
    }

    #pragma unroll
    for (int k = 0; k < 16; ++k) {
        const int f = k * 64 + l;
        const int pr = f >> 4, i = f & 15;
        wvP[(size_t)e0 * 16 + f] = pk2(L[pr * LSTR + 2 * i], L[pr * LSTR + 2 * i + 1]);
    }
}

// ---------------- K3a: aggregation only (low VGPR, high occupancy) ----------
__global__ __launch_bounds__(256) void k_aggr(
    const float* __restrict__ qkP, const unsigned* __restrict__ wvP,
    const unsigned* __restrict__ hv_bf, const int* __restrict__ colv,
    const int* __restrict__ base, const int* __restrict__ deg,
    float* __restrict__ uP)
{
    const int w = threadIdx.x >> 6, l = threadIdx.x & 63;
    const int h = l >> 4, i = l & 15;

    for (int n = blockIdx.x * 4 + w; n < NN; n += 2048 * 4) {
        const int b0 = base[n];
        const int dn = deg[n];
        float acc0 = 0.f, acc1 = 0.f;
        if (dn > 0) {
            const float* qkh = qkP + (size_t)h * EE + b0;
            const int emax = b0 + dn - 1;
            float m = -3.0e38f;
            for (int c = i; c < dn; c += 16) m = fmaxf(m, qkh[c]);
            #pragma unroll
            for (int off = 1; off < 16; off <<= 1)
                m = fmaxf(m, __shfl_xor(m, off));
            float den = 0.f;
            for (int c = i; c < dn; c += 16) den += __expf(qkh[c] - m);
            #pragma unroll
            for (int off = 1; off < 16; off <<= 1) den += __shfl_xor(den, off);
            const float rden = (den > 0.f) ? 1.0f / den : 0.f;
            for (int c0 = 0; c0 < dn; c0 += 16) {
                const int tn = (dn - c0 < 16) ? (dn - c0) : 16;
                float ex = 0.f; int cq = 0;
                if (i < tn) {
                    ex = __expf(qkh[c0 + i] - m) * rden;
                    cq = colv[b0 + c0 + i];
                }
                const int t4 = (tn + 3) & ~3;
                for (int i2 = 0; i2 < t4; i2 += 4) {
                    #pragma unroll
                    for (int u = 0; u < 4; ++u) {
                        const int src = (l & 48) | (i2 + u);
                        const float wgt = __shfl(ex, src);
                        const int ce = __shfl(cq, src);
                        int ep = b0 + c0 + i2 + u;
                        ep = (ep > emax) ? emax : ep;
                        const unsigned hvv = hv_bf[(size_t)ce * 64 + l];
                        const unsigned wvv = wvP[(size_t)ep * 16 + i];
                        float ha, hb, wa, wb;
                        unp2(hvv, ha, hb); unp2(wvv, wa, wb);
                        acc0 = fmaf(wgt, wa * ha, acc0);
                        acc1 = fmaf(wgt, wb * hb, acc1);
                    }
                }
            }
        }
        *(float2*)(uP + (size_t)n * HD + 2 * l) = make_float2(acc0, acc1);
    }
}

// ---------------- K3b: dense tail: wvl matvec + LN2 + ssp + out matmul ------
__global__ __launch_bounds__(256) void k_tail(
    const float* __restrict__ x, const float* __restrict__ uP,
    const int* __restrict__ deg,
    const float* __restrict__ wvl_w, const float* __restrict__ wvl_b,
    const float* __restrict__ out_w, const float* __restrict__ out_b,
    const float* __restrict__ ln2_g, const float* __restrict__ ln2_b,
    float* __restrict__ out)
{
    __shared__ float su[4][HD];
    const int w = threadIdx.x >> 6, l = threadIdx.x & 63;
    const int h = l >> 4, i = l & 15;
    const int t0 = 2 * l;
    const float2 lg2 = *(const float2*)(ln2_g + t0);
    const float2 lb2 = *(const float2*)(ln2_b + t0);
    const float2 ob2 = *(const float2*)(out_b + t0);
    const int j0 = 2 * i;
    float* sb = su[w];

    for (int n = blockIdx.x * 4 + w; n < NN; n += 2048 * 4) {
        const int dn = deg[n];
        const float2 xv = *(const float2*)(x + (size_t)n * HD + t0);

        float ag0 = 0.f, ag1 = 0.f;
        if (dn > 0) {
            const float2 wb = *(const float2*)(wvl_b + j0);
            ag0 = wb.x; ag1 = wb.y;
            const float4* up = (const float4*)(uP + (size_t)n * HD + h * HH);
            const float4* r0 = (const float4*)(wvl_w + (size_t)j0 * HH);
            const float4* r1 = (const float4*)(wvl_w + (size_t)(j0 + 1) * HH);
            #pragma unroll
            for (int q = 0; q < 8; ++q) {
                const float4 u = up[q];
                const float4 a = r0[q], b = r1[q];
                ag0 = fmaf(u.x, a.x, ag0); ag0 = fmaf(u.y, a.y, ag0);
                ag0 = fmaf(u.z, a.z, ag0); ag0 = fmaf(u.w, a.w, ag0);
                ag1 = fmaf(u.x, b.x, ag1); ag1 = fmaf(u.y, b.y, ag1);
                ag1 = fmaf(u.z, b.z, ag1); ag1 = fmaf(u.w, b.w, ag1);
            }
        }
        const float x20 = ag0 + xv.x;
        const float x21 = ag1 + xv.y;

        float s1 = x20 + x21, s2 = x20 * x20 + x21 * x21;
        #pragma unroll
        for (int off = 1; off < 64; off <<= 1) {
            s1 += __shfl_xor(s1, off);
            s2 += __shfl_xor(s2, off);
        }
        const float mean = s1 * (1.0f / HD);
        const float var  = s2 * (1.0f / HD) - mean * mean;
        const float rstd = rsqrtf(var + 1e-5f);
        const float ss0 = ssp_f((x20 - mean) * rstd * lg2.x + lb2.x);
        const float ss1 = ssp_f((x21 - mean) * rstd * lg2.y + lb2.y);

        *(float2*)(sb + t0) = make_float2(ss0, ss1);
        float o0 = ob2.x + x20, o1 = ob2.y + x21;
        const float4* wr0 = (const float4*)(out_w + (size_t)t0 * HD);
        const float4* wr1 = (const float4*)(out_w + (size_t)(t0 + 1) * HD);
        #pragma unroll
        for (int c = 0; c < 8; ++c) {           // 16 values per chunk
            const float4* sp = (const float4*)(sb + c * 16);
            #pragma unroll
            for (int q = 0; q < 4; ++q) {
                const float4 sv = sp[q];
                const float4 a = wr0[c * 4 + q], b = wr1[c * 4 + q];
                o0 = fmaf(sv.x, a.x, o0); o0 = fmaf(sv.y, a.y, o0);
                o0 = fmaf(sv.z, a.z, o0); o0 = fmaf(sv.w, a.w, o0);
                o1 = fmaf(sv.x, b.x, o1); o1 = fmaf(sv.y, b.y, o1);
                o1 = fmaf(sv.z, b.z, o1); o1 = fmaf(sv.w, b.w, o1);
            }
        }
        *(float2*)(out + (size_t)n * HD + t0) = make_float2(o0, o1);
    }
}

extern "C" void kernel_launch(void* const* d_in, const int* in_sizes, int n_in,
                              void* d_out, int out_size, void* d_ws, size_t ws_size,
                              hipStream_t stream) {
    const float* x         = (const float*)d_in[0];
    const float* edge_attr = (const float*)d_in[1];
    const int*   edge_index= (const int*)  d_in[2];
    const float* k_w   = (const float*)d_in[3];
    const float* q_w   = (const float*)d_in[4];
    const float* v_w   = (const float*)d_in[5];
    const float* wk1_w = (const float*)d_in[6];
    const float* wk1_b = (const float*)d_in[7];
    const float* wk2_w = (const float*)d_in[8];
    const float* wk2_b = (const float*)d_in[9];
    const float* wkl_w = (const float*)d_in[10];
    const float* wkl_b = (const float*)d_in[11];
    const float* wv1_w = (const float*)d_in[12];
    const float* wv1_b = (const float*)d_in[13];
    const float* wv2_w = (const float*)d_in[14];
    const float* wv2_b = (const float*)d_in[15];
    const float* wvl_w = (const float*)d_in[16];
    const float* wvl_b = (const float*)d_in[17];
    const float* out_w = (const float*)d_in[18];
    const float* out_b = (const float*)d_in[19];
    const float* ln1_g = (const float*)d_in[20];
    const float* ln1_b = (const float*)d_in[21];
    const float* ln2_g = (const float*)d_in[22];
    const float* ln2_b = (const float*)d_in[23];

    char* ws = (char*)d_ws;
    unsigned* hk_bf = (unsigned*)ws;            ws += (size_t)NN * 64 * 4;
    unsigned* hv_bf = (unsigned*)ws;            ws += (size_t)NN * 64 * 4;
    unsigned* g_bf  = (unsigned*)ws;            ws += (size_t)NN * 64 * 4;
    float* c0  = (float*)ws;                    ws += (size_t)NN * NHD * 4;
    float* qkP = (float*)ws;                    ws += (size_t)NHD * EE * 4;
    unsigned* wvP = (unsigned*)ws;              ws += (size_t)EE * 16 * 4;
    unsigned* ea_bf = (unsigned*)ws;            ws += (size_t)EE * 32 * 4;
    uint4* fragbuf = (uint4*)ws;                ws += (size_t)12 * 64 * 16;
    float* uP = (float*)ws;                     ws += (size_t)NN * HD * 4;
    int* deg    = (int*)ws;                     ws += (size_t)NN * 4;
    int* base   = (int*)ws;                     ws += (size_t)NN * 4;
    int* cursor = (int*)ws;                     ws += (size_t)NN * 4;
    int* bsum   = (int*)ws;                     ws += (size_t)SCAN_B * 4;
    int* eidx   = (int*)ws;                     ws += (size_t)EE * 4;
    int* rowv   = (int*)ws;                     ws += (size_t)EE * 4;
    int* colv   = (int*)ws;                     ws += (size_t)EE * 4;

    (void)hipMemsetAsync(deg, 0, (size_t)NN * 4, stream);

    k_wfrag<<<1, 256, 0, stream>>>(wk1_w, wk2_w, wv1_w, wv2_w, fragbuf);
    k_node_prep<<<1024, 256, 0, stream>>>(x, k_w, q_w, v_w, wkl_w, wkl_b,
        ln1_g, ln1_b, hk_bf, hv_bf, g_bf, c0);
    k_deg<<<1024, 256, 0, stream>>>(edge_index, deg);
    k_scan_block<<<NBLK, SCAN_B, 0, stream>>>(deg, base, bsum);
    k_scan_top<<<1, SCAN_B, 0, stream>>>(bsum);
    k_scan_add<<<NBLK, SCAN_B, 0, stream>>>(base, bsum, cursor);
    k_scatter<<<1024, 256, 0, stream>>>(edge_index, cursor, eidx, rowv, colv);
    k_ea_csr<<<2048, 256, 0, stream>>>(edge_attr, eidx, ea_bf);
    k_edge_mfma<<<EE / 256, 256, 0, stream>>>(ea_bf, rowv, colv,
        hk_bf, g_bf, c0, fragbuf,
        wk1_b, wk2_b, wv1_b, wv2_b, qkP, wvP);
    k_aggr<<<2048, 256, 0, stream>>>(qkP, wvP, hv_bf, colv, base, deg, uP);
    k_tail<<<2048, 256, 0, stream>>>(x, uP, deg, wvl_w, wvl_b,
        out_w, out_b, ln2_g, ln2_b, (float*)d_out);
}

// Round 10
// 550.882 us; speedup vs baseline: 5.6754x; 1.1793x over previous
//
#include <hip/hip_runtime.h>
#include <math.h>

#define NN 50000
#define EE 640000
#define HD 128
#define ECD 64
#define NHD 4
#define HH 32
#define SCAN_B 256
#define NBLK ((NN + SCAN_B - 1) / SCAN_B)   // 196
#define LSTR 33   // LDS row stride in floats (64 edges x 32 vals, +1 pad)

typedef short bf16x8 __attribute__((ext_vector_type(8)));
typedef float f32x4 __attribute__((ext_vector_type(4)));

__device__ __forceinline__ float ssp_f(float v) {
    return fmaxf(v, 0.0f) + log1pf(__expf(-fabsf(v))) - 0.69314718055994531f;
}
__device__ __forceinline__ unsigned f2bf_u(float f) {
    unsigned u = __float_as_uint(f);
    unsigned r = ((u >> 16) & 1u) + 0x7FFFu;
    return (u + r) >> 16;
}
__device__ __forceinline__ unsigned pk2(float a, float b) {
    return f2bf_u(a) | (f2bf_u(b) << 16);
}
__device__ __forceinline__ void unp2(unsigned u, float& a, float& b) {
    a = __uint_as_float(u << 16);
    b = __uint_as_float(u & 0xffff0000u);
}
__device__ __forceinline__ bf16x8 as_bf(uint4 u) {
    union { uint4 a; bf16x8 b; } c; c.a = u; return c.b;
}

// ---------------- K1: LN1 + projections + g/c0 (wave-per-node, persistent) ----
__global__ __launch_bounds__(256) void k_node_prep(
    const float* __restrict__ x, const float* __restrict__ k_w,
    const float* __restrict__ q_w, const float* __restrict__ v_w,
    const float* __restrict__ wkl_w, const float* __restrict__ wkl_b,
    const float* __restrict__ ln1_g, const float* __restrict__ ln1_b,
    unsigned* __restrict__ hk_bf, unsigned* __restrict__ hv_bf,
    unsigned* __restrict__ g_bf, float* __restrict__ c0_out)
{
    __shared__ float wklT[HH * 36];
    __shared__ float ybuf[4][HD];
    for (int idx = threadIdx.x; idx < HH * HH; idx += 256)
        wklT[(idx & 31) * 36 + (idx >> 5)] = wkl_w[idx];
    __syncthreads();

    const int w = threadIdx.x >> 6, l = threadIdx.x & 63;
    const int h = l >> 4, i16 = l & 15;
    const int t0 = 2 * l;
    const float2 lg2 = *(const float2*)(ln1_g + t0);
    const float2 lb2 = *(const float2*)(ln1_b + t0);
    const float2 wb2 = *(const float2*)(wkl_b + 2 * i16);
    float* yb = ybuf[w];

    for (int n = blockIdx.x * 4 + w; n < NN; n += 1024 * 4) {
        const float2 xv = *(const float2*)(x + (size_t)n * HD + t0);
        float s1 = xv.x + xv.y;
        float s2 = xv.x * xv.x + xv.y * xv.y;
        #pragma unroll
        for (int off = 1; off < 64; off <<= 1) {
            s1 += __shfl_xor(s1, off);
            s2 += __shfl_xor(s2, off);
        }
        const float mean = s1 * (1.0f / HD);
        const float var  = s2 * (1.0f / HD) - mean * mean;
        const float rstd = rsqrtf(var + 1e-5f);
        const float y0 = (xv.x - mean) * rstd * lg2.x + lb2.x;
        const float y1 = (xv.y - mean) * rstd * lg2.y + lb2.y;
        *(float2*)(yb + t0) = make_float2(y0, y1);

        float yr[32];
        {
            const float4* yp = (const float4*)(yb + h * HH);
            #pragma unroll
            for (int q = 0; q < 8; ++q) {
                const float4 v = yp[q];
                yr[q*4+0] = v.x; yr[q*4+1] = v.y; yr[q*4+2] = v.z; yr[q*4+3] = v.w;
            }
        }
        float ak0=0,ak1=0,aq0=0,aq1=0,av0=0,av1=0;
        {
            const float4* kr0 = (const float4*)(k_w + (size_t)t0 * HH);
            const float4* kr1 = (const float4*)(k_w + (size_t)(t0+1) * HH);
            const float4* qr0 = (const float4*)(q_w + (size_t)t0 * HH);
            const float4* qr1 = (const float4*)(q_w + (size_t)(t0+1) * HH);
            const float4* vr0 = (const float4*)(v_w + (size_t)t0 * HH);
            const float4* vr1 = (const float4*)(v_w + (size_t)(t0+1) * HH);
            #pragma unroll
            for (int q = 0; q < 8; ++q) {
                const float4 a = kr0[q], b = kr1[q], c = qr0[q], d = qr1[q];
                const float4 e = vr0[q], f = vr1[q];
                ak0 = fmaf(yr[q*4+0], a.x, ak0); ak0 = fmaf(yr[q*4+1], a.y, ak0);
                ak0 = fmaf(yr[q*4+2], a.z, ak0); ak0 = fmaf(yr[q*4+3], a.w, ak0);
                ak1 = fmaf(yr[q*4+0], b.x, ak1); ak1 = fmaf(yr[q*4+1], b.y, ak1);
                ak1 = fmaf(yr[q*4+2], b.z, ak1); ak1 = fmaf(yr[q*4+3], b.w, ak1);
                aq0 = fmaf(yr[q*4+0], c.x, aq0); aq0 = fmaf(yr[q*4+1], c.y, aq0);
                aq0 = fmaf(yr[q*4+2], c.z, aq0); aq0 = fmaf(yr[q*4+3], c.w, aq0);
                aq1 = fmaf(yr[q*4+0], d.x, aq1); aq1 = fmaf(yr[q*4+1], d.y, aq1);
                aq1 = fmaf(yr[q*4+2], d.z, aq1); aq1 = fmaf(yr[q*4+3], d.w, aq1);
                av0 = fmaf(yr[q*4+0], e.x, av0); av0 = fmaf(yr[q*4+1], e.y, av0);
                av0 = fmaf(yr[q*4+2], e.z, av0); av0 = fmaf(yr[q*4+3], e.w, av0);
                av1 = fmaf(yr[q*4+0], f.x, av1); av1 = fmaf(yr[q*4+1], f.y, av1);
                av1 = fmaf(yr[q*4+2], f.z, av1); av1 = fmaf(yr[q*4+3], f.w, av1);
            }
        }
        hk_bf[(size_t)n * 64 + l] = pk2(ak0, ak1);
        hv_bf[(size_t)n * 64 + l] = pk2(av0, av1);

        *(float2*)(yb + t0) = make_float2(aq0, aq1);
        float hqr[32];
        {
            const float4* hp = (const float4*)(yb + h * HH);
            #pragma unroll
            for (int q = 0; q < 8; ++q) {
                const float4 v = hp[q];
                hqr[q*4+0] = v.x; hqr[q*4+1] = v.y; hqr[q*4+2] = v.z; hqr[q*4+3] = v.w;
            }
        }
        float p = aq0 * wb2.x + aq1 * wb2.y;
        #pragma unroll
        for (int off = 1; off < 16; off <<= 1) p += __shfl_xor(p, off);
        if (i16 == 0) c0_out[n * NHD + h] = p;

        const int k0 = 2 * i16;
        float g0 = 0.f, g1 = 0.f;
        {
            const float4* w0 = (const float4*)(wklT + k0 * 36);
            const float4* w1 = (const float4*)(wklT + (k0 + 1) * 36);
            #pragma unroll
            for (int q = 0; q < 8; ++q) {
                const float4 a = w0[q], b = w1[q];
                g0 = fmaf(hqr[q*4+0], a.x, g0); g0 = fmaf(hqr[q*4+1], a.y, g0);
                g0 = fmaf(hqr[q*4+2], a.z, g0); g0 = fmaf(hqr[q*4+3], a.w, g0);
                g1 = fmaf(hqr[q*4+0], b.x, g1); g1 = fmaf(hqr[q*4+1], b.y, g1);
                g1 = fmaf(hqr[q*4+2], b.z, g1); g1 = fmaf(hqr[q*4+3], b.w, g1);
            }
        }
        g_bf[(size_t)n * 64 + l] = pk2(g0, g1);
    }
}

// ---------------- CSR build ----------------
__global__ __launch_bounds__(256) void k_deg(
    const int* __restrict__ edge_index, int* __restrict__ deg)
{
    for (int e = blockIdx.x * blockDim.x + threadIdx.x; e < EE;
         e += gridDim.x * blockDim.x)
        atomicAdd(&deg[edge_index[e]], 1);
}

__global__ __launch_bounds__(SCAN_B) void k_scan_block(
    const int* __restrict__ deg, int* __restrict__ base, int* __restrict__ bsum)
{
    const int i = blockIdx.x * SCAN_B + threadIdx.x;
    const int v = (i < NN) ? deg[i] : 0;
    __shared__ int s[SCAN_B];
    s[threadIdx.x] = v;
    __syncthreads();
    for (int off = 1; off < SCAN_B; off <<= 1) {
        int t = (threadIdx.x >= off) ? s[threadIdx.x - off] : 0;
        __syncthreads();
        s[threadIdx.x] += t;
        __syncthreads();
    }
    if (i < NN) base[i] = s[threadIdx.x] - v;
    if (threadIdx.x == SCAN_B - 1) bsum[blockIdx.x] = s[SCAN_B - 1];
}

__global__ __launch_bounds__(SCAN_B) void k_scan_top(int* __restrict__ bsum)
{
    const int i = threadIdx.x;
    const int v = (i < NBLK) ? bsum[i] : 0;
    __shared__ int s[SCAN_B];
    s[i] = v;
    __syncthreads();
    for (int off = 1; off < SCAN_B; off <<= 1) {
        int t = (i >= off) ? s[i - off] : 0;
        __syncthreads();
        s[i] += t;
        __syncthreads();
    }
    if (i < NBLK) bsum[i] = s[i] - v;
}

__global__ __launch_bounds__(SCAN_B) void k_scan_add(
    int* __restrict__ base, const int* __restrict__ bsum, int* __restrict__ cursor)
{
    const int i = blockIdx.x * SCAN_B + threadIdx.x;
    if (i < NN) {
        const int b = base[i] + bsum[i >> 8];
        base[i] = b;
        cursor[i] = b;
    }
}

__global__ __launch_bounds__(256) void k_scatter(
    const int* __restrict__ edge_index, int* __restrict__ cursor,
    int* __restrict__ eidx, int* __restrict__ rowv, int* __restrict__ colv)
{
    for (int e = blockIdx.x * blockDim.x + threadIdx.x; e < EE;
         e += gridDim.x * blockDim.x) {
        const int r = edge_index[e];
        const int pos = atomicAdd(&cursor[r], 1);
        eidx[pos] = e;
        rowv[pos] = r;
        colv[pos] = edge_index[EE + e];
    }
}

// ---------------- ea -> bf16, permuted to CSR order (grid-stride) ----------
__global__ __launch_bounds__(256) void k_ea_csr(
    const float* __restrict__ ea, const int* __restrict__ eidx,
    unsigned* __restrict__ ea_bf)
{
    for (int i = blockIdx.x * 256 + threadIdx.x; i < EE * 32;
         i += 2048 * 256) {
        const int pos = i >> 5, u = i & 31;
        const int e = eidx[pos];
        const float2 v = *(const float2*)(ea + (size_t)e * ECD + u * 2);
        ea_bf[(size_t)pos * 32 + u] = pk2(v.x, v.y);
    }
}

// ---------------- weight fragment packer (1 block) ----------------
__global__ __launch_bounds__(256) void k_wfrag(
    const float* __restrict__ wk1_w, const float* __restrict__ wk2_w,
    const float* __restrict__ wv1_w, const float* __restrict__ wv2_w,
    uint4* __restrict__ frag)
{
    const int t = threadIdx.x;
    const int l = t & 63;
    const int lm = l & 15, lg = l >> 4;
    {
        const int f = t >> 6;          // 0..3
        const int kt = f >> 1, nt = f & 1;
        const int out = nt * 16 + lm;
        uint4 a, b;
        unsigned ra[4], rb[4];
        #pragma unroll
        for (int p = 0; p < 4; ++p) {
            const int in0 = kt * 32 + lg * 8 + 2 * p;
            ra[p] = pk2(wk1_w[(size_t)out * ECD + in0], wk1_w[(size_t)out * ECD + in0 + 1]);
            rb[p] = pk2(wv1_w[(size_t)out * ECD + in0], wv1_w[(size_t)out * ECD + in0 + 1]);
        }
        a.x = ra[0]; a.y = ra[1]; a.z = ra[2]; a.w = ra[3];
        b.x = rb[0]; b.y = rb[1]; b.z = rb[2]; b.w = rb[3];
        frag[f * 64 + l] = a;
        frag[(6 + f) * 64 + l] = b;
    }
    if (t < 128) {
        const int nt = t >> 6;
        const int out = nt * 16 + lm;
        uint4 a, b;
        unsigned ra[4], rb[4];
        #pragma unroll
        for (int p = 0; p < 4; ++p) {
            const int in0 = lg * 8 + 2 * p;
            ra[p] = pk2(wk2_w[(size_t)out * HH + in0], wk2_w[(size_t)out * HH + in0 + 1]);
            rb[p] = pk2(wv2_w[(size_t)out * HH + in0], wv2_w[(size_t)out * HH + in0 + 1]);
        }
        a.x = ra[0]; a.y = ra[1]; a.z = ra[2]; a.w = ra[3];
        b.x = rb[0]; b.y = rb[1]; b.z = rb[2]; b.w = rb[3];
        frag[(4 + nt) * 64 + l] = a;
        frag[(10 + nt) * 64 + l] = b;
    }
}

// ---------------- out_w fragment packer: owf[nt*4+kt][64] ----------------
__global__ __launch_bounds__(256) void k_owfrag(
    const float* __restrict__ out_w, uint4* __restrict__ owf)
{
    const int t = threadIdx.x;
    const int l = t & 63;
    const int lm = l & 15, lg = l >> 4;
    #pragma unroll
    for (int it = 0; it < 8; ++it) {
        const int f = (t >> 6) + it * 4;   // 0..31 = nt*4+kt
        const int nt = f >> 2, kt = f & 3;
        const int n = nt * 16 + lm;
        unsigned r[4];
        #pragma unroll
        for (int p = 0; p < 4; ++p) {
            const int k0 = kt * 32 + lg * 8 + 2 * p;
            r[p] = pk2(out_w[(size_t)n * HD + k0], out_w[(size_t)n * HD + k0 + 1]);
        }
        uint4 o; o.x = r[0]; o.y = r[1]; o.z = r[2]; o.w = r[3];
        owf[f * 64 + l] = o;
    }
}

// ---------------- K2: MFMA edge kernel (wave = 64 edges) --------------------
__global__ __launch_bounds__(256) void k_edge_mfma(
    const unsigned* __restrict__ ea_bf,
    const int* __restrict__ rowv, const int* __restrict__ colv,
    const unsigned* __restrict__ hk_bf, const unsigned* __restrict__ g_bf,
    const float* __restrict__ c0_in, const uint4* __restrict__ frag,
    const float* __restrict__ wk1_b, const float* __restrict__ wk2_b,
    const float* __restrict__ wv1_b, const float* __restrict__ wv2_b,
    float* __restrict__ qkP, unsigned* __restrict__ wvP)
{
    __shared__ float lds[4][64 * LSTR];
    const int w = threadIdx.x >> 6, l = threadIdx.x & 63;
    const int lm = l & 15, lg = l >> 4;
    float* L = lds[w];
    const int e0 = blockIdx.x * 256 + w * 64;
    const int pos = e0 + l;
    const int row = rowv[pos];
    const int col = colv[pos];

    uint4 eaf[4][2];
    #pragma unroll
    for (int mt = 0; mt < 4; ++mt)
        #pragma unroll
        for (int kt = 0; kt < 2; ++kt)
            eaf[mt][kt] = *(const uint4*)(ea_bf +
                (size_t)(e0 + mt * 16 + lm) * 32 + kt * 16 + lg * 4);

    // ================= K path =================
    {
        const float b1a = wk1_b[lm], b1b = wk1_b[16 + lm];
        f32x4 acc[4][2];
        #pragma unroll
        for (int mt = 0; mt < 4; ++mt) {
            acc[mt][0] = f32x4{b1a, b1a, b1a, b1a};
            acc[mt][1] = f32x4{b1b, b1b, b1b, b1b};
        }
        const uint4 f00 = frag[0 * 64 + l], f01 = frag[1 * 64 + l];
        const uint4 f10 = frag[2 * 64 + l], f11 = frag[3 * 64 + l];
        #pragma unroll
        for (int mt = 0; mt < 4; ++mt) {
            acc[mt][0] = __builtin_amdgcn_mfma_f32_16x16x32_bf16(as_bf(eaf[mt][0]), as_bf(f00), acc[mt][0], 0, 0, 0);
            acc[mt][1] = __builtin_amdgcn_mfma_f32_16x16x32_bf16(as_bf(eaf[mt][0]), as_bf(f01), acc[mt][1], 0, 0, 0);
            acc[mt][0] = __builtin_amdgcn_mfma_f32_16x16x32_bf16(as_bf(eaf[mt][1]), as_bf(f10), acc[mt][0], 0, 0, 0);
            acc[mt][1] = __builtin_amdgcn_mfma_f32_16x16x32_bf16(as_bf(eaf[mt][1]), as_bf(f11), acc[mt][1], 0, 0, 0);
        }
        #pragma unroll
        for (int mt = 0; mt < 4; ++mt)
            #pragma unroll
            for (int nt = 0; nt < 2; ++nt)
                #pragma unroll
                for (int r = 0; r < 4; ++r)
                    L[(mt * 16 + lg * 4 + r) * LSTR + nt * 16 + lm] = ssp_f(acc[mt][nt][r]);

        const float b2a = wk2_b[lm], b2b = wk2_b[16 + lm];
        f32x4 acc2[4][2];
        const uint4 f20 = frag[4 * 64 + l], f21 = frag[5 * 64 + l];
        #pragma unroll
        for (int mt = 0; mt < 4; ++mt) {
            acc2[mt][0] = f32x4{b2a, b2a, b2a, b2a};
            acc2[mt][1] = f32x4{b2b, b2b, b2b, b2b};
            float av[8];
            #pragma unroll
            for (int j = 0; j < 8; ++j)
                av[j] = L[(mt * 16 + lm) * LSTR + lg * 8 + j];
            uint4 a2;
            a2.x = pk2(av[0], av[1]); a2.y = pk2(av[2], av[3]);
            a2.z = pk2(av[4], av[5]); a2.w = pk2(av[6], av[7]);
            acc2[mt][0] = __builtin_amdgcn_mfma_f32_16x16x32_bf16(as_bf(a2), as_bf(f20), acc2[mt][0], 0, 0, 0);
            acc2[mt][1] = __builtin_amdgcn_mfma_f32_16x16x32_bf16(as_bf(a2), as_bf(f21), acc2[mt][1], 0, 0, 0);
        }
        #pragma unroll
        for (int mt = 0; mt < 4; ++mt)
            #pragma unroll
            for (int nt = 0; nt < 2; ++nt)
                #pragma unroll
                for (int r = 0; r < 4; ++r)
                    L[(mt * 16 + lg * 4 + r) * LSTR + nt * 16 + lm] = acc2[mt][nt][r];
    }

    float wk[32];
    #pragma unroll
    for (int j = 0; j < 32; ++j) wk[j] = L[l * LSTR + j];

    {
        const uint4* hkp = (const uint4*)(hk_bf + (size_t)col * 64);
        const uint4* gp  = (const uint4*)(g_bf  + (size_t)row * 64);
        const float4 c0v = *(const float4*)(c0_in + (size_t)row * NHD);
        #pragma unroll
        for (int h = 0; h < NHD; ++h) {
            float s = 0.f;
            #pragma unroll
            for (int q = 0; q < 4; ++q) {
                const uint4 ku = hkp[h * 4 + q];
                const uint4 gu = gp[h * 4 + q];
                float ka, kb, ga, gb;
                unp2(ku.x, ka, kb); unp2(gu.x, ga, gb);
                s = fmaf(wk[q * 8 + 0] * ka, ga, s);
                s = fmaf(wk[q * 8 + 1] * kb, gb, s);
                unp2(ku.y, ka, kb); unp2(gu.y, ga, gb);
                s = fmaf(wk[q * 8 + 2] * ka, ga, s);
                s = fmaf(wk[q * 8 + 3] * kb, gb, s);
                unp2(ku.z, ka, kb); unp2(gu.z, ga, gb);
                s = fmaf(wk[q * 8 + 4] * ka, ga, s);
                s = fmaf(wk[q * 8 + 5] * kb, gb, s);
                unp2(ku.w, ka, kb); unp2(gu.w, ga, gb);
                s = fmaf(wk[q * 8 + 6] * ka, ga, s);
                s = fmaf(wk[q * 8 + 7] * kb, gb, s);
            }
            const float c0h = (h == 0) ? c0v.x : (h == 1) ? c0v.y : (h == 2) ? c0v.z : c0v.w;
            qkP[(size_t)h * EE + pos] = s + c0h;
        }
    }

    // ================= V path =================
    {
        const float b1a = wv1_b[lm], b1b = wv1_b[16 + lm];
        f32x4 acc[4][2];
        #pragma unroll
        for (int mt = 0; mt < 4; ++mt) {
            acc[mt][0] = f32x4{b1a, b1a, b1a, b1a};
            acc[mt][1] = f32x4{b1b, b1b, b1b, b1b};
        }
        const uint4 f00 = frag[6 * 64 + l], f01 = frag[7 * 64 + l];
        const uint4 f10 = frag[8 * 64 + l], f11 = frag[9 * 64 + l];
        #pragma unroll
        for (int mt = 0; mt < 4; ++mt) {
            acc[mt][0] = __builtin_amdgcn_mfma_f32_16x16x32_bf16(as_bf(eaf[mt][0]), as_bf(f00), acc[mt][0], 0, 0, 0);
            acc[mt][1] = __builtin_amdgcn_mfma_f32_16x16x32_bf16(as_bf(eaf[mt][0]), as_bf(f01), acc[mt][1], 0, 0, 0);
            acc[mt][0] = __builtin_amdgcn_mfma_f32_16x16x32_bf16(as_bf(eaf[mt][1]), as_bf(f10), acc[mt][0], 0, 0, 0);
            acc[mt][1] = __builtin_amdgcn_mfma_f32_16x16x32_bf16(as_bf(eaf[mt][1]), as_bf(f11), acc[mt][1], 0, 0, 0);
        }
        #pragma unroll
        for (int mt = 0; mt < 4; ++mt)
            #pragma unroll
            for (int nt = 0; nt < 2; ++nt)
                #pragma unroll
                for (int r = 0; r < 4; ++r)
                    L[(mt * 16 + lg * 4 + r) * LSTR + nt * 16 + lm] = ssp_f(acc[mt][nt][r]);

        const float b2a = wv2_b[lm], b2b = wv2_b[16 + lm];
        f32x4 acc2[4][2];
        const uint4 f20 = frag[10 * 64 + l], f21 = frag[11 * 64 + l];
        #pragma unroll
        for (int mt = 0; mt < 4; ++mt) {
            acc2[mt][0] = f32x4{b2a, b2a, b2a, b2a};
            acc2[mt][1] = f32x4{b2b, b2b, b2b, b2b};
            float av[8];
            #pragma unroll
            for (int j = 0; j < 8; ++j)
                av[j] = L[(mt * 16 + lm) * LSTR + lg * 8 + j];
            uint4 a2;
            a2.x = pk2(av[0], av[1]); a2.y = pk2(av[2], av[3]);
            a2.z = pk2(av[4], av[5]); a2.w = pk2(av[6], av[7]);
            acc2[mt][0] = __builtin_amdgcn_mfma_f32_16x16x32_bf16(as_bf(a2), as_bf(f20), acc2[mt][0], 0, 0, 0);
            acc2[mt][1] = __builtin_amdgcn_mfma_f32_16x16x32_bf16(as_bf(a2), as_bf(f21), acc2[mt][1], 0, 0, 0);
        }
        #pragma unroll
        for (int mt = 0; mt < 4; ++mt)
            #pragma unroll
            for (int nt = 0; nt < 2; ++nt)
                #pragma unroll
                for (int r = 0; r < 4; ++r)
                    L[(mt * 16 + lg * 4 + r) * LSTR + nt * 16 + lm] = acc2[mt][nt][r];
    }

    #pragma unroll
    for (int k = 0; k < 16; ++k) {
        const int f = k * 64 + l;
        const int pr = f >> 4, i = f & 15;
        wvP[(size_t)e0 * 16 + f] = pk2(L[pr * LSTR + 2 * i], L[pr * LSTR + 2 * i + 1]);
    }
}

// ---------------- K3a: aggregation only (low VGPR, high occupancy) ----------
__global__ __launch_bounds__(256) void k_aggr(
    const float* __restrict__ qkP, const unsigned* __restrict__ wvP,
    const unsigned* __restrict__ hv_bf, const int* __restrict__ colv,
    const int* __restrict__ base, const int* __restrict__ deg,
    float* __restrict__ uP)
{
    const int w = threadIdx.x >> 6, l = threadIdx.x & 63;
    const int h = l >> 4, i = l & 15;

    for (int n = blockIdx.x * 4 + w; n < NN; n += 2048 * 4) {
        const int b0 = base[n];
        const int dn = deg[n];
        float acc0 = 0.f, acc1 = 0.f;
        if (dn > 0) {
            const float* qkh = qkP + (size_t)h * EE + b0;
            const int emax = b0 + dn - 1;
            float m = -3.0e38f;
            for (int c = i; c < dn; c += 16) m = fmaxf(m, qkh[c]);
            #pragma unroll
            for (int off = 1; off < 16; off <<= 1)
                m = fmaxf(m, __shfl_xor(m, off));
            float den = 0.f;
            for (int c = i; c < dn; c += 16) den += __expf(qkh[c] - m);
            #pragma unroll
            for (int off = 1; off < 16; off <<= 1) den += __shfl_xor(den, off);
            const float rden = (den > 0.f) ? 1.0f / den : 0.f;
            for (int c0 = 0; c0 < dn; c0 += 16) {
                const int tn = (dn - c0 < 16) ? (dn - c0) : 16;
                float ex = 0.f; int cq = 0;
                if (i < tn) {
                    ex = __expf(qkh[c0 + i] - m) * rden;
                    cq = colv[b0 + c0 + i];
                }
                const int t4 = (tn + 3) & ~3;
                for (int i2 = 0; i2 < t4; i2 += 4) {
                    #pragma unroll
                    for (int u = 0; u < 4; ++u) {
                        const int src = (l & 48) | (i2 + u);
                        const float wgt = __shfl(ex, src);
                        const int ce = __shfl(cq, src);
                        int ep = b0 + c0 + i2 + u;
                        ep = (ep > emax) ? emax : ep;
                        const unsigned hvv = hv_bf[(size_t)ce * 64 + l];
                        const unsigned wvv = wvP[(size_t)ep * 16 + i];
                        float ha, hb, wa, wb;
                        unp2(hvv, ha, hb); unp2(wvv, wa, wb);
                        acc0 = fmaf(wgt, wa * ha, acc0);
                        acc1 = fmaf(wgt, wb * hb, acc1);
                    }
                }
            }
        }
        *(float2*)(uP + (size_t)n * HD + 2 * l) = make_float2(acc0, acc1);
    }
}

// ---------------- K3b: wvl matvec + residual + LN2 + ssp -> x2, sbf ---------
__global__ __launch_bounds__(256) void k_tail_a(
    const float* __restrict__ x, const float* __restrict__ uP,
    const int* __restrict__ deg,
    const float* __restrict__ wvl_w, const float* __restrict__ wvl_b,
    const float* __restrict__ ln2_g, const float* __restrict__ ln2_b,
    float* __restrict__ x2P, unsigned* __restrict__ sbf)
{
    const int w = threadIdx.x >> 6, l = threadIdx.x & 63;
    const int h = l >> 4, i = l & 15;
    const int t0 = 2 * l;
    const float2 lg2 = *(const float2*)(ln2_g + t0);
    const float2 lb2 = *(const float2*)(ln2_b + t0);
    const int j0 = 2 * i;

    for (int n = blockIdx.x * 4 + w; n < NN; n += 2048 * 4) {
        const int dn = deg[n];
        const float2 xv = *(const float2*)(x + (size_t)n * HD + t0);

        float ag0 = 0.f, ag1 = 0.f;
        if (dn > 0) {
            const float2 wb = *(const float2*)(wvl_b + j0);
            ag0 = wb.x; ag1 = wb.y;
            const float4* up = (const float4*)(uP + (size_t)n * HD + h * HH);
            const float4* r0 = (const float4*)(wvl_w + (size_t)j0 * HH);
            const float4* r1 = (const float4*)(wvl_w + (size_t)(j0 + 1) * HH);
            #pragma unroll
            for (int q = 0; q < 8; ++q) {
                const float4 u = up[q];
                const float4 a = r0[q], b = r1[q];
                ag0 = fmaf(u.x, a.x, ag0); ag0 = fmaf(u.y, a.y, ag0);
                ag0 = fmaf(u.z, a.z, ag0); ag0 = fmaf(u.w, a.w, ag0);
                ag1 = fmaf(u.x, b.x, ag1); ag1 = fmaf(u.y, b.y, ag1);
                ag1 = fmaf(u.z, b.z, ag1); ag1 = fmaf(u.w, b.w, ag1);
            }
        }
        const float x20 = ag0 + xv.x;
        const float x21 = ag1 + xv.y;

        float s1 = x20 + x21, s2 = x20 * x20 + x21 * x21;
        #pragma unroll
        for (int off = 1; off < 64; off <<= 1) {
            s1 += __shfl_xor(s1, off);
            s2 += __shfl_xor(s2, off);
        }
        const float mean = s1 * (1.0f / HD);
        const float var  = s2 * (1.0f / HD) - mean * mean;
        const float rstd = rsqrtf(var + 1e-5f);
        const float ss0 = ssp_f((x20 - mean) * rstd * lg2.x + lb2.x);
        const float ss1 = ssp_f((x21 - mean) * rstd * lg2.y + lb2.y);

        *(float2*)(x2P + (size_t)n * HD + t0) = make_float2(x20, x21);
        sbf[(size_t)n * 64 + l] = pk2(ss0, ss1);
    }
}

// ---------------- K3c: MFMA out-GEMM: out = sbf @ out_w^T + out_b + x2 ------
__global__ __launch_bounds__(256) void k_tail_gemm(
    const unsigned short* __restrict__ sbf, const float* __restrict__ x2P,
    const uint4* __restrict__ owf, const float* __restrict__ out_b,
    float* __restrict__ out)
{
    const int w = threadIdx.x >> 6, l = threadIdx.x & 63;
    const int lm = l & 15, lg = l >> 4;
    const int tile = blockIdx.x * 4 + w;
    if (tile * 16 >= NN) return;
    const int n0 = tile * 16;

    uint4 af[4];
    #pragma unroll
    for (int kt = 0; kt < 4; ++kt)
        af[kt] = *(const uint4*)(sbf + (size_t)(n0 + lm) * HD + kt * 32 + lg * 8);

    f32x4 acc[8];
    #pragma unroll
    for (int nt = 0; nt < 8; ++nt) {
        const float b = out_b[nt * 16 + lm];
        acc[nt] = f32x4{b, b, b, b};
    }
    #pragma unroll
    for (int kt = 0; kt < 4; ++kt) {
        #pragma unroll
        for (int nt = 0; nt < 8; ++nt)
            acc[nt] = __builtin_amdgcn_mfma_f32_16x16x32_bf16(
                as_bf(af[kt]), as_bf(owf[(nt * 4 + kt) * 64 + l]), acc[nt], 0, 0, 0);
    }
    #pragma unroll
    for (int nt = 0; nt < 8; ++nt)
        #pragma unroll
        for (int r = 0; r < 4; ++r) {
            const size_t idx = (size_t)(n0 + lg * 4 + r) * HD + nt * 16 + lm;
            out[idx] = acc[nt][r] + x2P[idx];
        }
}

extern "C" void kernel_launch(void* const* d_in, const int* in_sizes, int n_in,
                              void* d_out, int out_size, void* d_ws, size_t ws_size,
                              hipStream_t stream) {
    const float* x         = (const float*)d_in[0];
    const float* edge_attr = (const float*)d_in[1];
    const int*   edge_index= (const int*)  d_in[2];
    const float* k_w   = (const float*)d_in[3];
    const float* q_w   = (const float*)d_in[4];
    const float* v_w   = (const float*)d_in[5];
    const float* wk1_w = (const float*)d_in[6];
    const float* wk1_b = (const float*)d_in[7];
    const float* wk2_w = (const float*)d_in[8];
    const float* wk2_b = (const float*)d_in[9];
    const float* wkl_w = (const float*)d_in[10];
    const float* wkl_b = (const float*)d_in[11];
    const float* wv1_w = (const float*)d_in[12];
    const float* wv1_b = (const float*)d_in[13];
    const float* wv2_w = (const float*)d_in[14];
    const float* wv2_b = (const float*)d_in[15];
    const float* wvl_w = (const float*)d_in[16];
    const float* wvl_b = (const float*)d_in[17];
    const float* out_w = (const float*)d_in[18];
    const float* out_b = (const float*)d_in[19];
    const float* ln1_g = (const float*)d_in[20];
    const float* ln1_b = (const float*)d_in[21];
    const float* ln2_g = (const float*)d_in[22];
    const float* ln2_b = (const float*)d_in[23];

    char* ws = (char*)d_ws;
    unsigned* hk_bf = (unsigned*)ws;            ws += (size_t)NN * 64 * 4;
    unsigned* hv_bf = (unsigned*)ws;            ws += (size_t)NN * 64 * 4;
    unsigned* g_bf  = (unsigned*)ws;            ws += (size_t)NN * 64 * 4;
    float* c0  = (float*)ws;                    ws += (size_t)NN * NHD * 4;
    float* qkP = (float*)ws;                    ws += (size_t)NHD * EE * 4;
    unsigned* wvP = (unsigned*)ws;              ws += (size_t)EE * 16 * 4;
    unsigned* ea_bf = (unsigned*)ws;            ws += (size_t)EE * 32 * 4;
    uint4* fragbuf = (uint4*)ws;                ws += (size_t)12 * 64 * 16;
    uint4* owfbuf  = (uint4*)ws;                ws += (size_t)32 * 64 * 16;
    float* uP = (float*)ws;                     ws += (size_t)NN * HD * 4;
    float* x2P = (float*)ws;                    ws += (size_t)NN * HD * 4;
    unsigned* sbf = (unsigned*)ws;              ws += (size_t)NN * 64 * 4;
    int* deg    = (int*)ws;                     ws += (size_t)NN * 4;
    int* base   = (int*)ws;                     ws += (size_t)NN * 4;
    int* cursor = (int*)ws;                     ws += (size_t)NN * 4;
    int* bsum   = (int*)ws;                     ws += (size_t)SCAN_B * 4;
    int* eidx   = (int*)ws;                     ws += (size_t)EE * 4;
    int* rowv   = (int*)ws;                     ws += (size_t)EE * 4;
    int* colv   = (int*)ws;                     ws += (size_t)EE * 4;

    (void)hipMemsetAsync(deg, 0, (size_t)NN * 4, stream);

    k_wfrag<<<1, 256, 0, stream>>>(wk1_w, wk2_w, wv1_w, wv2_w, fragbuf);
    k_owfrag<<<1, 256, 0, stream>>>(out_w, owfbuf);
    k_node_prep<<<1024, 256, 0, stream>>>(x, k_w, q_w, v_w, wkl_w, wkl_b,
        ln1_g, ln1_b, hk_bf, hv_bf, g_bf, c0);
    k_deg<<<1024, 256, 0, stream>>>(edge_index, deg);
    k_scan_block<<<NBLK, SCAN_B, 0, stream>>>(deg, base, bsum);
    k_scan_top<<<1, SCAN_B, 0, stream>>>(bsum);
    k_scan_add<<<NBLK, SCAN_B, 0, stream>>>(base, bsum, cursor);
    k_scatter<<<1024, 256, 0, stream>>>(edge_index, cursor, eidx, rowv, colv);
    k_ea_csr<<<2048, 256, 0, stream>>>(edge_attr, eidx, ea_bf);
    k_edge_mfma<<<EE / 256, 256, 0, stream>>>(ea_bf, rowv, colv,
        hk_bf, g_bf, c0, fragbuf,
        wk1_b, wk2_b, wv1_b, wv2_b, qkP, wvP);
    k_aggr<<<2048, 256, 0, stream>>>(qkP, wvP, hv_bf, colv, base, deg, uP);
    k_tail_a<<<2048, 256, 0, stream>>>(x, uP, deg, wvl_w, wvl_b,
        ln2_g, ln2_b, x2P, sbf);
    k_tail_gemm<<<(NN / 16 + 3) / 4, 256, 0, stream>>>(
        (const unsigned short*)sbf, x2P, owfbuf, out_b, (float*)d_out);
}

// Round 11
// 482.011 us; speedup vs baseline: 6.4863x; 1.1429x over previous
//
#include <hip/hip_runtime.h>
#include <math.h>

#define NN 50000
#define EE 640000
#define HD 128
#define ECD 64
#define NHD 4
#define HH 32
#define SCAN_B 256
#define NBLK ((NN + SCAN_B - 1) / SCAN_B)   // 196
#define LSTR 33   // LDS row stride in floats (64 edges x 32 vals, +1 pad)

typedef short bf16x8 __attribute__((ext_vector_type(8)));
typedef float f32x4 __attribute__((ext_vector_type(4)));

// fast shifted-softplus: native v_exp/v_log, ~1ulp
__device__ __forceinline__ float ssp_f(float v) {
    return fmaxf(v, 0.0f) + __logf(1.0f + __expf(-fabsf(v))) - 0.69314718055994531f;
}
// RNE bf16 (used for persistent tables)
__device__ __forceinline__ unsigned f2bf_u(float f) {
    unsigned u = __float_as_uint(f);
    unsigned r = ((u >> 16) & 1u) + 0x7FFFu;
    return (u + r) >> 16;
}
__device__ __forceinline__ unsigned pk2(float a, float b) {
    return f2bf_u(a) | (f2bf_u(b) << 16);
}
// fast bf16 (round-half-up) for hot edge kernel
__device__ __forceinline__ unsigned f2bf_f(float f) {
    return (__float_as_uint(f) + 0x8000u) >> 16;
}
__device__ __forceinline__ unsigned pk2f(float a, float b) {
    return f2bf_f(a) | (f2bf_f(b) << 16);
}
__device__ __forceinline__ void unp2(unsigned u, float& a, float& b) {
    a = __uint_as_float(u << 16);
    b = __uint_as_float(u & 0xffff0000u);
}
__device__ __forceinline__ bf16x8 as_bf(uint4 u) {
    union { uint4 a; bf16x8 b; } c; c.a = u; return c.b;
}

// ---------------- K1: LN1 + projections + g/c0 (wave-per-node, persistent) ----
__global__ __launch_bounds__(256) void k_node_prep(
    const float* __restrict__ x, const float* __restrict__ k_w,
    const float* __restrict__ q_w, const float* __restrict__ v_w,
    const float* __restrict__ wkl_w, const float* __restrict__ wkl_b,
    const float* __restrict__ ln1_g, const float* __restrict__ ln1_b,
    unsigned* __restrict__ hk_bf, unsigned* __restrict__ hv_bf,
    unsigned* __restrict__ g_bf, float* __restrict__ c0_out)
{
    __shared__ float wklT[HH * 36];
    __shared__ float ybuf[4][HD];
    for (int idx = threadIdx.x; idx < HH * HH; idx += 256)
        wklT[(idx & 31) * 36 + (idx >> 5)] = wkl_w[idx];
    __syncthreads();

    const int w = threadIdx.x >> 6, l = threadIdx.x & 63;
    const int h = l >> 4, i16 = l & 15;
    const int t0 = 2 * l;
    const float2 lg2 = *(const float2*)(ln1_g + t0);
    const float2 lb2 = *(const float2*)(ln1_b + t0);
    const float2 wb2 = *(const float2*)(wkl_b + 2 * i16);
    float* yb = ybuf[w];

    for (int n = blockIdx.x * 4 + w; n < NN; n += 1024 * 4) {
        const float2 xv = *(const float2*)(x + (size_t)n * HD + t0);
        float s1 = xv.x + xv.y;
        float s2 = xv.x * xv.x + xv.y * xv.y;
        #pragma unroll
        for (int off = 1; off < 64; off <<= 1) {
            s1 += __shfl_xor(s1, off);
            s2 += __shfl_xor(s2, off);
        }
        const float mean = s1 * (1.0f / HD);
        const float var  = s2 * (1.0f / HD) - mean * mean;
        const float rstd = rsqrtf(var + 1e-5f);
        const float y0 = (xv.x - mean) * rstd * lg2.x + lb2.x;
        const float y1 = (xv.y - mean) * rstd * lg2.y + lb2.y;
        *(float2*)(yb + t0) = make_float2(y0, y1);

        float yr[32];
        {
            const float4* yp = (const float4*)(yb + h * HH);
            #pragma unroll
            for (int q = 0; q < 8; ++q) {
                const float4 v = yp[q];
                yr[q*4+0] = v.x; yr[q*4+1] = v.y; yr[q*4+2] = v.z; yr[q*4+3] = v.w;
            }
        }
        float ak0=0,ak1=0,aq0=0,aq1=0,av0=0,av1=0;
        {
            const float4* kr0 = (const float4*)(k_w + (size_t)t0 * HH);
            const float4* kr1 = (const float4*)(k_w + (size_t)(t0+1) * HH);
            const float4* qr0 = (const float4*)(q_w + (size_t)t0 * HH);
            const float4* qr1 = (const float4*)(q_w + (size_t)(t0+1) * HH);
            const float4* vr0 = (const float4*)(v_w + (size_t)t0 * HH);
            const float4* vr1 = (const float4*)(v_w + (size_t)(t0+1) * HH);
            #pragma unroll
            for (int q = 0; q < 8; ++q) {
                const float4 a = kr0[q], b = kr1[q], c = qr0[q], d = qr1[q];
                const float4 e = vr0[q], f = vr1[q];
                ak0 = fmaf(yr[q*4+0], a.x, ak0); ak0 = fmaf(yr[q*4+1], a.y, ak0);
                ak0 = fmaf(yr[q*4+2], a.z, ak0); ak0 = fmaf(yr[q*4+3], a.w, ak0);
                ak1 = fmaf(yr[q*4+0], b.x, ak1); ak1 = fmaf(yr[q*4+1], b.y, ak1);
                ak1 = fmaf(yr[q*4+2], b.z, ak1); ak1 = fmaf(yr[q*4+3], b.w, ak1);
                aq0 = fmaf(yr[q*4+0], c.x, aq0); aq0 = fmaf(yr[q*4+1], c.y, aq0);
                aq0 = fmaf(yr[q*4+2], c.z, aq0); aq0 = fmaf(yr[q*4+3], c.w, aq0);
                aq1 = fmaf(yr[q*4+0], d.x, aq1); aq1 = fmaf(yr[q*4+1], d.y, aq1);
                aq1 = fmaf(yr[q*4+2], d.z, aq1); aq1 = fmaf(yr[q*4+3], d.w, aq1);
                av0 = fmaf(yr[q*4+0], e.x, av0); av0 = fmaf(yr[q*4+1], e.y, av0);
                av0 = fmaf(yr[q*4+2], e.z, av0); av0 = fmaf(yr[q*4+3], e.w, av0);
                av1 = fmaf(yr[q*4+0], f.x, av1); av1 = fmaf(yr[q*4+1], f.y, av1);
                av1 = fmaf(yr[q*4+2], f.z, av1); av1 = fmaf(yr[q*4+3], f.w, av1);
            }
        }
        hk_bf[(size_t)n * 64 + l] = pk2(ak0, ak1);
        hv_bf[(size_t)n * 64 + l] = pk2(av0, av1);

        *(float2*)(yb + t0) = make_float2(aq0, aq1);
        float hqr[32];
        {
            const float4* hp = (const float4*)(yb + h * HH);
            #pragma unroll
            for (int q = 0; q < 8; ++q) {
                const float4 v = hp[q];
                hqr[q*4+0] = v.x; hqr[q*4+1] = v.y; hqr[q*4+2] = v.z; hqr[q*4+3] = v.w;
            }
        }
        float p = aq0 * wb2.x + aq1 * wb2.y;
        #pragma unroll
        for (int off = 1; off < 16; off <<= 1) p += __shfl_xor(p, off);
        if (i16 == 0) c0_out[n * NHD + h] = p;

        const int k0 = 2 * i16;
        float g0 = 0.f, g1 = 0.f;
        {
            const float4* w0 = (const float4*)(wklT + k0 * 36);
            const float4* w1 = (const float4*)(wklT + (k0 + 1) * 36);
            #pragma unroll
            for (int q = 0; q < 8; ++q) {
                const float4 a = w0[q], b = w1[q];
                g0 = fmaf(hqr[q*4+0], a.x, g0); g0 = fmaf(hqr[q*4+1], a.y, g0);
                g0 = fmaf(hqr[q*4+2], a.z, g0); g0 = fmaf(hqr[q*4+3], a.w, g0);
                g1 = fmaf(hqr[q*4+0], b.x, g1); g1 = fmaf(hqr[q*4+1], b.y, g1);
                g1 = fmaf(hqr[q*4+2], b.z, g1); g1 = fmaf(hqr[q*4+3], b.w, g1);
            }
        }
        g_bf[(size_t)n * 64 + l] = pk2(g0, g1);
    }
}

// ---------------- CSR build ----------------
__global__ __launch_bounds__(256) void k_deg(
    const int* __restrict__ edge_index, int* __restrict__ deg)
{
    for (int e = blockIdx.x * blockDim.x + threadIdx.x; e < EE;
         e += gridDim.x * blockDim.x)
        atomicAdd(&deg[edge_index[e]], 1);
}

__global__ __launch_bounds__(SCAN_B) void k_scan_block(
    const int* __restrict__ deg, int* __restrict__ base, int* __restrict__ bsum)
{
    const int i = blockIdx.x * SCAN_B + threadIdx.x;
    const int v = (i < NN) ? deg[i] : 0;
    __shared__ int s[SCAN_B];
    s[threadIdx.x] = v;
    __syncthreads();
    for (int off = 1; off < SCAN_B; off <<= 1) {
        int t = (threadIdx.x >= off) ? s[threadIdx.x - off] : 0;
        __syncthreads();
        s[threadIdx.x] += t;
        __syncthreads();
    }
    if (i < NN) base[i] = s[threadIdx.x] - v;
    if (threadIdx.x == SCAN_B - 1) bsum[blockIdx.x] = s[SCAN_B - 1];
}

__global__ __launch_bounds__(SCAN_B) void k_scan_top(int* __restrict__ bsum)
{
    const int i = threadIdx.x;
    const int v = (i < NBLK) ? bsum[i] : 0;
    __shared__ int s[SCAN_B];
    s[i] = v;
    __syncthreads();
    for (int off = 1; off < SCAN_B; off <<= 1) {
        int t = (i >= off) ? s[i - off] : 0;
        __syncthreads();
        s[i] += t;
        __syncthreads();
    }
    if (i < NBLK) bsum[i] = s[i] - v;
}

__global__ __launch_bounds__(SCAN_B) void k_scan_add(
    int* __restrict__ base, const int* __restrict__ bsum, int* __restrict__ cursor)
{
    const int i = blockIdx.x * SCAN_B + threadIdx.x;
    if (i < NN) {
        const int b = base[i] + bsum[i >> 8];
        base[i] = b;
        cursor[i] = b;
    }
}

__global__ __launch_bounds__(256) void k_scatter(
    const int* __restrict__ edge_index, int* __restrict__ cursor,
    int* __restrict__ eidx, int* __restrict__ rowv, int* __restrict__ colv)
{
    for (int e = blockIdx.x * blockDim.x + threadIdx.x; e < EE;
         e += gridDim.x * blockDim.x) {
        const int r = edge_index[e];
        const int pos = atomicAdd(&cursor[r], 1);
        eidx[pos] = e;
        rowv[pos] = r;
        colv[pos] = edge_index[EE + e];
    }
}

// ---------------- ea -> bf16, permuted to CSR order (grid-stride) ----------
__global__ __launch_bounds__(256) void k_ea_csr(
    const float* __restrict__ ea, const int* __restrict__ eidx,
    unsigned* __restrict__ ea_bf)
{
    for (int i = blockIdx.x * 256 + threadIdx.x; i < EE * 32;
         i += 2048 * 256) {
        const int pos = i >> 5, u = i & 31;
        const int e = eidx[pos];
        const float2 v = *(const float2*)(ea + (size_t)e * ECD + u * 2);
        ea_bf[(size_t)pos * 32 + u] = pk2(v.x, v.y);
    }
}

// ---------------- weight fragment packer (1 block) ----------------
__global__ __launch_bounds__(256) void k_wfrag(
    const float* __restrict__ wk1_w, const float* __restrict__ wk2_w,
    const float* __restrict__ wv1_w, const float* __restrict__ wv2_w,
    uint4* __restrict__ frag)
{
    const int t = threadIdx.x;
    const int l = t & 63;
    const int lm = l & 15, lg = l >> 4;
    {
        const int f = t >> 6;          // 0..3
        const int kt = f >> 1, nt = f & 1;
        const int out = nt * 16 + lm;
        uint4 a, b;
        unsigned ra[4], rb[4];
        #pragma unroll
        for (int p = 0; p < 4; ++p) {
            const int in0 = kt * 32 + lg * 8 + 2 * p;
            ra[p] = pk2(wk1_w[(size_t)out * ECD + in0], wk1_w[(size_t)out * ECD + in0 + 1]);
            rb[p] = pk2(wv1_w[(size_t)out * ECD + in0], wv1_w[(size_t)out * ECD + in0 + 1]);
        }
        a.x = ra[0]; a.y = ra[1]; a.z = ra[2]; a.w = ra[3];
        b.x = rb[0]; b.y = rb[1]; b.z = rb[2]; b.w = rb[3];
        frag[f * 64 + l] = a;
        frag[(6 + f) * 64 + l] = b;
    }
    if (t < 128) {
        const int nt = t >> 6;
        const int out = nt * 16 + lm;
        uint4 a, b;
        unsigned ra[4], rb[4];
        #pragma unroll
        for (int p = 0; p < 4; ++p) {
            const int in0 = lg * 8 + 2 * p;
            ra[p] = pk2(wk2_w[(size_t)out * HH + in0], wk2_w[(size_t)out * HH + in0 + 1]);
            rb[p] = pk2(wv2_w[(size_t)out * HH + in0], wv2_w[(size_t)out * HH + in0 + 1]);
        }
        a.x = ra[0]; a.y = ra[1]; a.z = ra[2]; a.w = ra[3];
        b.x = rb[0]; b.y = rb[1]; b.z = rb[2]; b.w = rb[3];
        frag[(4 + nt) * 64 + l] = a;
        frag[(10 + nt) * 64 + l] = b;
    }
}

// ---------------- out_w fragment packer: owf[nt*4+kt][64] ----------------
__global__ __launch_bounds__(256) void k_owfrag(
    const float* __restrict__ out_w, uint4* __restrict__ owf)
{
    const int t = threadIdx.x;
    const int l = t & 63;
    const int lm = l & 15, lg = l >> 4;
    #pragma unroll
    for (int it = 0; it < 8; ++it) {
        const int f = (t >> 6) + it * 4;   // 0..31 = nt*4+kt
        const int nt = f >> 2, kt = f & 3;
        const int n = nt * 16 + lm;
        unsigned r[4];
        #pragma unroll
        for (int p = 0; p < 4; ++p) {
            const int k0 = kt * 32 + lg * 8 + 2 * p;
            r[p] = pk2(out_w[(size_t)n * HD + k0], out_w[(size_t)n * HD + k0 + 1]);
        }
        uint4 o; o.x = r[0]; o.y = r[1]; o.z = r[2]; o.w = r[3];
        owf[f * 64 + l] = o;
    }
}

// ---------------- K2: MFMA edge kernel (wave = 64 edges) --------------------
__global__ __launch_bounds__(256) void k_edge_mfma(
    const unsigned* __restrict__ ea_bf,
    const int* __restrict__ rowv, const int* __restrict__ colv,
    const unsigned* __restrict__ hk_bf, const unsigned* __restrict__ g_bf,
    const float* __restrict__ c0_in, const uint4* __restrict__ frag,
    const float* __restrict__ wk1_b, const float* __restrict__ wk2_b,
    const float* __restrict__ wv1_b, const float* __restrict__ wv2_b,
    float* __restrict__ qkP, unsigned* __restrict__ wvP)
{
    __shared__ float lds[4][64 * LSTR];
    const int w = threadIdx.x >> 6, l = threadIdx.x & 63;
    const int lm = l & 15, lg = l >> 4;
    float* L = lds[w];
    const int e0 = blockIdx.x * 256 + w * 64;
    const int pos = e0 + l;
    const int row = rowv[pos];
    const int col = colv[pos];

    uint4 eaf[4][2];
    #pragma unroll
    for (int mt = 0; mt < 4; ++mt)
        #pragma unroll
        for (int kt = 0; kt < 2; ++kt)
            eaf[mt][kt] = *(const uint4*)(ea_bf +
                (size_t)(e0 + mt * 16 + lm) * 32 + kt * 16 + lg * 4);

    // ================= K path =================
    {
        const float b1a = wk1_b[lm], b1b = wk1_b[16 + lm];
        f32x4 acc[4][2];
        #pragma unroll
        for (int mt = 0; mt < 4; ++mt) {
            acc[mt][0] = f32x4{b1a, b1a, b1a, b1a};
            acc[mt][1] = f32x4{b1b, b1b, b1b, b1b};
        }
        const uint4 f00 = frag[0 * 64 + l], f01 = frag[1 * 64 + l];
        const uint4 f10 = frag[2 * 64 + l], f11 = frag[3 * 64 + l];
        #pragma unroll
        for (int mt = 0; mt < 4; ++mt) {
            acc[mt][0] = __builtin_amdgcn_mfma_f32_16x16x32_bf16(as_bf(eaf[mt][0]), as_bf(f00), acc[mt][0], 0, 0, 0);
            acc[mt][1] = __builtin_amdgcn_mfma_f32_16x16x32_bf16(as_bf(eaf[mt][0]), as_bf(f01), acc[mt][1], 0, 0, 0);
            acc[mt][0] = __builtin_amdgcn_mfma_f32_16x16x32_bf16(as_bf(eaf[mt][1]), as_bf(f10), acc[mt][0], 0, 0, 0);
            acc[mt][1] = __builtin_amdgcn_mfma_f32_16x16x32_bf16(as_bf(eaf[mt][1]), as_bf(f11), acc[mt][1], 0, 0, 0);
        }
        #pragma unroll
        for (int mt = 0; mt < 4; ++mt)
            #pragma unroll
            for (int nt = 0; nt < 2; ++nt)
                #pragma unroll
                for (int r = 0; r < 4; ++r)
                    L[(mt * 16 + lg * 4 + r) * LSTR + nt * 16 + lm] = ssp_f(acc[mt][nt][r]);

        const float b2a = wk2_b[lm], b2b = wk2_b[16 + lm];
        f32x4 acc2[4][2];
        const uint4 f20 = frag[4 * 64 + l], f21 = frag[5 * 64 + l];
        #pragma unroll
        for (int mt = 0; mt < 4; ++mt) {
            acc2[mt][0] = f32x4{b2a, b2a, b2a, b2a};
            acc2[mt][1] = f32x4{b2b, b2b, b2b, b2b};
            float av[8];
            #pragma unroll
            for (int j = 0; j < 8; ++j)
                av[j] = L[(mt * 16 + lm) * LSTR + lg * 8 + j];
            uint4 a2;
            a2.x = pk2f(av[0], av[1]); a2.y = pk2f(av[2], av[3]);
            a2.z = pk2f(av[4], av[5]); a2.w = pk2f(av[6], av[7]);
            acc2[mt][0] = __builtin_amdgcn_mfma_f32_16x16x32_bf16(as_bf(a2), as_bf(f20), acc2[mt][0], 0, 0, 0);
            acc2[mt][1] = __builtin_amdgcn_mfma_f32_16x16x32_bf16(as_bf(a2), as_bf(f21), acc2[mt][1], 0, 0, 0);
        }
        #pragma unroll
        for (int mt = 0; mt < 4; ++mt)
            #pragma unroll
            for (int nt = 0; nt < 2; ++nt)
                #pragma unroll
                for (int r = 0; r < 4; ++r)
                    L[(mt * 16 + lg * 4 + r) * LSTR + nt * 16 + lm] = acc2[mt][nt][r];
    }

    float wk[32];
    #pragma unroll
    for (int j = 0; j < 32; ++j) wk[j] = L[l * LSTR + j];

    {
        const uint4* hkp = (const uint4*)(hk_bf + (size_t)col * 64);
        const uint4* gp  = (const uint4*)(g_bf  + (size_t)row * 64);
        const float4 c0v = *(const float4*)(c0_in + (size_t)row * NHD);
        #pragma unroll
        for (int h = 0; h < NHD; ++h) {
            float s = 0.f;
            #pragma unroll
            for (int q = 0; q < 4; ++q) {
                const uint4 ku = hkp[h * 4 + q];
                const uint4 gu = gp[h * 4 + q];
                float ka, kb, ga, gb;
                unp2(ku.x, ka, kb); unp2(gu.x, ga, gb);
                s = fmaf(wk[q * 8 + 0] * ka, ga, s);
                s = fmaf(wk[q * 8 + 1] * kb, gb, s);
                unp2(ku.y, ka, kb); unp2(gu.y, ga, gb);
                s = fmaf(wk[q * 8 + 2] * ka, ga, s);
                s = fmaf(wk[q * 8 + 3] * kb, gb, s);
                unp2(ku.z, ka, kb); unp2(gu.z, ga, gb);
                s = fmaf(wk[q * 8 + 4] * ka, ga, s);
                s = fmaf(wk[q * 8 + 5] * kb, gb, s);
                unp2(ku.w, ka, kb); unp2(gu.w, ga, gb);
                s = fmaf(wk[q * 8 + 6] * ka, ga, s);
                s = fmaf(wk[q * 8 + 7] * kb, gb, s);
            }
            const float c0h = (h == 0) ? c0v.x : (h == 1) ? c0v.y : (h == 2) ? c0v.z : c0v.w;
            qkP[(size_t)h * EE + pos] = s + c0h;
        }
    }

    // ================= V path =================
    {
        const float b1a = wv1_b[lm], b1b = wv1_b[16 + lm];
        f32x4 acc[4][2];
        #pragma unroll
        for (int mt = 0; mt < 4; ++mt) {
            acc[mt][0] = f32x4{b1a, b1a, b1a, b1a};
            acc[mt][1] = f32x4{b1b, b1b, b1b, b1b};
        }
        const uint4 f00 = frag[6 * 64 + l], f01 = frag[7 * 64 + l];
        const uint4 f10 = frag[8 * 64 + l], f11 = frag[9 * 64 + l];
        #pragma unroll
        for (int mt = 0; mt < 4; ++mt) {
            acc[mt][0] = __builtin_amdgcn_mfma_f32_16x16x32_bf16(as_bf(eaf[mt][0]), as_bf(f00), acc[mt][0], 0, 0, 0);
            acc[mt][1] = __builtin_amdgcn_mfma_f32_16x16x32_bf16(as_bf(eaf[mt][0]), as_bf(f01), acc[mt][1], 0, 0, 0);
            acc[mt][0] = __builtin_amdgcn_mfma_f32_16x16x32_bf16(as_bf(eaf[mt][1]), as_bf(f10), acc[mt][0], 0, 0, 0);
            acc[mt][1] = __builtin_amdgcn_mfma_f32_16x16x32_bf16(as_bf(eaf[mt][1]), as_bf(f11), acc[mt][1], 0, 0, 0);
        }
        #pragma unroll
        for (int mt = 0; mt < 4; ++mt)
            #pragma unroll
            for (int nt = 0; nt < 2; ++nt)
                #pragma unroll
                for (int r = 0; r < 4; ++r)
                    L[(mt * 16 + lg * 4 + r) * LSTR + nt * 16 + lm] = ssp_f(acc[mt][nt][r]);

        const float b2a = wv2_b[lm], b2b = wv2_b[16 + lm];
        f32x4 acc2[4][2];
        const uint4 f20 = frag[10 * 64 + l], f21 = frag[11 * 64 + l];
        #pragma unroll
        for (int mt = 0; mt < 4; ++mt) {
            acc2[mt][0] = f32x4{b2a, b2a, b2a, b2a};
            acc2[mt][1] = f32x4{b2b, b2b, b2b, b2b};
            float av[8];
            #pragma unroll
            for (int j = 0; j < 8; ++j)
                av[j] = L[(mt * 16 + lm) * LSTR + lg * 8 + j];
            uint4 a2;
            a2.x = pk2f(av[0], av[1]); a2.y = pk2f(av[2], av[3]);
            a2.z = pk2f(av[4], av[5]); a2.w = pk2f(av[6], av[7]);
            acc2[mt][0] = __builtin_amdgcn_mfma_f32_16x16x32_bf16(as_bf(a2), as_bf(f20), acc2[mt][0], 0, 0, 0);
            acc2[mt][1] = __builtin_amdgcn_mfma_f32_16x16x32_bf16(as_bf(a2), as_bf(f21), acc2[mt][1], 0, 0, 0);
        }
        #pragma unroll
        for (int mt = 0; mt < 4; ++mt)
            #pragma unroll
            for (int nt = 0; nt < 2; ++nt)
                #pragma unroll
                for (int r = 0; r < 4; ++r)
                    L[(mt * 16 + lg * 4 + r) * LSTR + nt * 16 + lm] = acc2[mt][nt][r];
    }

    #pragma unroll
    for (int k = 0; k < 16; ++k) {
        const int f = k * 64 + l;
        const int pr = f >> 4, i = f & 15;
        wvP[(size_t)e0 * 16 + f] = pk2f(L[pr * LSTR + 2 * i], L[pr * LSTR + 2 * i + 1]);
    }
}

// ---------------- K3a: aggregation only (low VGPR, high occupancy) ----------
__global__ __launch_bounds__(256) void k_aggr(
    const float* __restrict__ qkP, const unsigned* __restrict__ wvP,
    const unsigned* __restrict__ hv_bf, const int* __restrict__ colv,
    const int* __restrict__ base, const int* __restrict__ deg,
    float* __restrict__ uP)
{
    const int w = threadIdx.x >> 6, l = threadIdx.x & 63;
    const int h = l >> 4, i = l & 15;

    for (int n = blockIdx.x * 4 + w; n < NN; n += 2048 * 4) {
        const int b0 = base[n];
        const int dn = deg[n];
        float acc0 = 0.f, acc1 = 0.f;
        if (dn > 0) {
            const float* qkh = qkP + (size_t)h * EE + b0;
            const int emax = b0 + dn - 1;
            float m = -3.0e38f;
            for (int c = i; c < dn; c += 16) m = fmaxf(m, qkh[c]);
            #pragma unroll
            for (int off = 1; off < 16; off <<= 1)
                m = fmaxf(m, __shfl_xor(m, off));
            float den = 0.f;
            for (int c = i; c < dn; c += 16) den += __expf(qkh[c] - m);
            #pragma unroll
            for (int off = 1; off < 16; off <<= 1) den += __shfl_xor(den, off);
            const float rden = (den > 0.f) ? 1.0f / den : 0.f;
            for (int c0 = 0; c0 < dn; c0 += 16) {
                const int tn = (dn - c0 < 16) ? (dn - c0) : 16;
                float ex = 0.f; int cq = 0;
                if (i < tn) {
                    ex = __expf(qkh[c0 + i] - m) * rden;
                    cq = colv[b0 + c0 + i];
                }
                const int t4 = (tn + 3) & ~3;
                for (int i2 = 0; i2 < t4; i2 += 4) {
                    #pragma unroll
                    for (int u = 0; u < 4; ++u) {
                        const int src = (l & 48) | (i2 + u);
                        const float wgt = __shfl(ex, src);
                        const int ce = __shfl(cq, src);
                        int ep = b0 + c0 + i2 + u;
                        ep = (ep > emax) ? emax : ep;
                        const unsigned hvv = hv_bf[(size_t)ce * 64 + l];
                        const unsigned wvv = wvP[(size_t)ep * 16 + i];
                        float ha, hb, wa, wb;
                        unp2(hvv, ha, hb); unp2(wvv, wa, wb);
                        acc0 = fmaf(wgt, wa * ha, acc0);
                        acc1 = fmaf(wgt, wb * hb, acc1);
                    }
                }
            }
        }
        *(float2*)(uP + (size_t)n * HD + 2 * l) = make_float2(acc0, acc1);
    }
}

// ---------------- K3b: wvl matvec + residual + LN2 + ssp -> x2, sbf ---------
__global__ __launch_bounds__(256) void k_tail_a(
    const float* __restrict__ x, const float* __restrict__ uP,
    const int* __restrict__ deg,
    const float* __restrict__ wvl_w, const float* __restrict__ wvl_b,
    const float* __restrict__ ln2_g, const float* __restrict__ ln2_b,
    float* __restrict__ x2P, unsigned* __restrict__ sbf)
{
    const int w = threadIdx.x >> 6, l = threadIdx.x & 63;
    const int h = l >> 4, i = l & 15;
    const int t0 = 2 * l;
    const float2 lg2 = *(const float2*)(ln2_g + t0);
    const float2 lb2 = *(const float2*)(ln2_b + t0);
    const int j0 = 2 * i;

    for (int n = blockIdx.x * 4 + w; n < NN; n += 2048 * 4) {
        const int dn = deg[n];
        const float2 xv = *(const float2*)(x + (size_t)n * HD + t0);

        float ag0 = 0.f, ag1 = 0.f;
        if (dn > 0) {
            const float2 wb = *(const float2*)(wvl_b + j0);
            ag0 = wb.x; ag1 = wb.y;
            const float4* up = (const float4*)(uP + (size_t)n * HD + h * HH);
            const float4* r0 = (const float4*)(wvl_w + (size_t)j0 * HH);
            const float4* r1 = (const float4*)(wvl_w + (size_t)(j0 + 1) * HH);
            #pragma unroll
            for (int q = 0; q < 8; ++q) {
                const float4 u = up[q];
                const float4 a = r0[q], b = r1[q];
                ag0 = fmaf(u.x, a.x, ag0); ag0 = fmaf(u.y, a.y, ag0);
                ag0 = fmaf(u.z, a.z, ag0); ag0 = fmaf(u.w, a.w, ag0);
                ag1 = fmaf(u.x, b.x, ag1); ag1 = fmaf(u.y, b.y, ag1);
                ag1 = fmaf(u.z, b.z, ag1); ag1 = fmaf(u.w, b.w, ag1);
            }
        }
        const float x20 = ag0 + xv.x;
        const float x21 = ag1 + xv.y;

        float s1 = x20 + x21, s2 = x20 * x20 + x21 * x21;
        #pragma unroll
        for (int off = 1; off < 64; off <<= 1) {
            s1 += __shfl_xor(s1, off);
            s2 += __shfl_xor(s2, off);
        }
        const float mean = s1 * (1.0f / HD);
        const float var  = s2 * (1.0f / HD) - mean * mean;
        const float rstd = rsqrtf(var + 1e-5f);
        const float ss0 = ssp_f((x20 - mean) * rstd * lg2.x + lb2.x);
        const float ss1 = ssp_f((x21 - mean) * rstd * lg2.y + lb2.y);

        *(float2*)(x2P + (size_t)n * HD + t0) = make_float2(x20, x21);
        sbf[(size_t)n * 64 + l] = pk2(ss0, ss1);
    }
}

// ---------------- K3c: MFMA out-GEMM: out = sbf @ out_w^T + out_b + x2 ------
__global__ __launch_bounds__(256) void k_tail_gemm(
    const unsigned short* __restrict__ sbf, const float* __restrict__ x2P,
    const uint4* __restrict__ owf, const float* __restrict__ out_b,
    float* __restrict__ out)
{
    const int w = threadIdx.x >> 6, l = threadIdx.x & 63;
    const int lm = l & 15, lg = l >> 4;
    const int tile = blockIdx.x * 4 + w;
    if (tile * 16 >= NN) return;
    const int n0 = tile * 16;

    uint4 af[4];
    #pragma unroll
    for (int kt = 0; kt < 4; ++kt)
        af[kt] = *(const uint4*)(sbf + (size_t)(n0 + lm) * HD + kt * 32 + lg * 8);

    f32x4 acc[8];
    #pragma unroll
    for (int nt = 0; nt < 8; ++nt) {
        const float b = out_b[nt * 16 + lm];
        acc[nt] = f32x4{b, b, b, b};
    }
    #pragma unroll
    for (int kt = 0; kt < 4; ++kt) {
        #pragma unroll
        for (int nt = 0; nt < 8; ++nt)
            acc[nt] = __builtin_amdgcn_mfma_f32_16x16x32_bf16(
                as_bf(af[kt]), as_bf(owf[(nt * 4 + kt) * 64 + l]), acc[nt], 0, 0, 0);
    }
    #pragma unroll
    for (int nt = 0; nt < 8; ++nt)
        #pragma unroll
        for (int r = 0; r < 4; ++r) {
            const size_t idx = (size_t)(n0 + lg * 4 + r) * HD + nt * 16 + lm;
            out[idx] = acc[nt][r] + x2P[idx];
        }
}

extern "C" void kernel_launch(void* const* d_in, const int* in_sizes, int n_in,
                              void* d_out, int out_size, void* d_ws, size_t ws_size,
                              hipStream_t stream) {
    const float* x         = (const float*)d_in[0];
    const float* edge_attr = (const float*)d_in[1];
    const int*   edge_index= (const int*)  d_in[2];
    const float* k_w   = (const float*)d_in[3];
    const float* q_w   = (const float*)d_in[4];
    const float* v_w   = (const float*)d_in[5];
    const float* wk1_w = (const float*)d_in[6];
    const float* wk1_b = (const float*)d_in[7];
    const float* wk2_w = (const float*)d_in[8];
    const float* wk2_b = (const float*)d_in[9];
    const float* wkl_w = (const float*)d_in[10];
    const float* wkl_b = (const float*)d_in[11];
    const float* wv1_w = (const float*)d_in[12];
    const float* wv1_b = (const float*)d_in[13];
    const float* wv2_w = (const float*)d_in[14];
    const float* wv2_b = (const float*)d_in[15];
    const float* wvl_w = (const float*)d_in[16];
    const float* wvl_b = (const float*)d_in[17];
    const float* out_w = (const float*)d_in[18];
    const float* out_b = (const float*)d_in[19];
    const float* ln1_g = (const float*)d_in[20];
    const float* ln1_b = (const float*)d_in[21];
    const float* ln2_g = (const float*)d_in[22];
    const float* ln2_b = (const float*)d_in[23];

    char* ws = (char*)d_ws;
    unsigned* hk_bf = (unsigned*)ws;            ws += (size_t)NN * 64 * 4;
    unsigned* hv_bf = (unsigned*)ws;            ws += (size_t)NN * 64 * 4;
    unsigned* g_bf  = (unsigned*)ws;            ws += (size_t)NN * 64 * 4;
    float* c0  = (float*)ws;                    ws += (size_t)NN * NHD * 4;
    float* qkP = (float*)ws;                    ws += (size_t)NHD * EE * 4;
    unsigned* wvP = (unsigned*)ws;              ws += (size_t)EE * 16 * 4;
    unsigned* ea_bf = (unsigned*)ws;            ws += (size_t)EE * 32 * 4;
    uint4* fragbuf = (uint4*)ws;                ws += (size_t)12 * 64 * 16;
    uint4* owfbuf  = (uint4*)ws;                ws += (size_t)32 * 64 * 16;
    float* uP = (float*)ws;                     ws += (size_t)NN * HD * 4;
    float* x2P = (float*)ws;                    ws += (size_t)NN * HD * 4;
    unsigned* sbf = (unsigned*)ws;              ws += (size_t)NN * 64 * 4;
    int* deg    = (int*)ws;                     ws += (size_t)NN * 4;
    int* base   = (int*)ws;                     ws += (size_t)NN * 4;
    int* cursor = (int*)ws;                     ws += (size_t)NN * 4;
    int* bsum   = (int*)ws;                     ws += (size_t)SCAN_B * 4;
    int* eidx   = (int*)ws;                     ws += (size_t)EE * 4;
    int* rowv   = (int*)ws;                     ws += (size_t)EE * 4;
    int* colv   = (int*)ws;                     ws += (size_t)EE * 4;

    (void)hipMemsetAsync(deg, 0, (size_t)NN * 4, stream);

    k_wfrag<<<1, 256, 0, stream>>>(wk1_w, wk2_w, wv1_w, wv2_w, fragbuf);
    k_owfrag<<<1, 256, 0, stream>>>(out_w, owfbuf);
    k_node_prep<<<1024, 256, 0, stream>>>(x, k_w, q_w, v_w, wkl_w, wkl_b,
        ln1_g, ln1_b, hk_bf, hv_bf, g_bf, c0);
    k_deg<<<1024, 256, 0, stream>>>(edge_index, deg);
    k_scan_block<<<NBLK, SCAN_B, 0, stream>>>(deg, base, bsum);
    k_scan_top<<<1, SCAN_B, 0, stream>>>(bsum);
    k_scan_add<<<NBLK, SCAN_B, 0, stream>>>(base, bsum, cursor);
    k_scatter<<<1024, 256, 0, stream>>>(edge_index, cursor, eidx, rowv, colv);
    k_ea_csr<<<2048, 256, 0, stream>>>(edge_attr, eidx, ea_bf);
    k_edge_mfma<<<EE / 256, 256, 0, stream>>>(ea_bf, rowv, colv,
        hk_bf, g_bf, c0, fragbuf,
        wk1_b, wk2_b, wv1_b, wv2_b, qkP, wvP);
    k_aggr<<<2048, 256, 0, stream>>>(qkP, wvP, hv_bf, colv, base, deg, uP);
    k_tail_a<<<2048, 256, 0, stream>>>(x, uP, deg, wvl_w, wvl_b,
        ln2_g, ln2_b, x2P, sbf);
    k_tail_gemm<<<(NN / 16 + 3) / 4, 256, 0, stream>>>(
        (const unsigned short*)sbf, x2P, owfbuf, out_b, (float*)d_out);
}

// Round 12
// 430.382 us; speedup vs baseline: 7.2644x; 1.1200x over previous
//
#include <hip/hip_runtime.h>
#include <math.h>

#define NN 50000
#define EE 640000
#define HD 128
#define ECD 64
#define NHD 4
#define HH 32
#define SCAN_B 256
#define NBLK ((NN + SCAN_B - 1) / SCAN_B)   // 196
#define LSTR 33
#define NTILE ((NN + 15) / 16)              // 3125

typedef short bf16x8 __attribute__((ext_vector_type(8)));
typedef float f32x4 __attribute__((ext_vector_type(4)));

__device__ __forceinline__ float ssp_f(float v) {
    return fmaxf(v, 0.0f) + __logf(1.0f + __expf(-fabsf(v))) - 0.69314718055994531f;
}
__device__ __forceinline__ unsigned f2bf_u(float f) {
    unsigned u = __float_as_uint(f);
    unsigned r = ((u >> 16) & 1u) + 0x7FFFu;
    return (u + r) >> 16;
}
__device__ __forceinline__ unsigned pk2(float a, float b) {
    return f2bf_u(a) | (f2bf_u(b) << 16);
}
__device__ __forceinline__ unsigned f2bf_f(float f) {
    return (__float_as_uint(f) + 0x8000u) >> 16;
}
__device__ __forceinline__ unsigned pk2f(float a, float b) {
    return f2bf_f(a) | (f2bf_f(b) << 16);
}
__device__ __forceinline__ void unp2(unsigned u, float& a, float& b) {
    a = __uint_as_float(u << 16);
    b = __uint_as_float(u & 0xffff0000u);
}
__device__ __forceinline__ bf16x8 as_bf(uint4 u) {
    union { uint4 a; bf16x8 b; } c; c.a = u; return c.b;
}

// ---------------- K1a: LN1 + c0 (wave-per-node, low VGPR) ----------------
__global__ __launch_bounds__(256) void k_ln1(
    const float* __restrict__ x, const float* __restrict__ ln1_g,
    const float* __restrict__ ln1_b, const float* __restrict__ cw,
    unsigned* __restrict__ y_bf, float* __restrict__ c0_out)
{
    const int w = threadIdx.x >> 6, l = threadIdx.x & 63;
    const int h = l >> 4, i16 = l & 15;
    const int t0 = 2 * l;
    const float2 lg2 = *(const float2*)(ln1_g + t0);
    const float2 lb2 = *(const float2*)(ln1_b + t0);
    const float2 cw2 = *(const float2*)(cw + t0);

    for (int n = blockIdx.x * 4 + w; n < NN; n += 2048 * 4) {
        const float2 xv = *(const float2*)(x + (size_t)n * HD + t0);
        float s1 = xv.x + xv.y;
        float s2 = xv.x * xv.x + xv.y * xv.y;
        #pragma unroll
        for (int off = 1; off < 64; off <<= 1) {
            s1 += __shfl_xor(s1, off);
            s2 += __shfl_xor(s2, off);
        }
        const float mean = s1 * (1.0f / HD);
        const float var  = s2 * (1.0f / HD) - mean * mean;
        const float rstd = rsqrtf(var + 1e-5f);
        const float y0 = (xv.x - mean) * rstd * lg2.x + lb2.x;
        const float y1 = (xv.y - mean) * rstd * lg2.y + lb2.y;
        y_bf[(size_t)n * 64 + l] = pk2(y0, y1);

        float p = y0 * cw2.x + y1 * cw2.y;
        #pragma unroll
        for (int off = 1; off < 16; off <<= 1) p += __shfl_xor(p, off);
        if (i16 == 0) c0_out[n * NHD + h] = p;
    }
}

// ---------------- projection weight packer: pf[tg*512 + nt*64 + l], cw ------
// tg: 0=hk(k_w) 1=hv(v_w) 2=g(gw = q_w^T folded with wkl_w)
// B-frag: lane l slot j -> W[out=(nt&1)*16+(l&15)][d=(l>>4)*8+j] for head nt>>1
__global__ __launch_bounds__(256) void k_pwfrag(
    const float* __restrict__ kw, const float* __restrict__ vw,
    const float* __restrict__ qw, const float* __restrict__ wklw,
    const float* __restrict__ wklb,
    uint4* __restrict__ pf, float* __restrict__ cw)
{
    const int t = threadIdx.x;
    #pragma unroll
    for (int it = 0; it < 6; ++it) {
        const int f = t + it * 256;      // 0..1535
        const int tg = f >> 9;
        const int rem = f & 511;
        const int nt = rem >> 6, l = rem & 63;
        const int lm = l & 15, lg = l >> 4;
        const int h = nt >> 1, od = (nt & 1) * 16 + lm;
        float val[8];
        if (tg == 2) {
            #pragma unroll
            for (int j = 0; j < 8; ++j) {
                float s = 0.f;
                for (int j2 = 0; j2 < 32; ++j2)
                    s += qw[(size_t)(h * 32 + j2) * 32 + lg * 8 + j] * wklw[j2 * 32 + od];
                val[j] = s;
            }
        } else {
            const float* wp = (tg == 0) ? kw : vw;
            #pragma unroll
            for (int j = 0; j < 8; ++j)
                val[j] = wp[(size_t)(h * 32 + od) * 32 + lg * 8 + j];
        }
        uint4 o;
        o.x = pk2(val[0], val[1]); o.y = pk2(val[2], val[3]);
        o.z = pk2(val[4], val[5]); o.w = pk2(val[6], val[7]);
        pf[f] = o;
    }
    #pragma unroll
    for (int d2 = 0; d2 < 2; ++d2) {
        const int idx = t * 2 + d2;     // 0..511
        const int h = idx >> 5, d = idx & 31;
        float s = 0.f;
        for (int j = 0; j < 32; ++j)
            s += qw[(size_t)(h * 32 + j) * 32 + d] * wklb[j];
        cw[idx] = s;
    }
}

// ---------------- K1b: MFMA block-diag projections: hk, hv, g ---------------
__global__ __launch_bounds__(256) void k_proj(
    const unsigned* __restrict__ y_bf, const uint4* __restrict__ pf,
    unsigned short* __restrict__ hk16, unsigned short* __restrict__ hv16,
    unsigned short* __restrict__ g16)
{
    const int w = threadIdx.x >> 6, l = threadIdx.x & 63;
    const int lm = l & 15, lg = l >> 4;
    const int tile = blockIdx.x * 4 + w;
    if (tile >= NTILE) return;
    const int n0 = tile * 16;

    uint4 af[4];
    #pragma unroll
    for (int h = 0; h < 4; ++h)
        af[h] = *(const uint4*)(y_bf + (size_t)(n0 + lm) * 64 + h * 16 + lg * 4);

    unsigned short* const outs[3] = {hk16, hv16, g16};
    #pragma unroll
    for (int tg = 0; tg < 3; ++tg) {
        f32x4 acc[8];
        #pragma unroll
        for (int nt = 0; nt < 8; ++nt) {
            acc[nt] = f32x4{0.f, 0.f, 0.f, 0.f};
            acc[nt] = __builtin_amdgcn_mfma_f32_16x16x32_bf16(
                as_bf(af[nt >> 1]), as_bf(pf[tg * 512 + nt * 64 + l]), acc[nt], 0, 0, 0);
        }
        unsigned short* o = outs[tg];
        #pragma unroll
        for (int nt = 0; nt < 8; ++nt)
            #pragma unroll
            for (int r = 0; r < 4; ++r)
                o[(size_t)(n0 + lg * 4 + r) * HD + nt * 16 + lm] =
                    (unsigned short)f2bf_u(acc[nt][r]);
    }
}

// ---------------- CSR build ----------------
__global__ __launch_bounds__(256) void k_deg(
    const int* __restrict__ edge_index, int* __restrict__ deg)
{
    for (int e = blockIdx.x * blockDim.x + threadIdx.x; e < EE;
         e += gridDim.x * blockDim.x)
        atomicAdd(&deg[edge_index[e]], 1);
}

__global__ __launch_bounds__(SCAN_B) void k_scan_block(
    const int* __restrict__ deg, int* __restrict__ base, int* __restrict__ bsum)
{
    const int i = blockIdx.x * SCAN_B + threadIdx.x;
    const int v = (i < NN) ? deg[i] : 0;
    __shared__ int s[SCAN_B];
    s[threadIdx.x] = v;
    __syncthreads();
    for (int off = 1; off < SCAN_B; off <<= 1) {
        int t = (threadIdx.x >= off) ? s[threadIdx.x - off] : 0;
        __syncthreads();
        s[threadIdx.x] += t;
        __syncthreads();
    }
    if (i < NN) base[i] = s[threadIdx.x] - v;
    if (threadIdx.x == SCAN_B - 1) bsum[blockIdx.x] = s[SCAN_B - 1];
}

__global__ __launch_bounds__(SCAN_B) void k_scan_top(int* __restrict__ bsum)
{
    const int i = threadIdx.x;
    const int v = (i < NBLK) ? bsum[i] : 0;
    __shared__ int s[SCAN_B];
    s[i] = v;
    __syncthreads();
    for (int off = 1; off < SCAN_B; off <<= 1) {
        int t = (i >= off) ? s[i - off] : 0;
        __syncthreads();
        s[i] += t;
        __syncthreads();
    }
    if (i < NBLK) bsum[i] = s[i] - v;
}

__global__ __launch_bounds__(SCAN_B) void k_scan_add(
    int* __restrict__ base, const int* __restrict__ bsum, int* __restrict__ cursor)
{
    const int i = blockIdx.x * SCAN_B + threadIdx.x;
    if (i < NN) {
        const int b = base[i] + bsum[i >> 8];
        base[i] = b;
        cursor[i] = b;
    }
}

__global__ __launch_bounds__(256) void k_scatter(
    const int* __restrict__ edge_index, int* __restrict__ cursor,
    int* __restrict__ eidx, int* __restrict__ rowv, int* __restrict__ colv)
{
    for (int e = blockIdx.x * blockDim.x + threadIdx.x; e < EE;
         e += gridDim.x * blockDim.x) {
        const int r = edge_index[e];
        const int pos = atomicAdd(&cursor[r], 1);
        eidx[pos] = e;
        rowv[pos] = r;
        colv[pos] = edge_index[EE + e];
    }
}

// ---------------- ea -> bf16, permuted to CSR order (grid-stride) ----------
__global__ __launch_bounds__(256) void k_ea_csr(
    const float* __restrict__ ea, const int* __restrict__ eidx,
    unsigned* __restrict__ ea_bf)
{
    for (int i = blockIdx.x * 256 + threadIdx.x; i < EE * 32;
         i += 2048 * 256) {
        const int pos = i >> 5, u = i & 31;
        const int e = eidx[pos];
        const float2 v = *(const float2*)(ea + (size_t)e * ECD + u * 2);
        ea_bf[(size_t)pos * 32 + u] = pk2(v.x, v.y);
    }
}

// ---------------- edge-MLP weight fragment packer (1 block) ----------------
__global__ __launch_bounds__(256) void k_wfrag(
    const float* __restrict__ wk1_w, const float* __restrict__ wk2_w,
    const float* __restrict__ wv1_w, const float* __restrict__ wv2_w,
    uint4* __restrict__ frag)
{
    const int t = threadIdx.x;
    const int l = t & 63;
    const int lm = l & 15, lg = l >> 4;
    {
        const int f = t >> 6;          // 0..3
        const int kt = f >> 1, nt = f & 1;
        const int out = nt * 16 + lm;
        uint4 a, b;
        unsigned ra[4], rb[4];
        #pragma unroll
        for (int p = 0; p < 4; ++p) {
            const int in0 = kt * 32 + lg * 8 + 2 * p;
            ra[p] = pk2(wk1_w[(size_t)out * ECD + in0], wk1_w[(size_t)out * ECD + in0 + 1]);
            rb[p] = pk2(wv1_w[(size_t)out * ECD + in0], wv1_w[(size_t)out * ECD + in0 + 1]);
        }
        a.x = ra[0]; a.y = ra[1]; a.z = ra[2]; a.w = ra[3];
        b.x = rb[0]; b.y = rb[1]; b.z = rb[2]; b.w = rb[3];
        frag[f * 64 + l] = a;
        frag[(6 + f) * 64 + l] = b;
    }
    if (t < 128) {
        const int nt = t >> 6;
        const int out = nt * 16 + lm;
        uint4 a, b;
        unsigned ra[4], rb[4];
        #pragma unroll
        for (int p = 0; p < 4; ++p) {
            const int in0 = lg * 8 + 2 * p;
            ra[p] = pk2(wk2_w[(size_t)out * HH + in0], wk2_w[(size_t)out * HH + in0 + 1]);
            rb[p] = pk2(wv2_w[(size_t)out * HH + in0], wv2_w[(size_t)out * HH + in0 + 1]);
        }
        a.x = ra[0]; a.y = ra[1]; a.z = ra[2]; a.w = ra[3];
        b.x = rb[0]; b.y = rb[1]; b.z = rb[2]; b.w = rb[3];
        frag[(4 + nt) * 64 + l] = a;
        frag[(10 + nt) * 64 + l] = b;
    }
}

// ---------------- out_w fragment packer: owf[nt*4+kt][64] ----------------
__global__ __launch_bounds__(256) void k_owfrag(
    const float* __restrict__ out_w, uint4* __restrict__ owf)
{
    const int t = threadIdx.x;
    const int l = t & 63;
    const int lm = l & 15, lg = l >> 4;
    #pragma unroll
    for (int it = 0; it < 8; ++it) {
        const int f = (t >> 6) + it * 4;   // 0..31 = nt*4+kt
        const int nt = f >> 2, kt = f & 3;
        const int n = nt * 16 + lm;
        unsigned r[4];
        #pragma unroll
        for (int p = 0; p < 4; ++p) {
            const int k0 = kt * 32 + lg * 8 + 2 * p;
            r[p] = pk2(out_w[(size_t)n * HD + k0], out_w[(size_t)n * HD + k0 + 1]);
        }
        uint4 o; o.x = r[0]; o.y = r[1]; o.z = r[2]; o.w = r[3];
        owf[f * 64 + l] = o;
    }
}

// ---------------- K2: MFMA edge kernel (wave = 64 edges) --------------------
__global__ __launch_bounds__(256) void k_edge_mfma(
    const unsigned* __restrict__ ea_bf,
    const int* __restrict__ rowv, const int* __restrict__ colv,
    const unsigned* __restrict__ hk_bf, const unsigned* __restrict__ g_bf,
    const float* __restrict__ c0_in, const uint4* __restrict__ frag,
    const float* __restrict__ wk1_b, const float* __restrict__ wk2_b,
    const float* __restrict__ wv1_b, const float* __restrict__ wv2_b,
    float* __restrict__ qkP, unsigned* __restrict__ wvP)
{
    __shared__ float lds[4][64 * LSTR];
    const int w = threadIdx.x >> 6, l = threadIdx.x & 63;
    const int lm = l & 15, lg = l >> 4;
    float* L = lds[w];
    const int e0 = blockIdx.x * 256 + w * 64;
    const int pos = e0 + l;
    const int row = rowv[pos];
    const int col = colv[pos];

    uint4 eaf[4][2];
    #pragma unroll
    for (int mt = 0; mt < 4; ++mt)
        #pragma unroll
        for (int kt = 0; kt < 2; ++kt)
            eaf[mt][kt] = *(const uint4*)(ea_bf +
                (size_t)(e0 + mt * 16 + lm) * 32 + kt * 16 + lg * 4);

    // ================= K path =================
    {
        const float b1a = wk1_b[lm], b1b = wk1_b[16 + lm];
        f32x4 acc[4][2];
        #pragma unroll
        for (int mt = 0; mt < 4; ++mt) {
            acc[mt][0] = f32x4{b1a, b1a, b1a, b1a};
            acc[mt][1] = f32x4{b1b, b1b, b1b, b1b};
        }
        const uint4 f00 = frag[0 * 64 + l], f01 = frag[1 * 64 + l];
        const uint4 f10 = frag[2 * 64 + l], f11 = frag[3 * 64 + l];
        #pragma unroll
        for (int mt = 0; mt < 4; ++mt) {
            acc[mt][0] = __builtin_amdgcn_mfma_f32_16x16x32_bf16(as_bf(eaf[mt][0]), as_bf(f00), acc[mt][0], 0, 0, 0);
            acc[mt][1] = __builtin_amdgcn_mfma_f32_16x16x32_bf16(as_bf(eaf[mt][0]), as_bf(f01), acc[mt][1], 0, 0, 0);
            acc[mt][0] = __builtin_amdgcn_mfma_f32_16x16x32_bf16(as_bf(eaf[mt][1]), as_bf(f10), acc[mt][0], 0, 0, 0);
            acc[mt][1] = __builtin_amdgcn_mfma_f32_16x16x32_bf16(as_bf(eaf[mt][1]), as_bf(f11), acc[mt][1], 0, 0, 0);
        }
        #pragma unroll
        for (int mt = 0; mt < 4; ++mt)
            #pragma unroll
            for (int nt = 0; nt < 2; ++nt)
                #pragma unroll
                for (int r = 0; r < 4; ++r)
                    L[(mt * 16 + lg * 4 + r) * LSTR + nt * 16 + lm] = ssp_f(acc[mt][nt][r]);

        const float b2a = wk2_b[lm], b2b = wk2_b[16 + lm];
        f32x4 acc2[4][2];
        const uint4 f20 = frag[4 * 64 + l], f21 = frag[5 * 64 + l];
        #pragma unroll
        for (int mt = 0; mt < 4; ++mt) {
            acc2[mt][0] = f32x4{b2a, b2a, b2a, b2a};
            acc2[mt][1] = f32x4{b2b, b2b, b2b, b2b};
            float av[8];
            #pragma unroll
            for (int j = 0; j < 8; ++j)
                av[j] = L[(mt * 16 + lm) * LSTR + lg * 8 + j];
            uint4 a2;
            a2.x = pk2f(av[0], av[1]); a2.y = pk2f(av[2], av[3]);
            a2.z = pk2f(av[4], av[5]); a2.w = pk2f(av[6], av[7]);
            acc2[mt][0] = __builtin_amdgcn_mfma_f32_16x16x32_bf16(as_bf(a2), as_bf(f20), acc2[mt][0], 0, 0, 0);
            acc2[mt][1] = __builtin_amdgcn_mfma_f32_16x16x32_bf16(as_bf(a2), as_bf(f21), acc2[mt][1], 0, 0, 0);
        }
        #pragma unroll
        for (int mt = 0; mt < 4; ++mt)
            #pragma unroll
            for (int nt = 0; nt < 2; ++nt)
                #pragma unroll
                for (int r = 0; r < 4; ++r)
                    L[(mt * 16 + lg * 4 + r) * LSTR + nt * 16 + lm] = acc2[mt][nt][r];
    }

    float wk[32];
    #pragma unroll
    for (int j = 0; j < 32; ++j) wk[j] = L[l * LSTR + j];

    {
        const uint4* hkp = (const uint4*)(hk_bf + (size_t)col * 64);
        const uint4* gp  = (const uint4*)(g_bf  + (size_t)row * 64);
        const float4 c0v = *(const float4*)(c0_in + (size_t)row * NHD);
        #pragma unroll
        for (int h = 0; h < NHD; ++h) {
            float s = 0.f;
            #pragma unroll
            for (int q = 0; q < 4; ++q) {
                const uint4 ku = hkp[h * 4 + q];
                const uint4 gu = gp[h * 4 + q];
                float ka, kb, ga, gb;
                unp2(ku.x, ka, kb); unp2(gu.x, ga, gb);
                s = fmaf(wk[q * 8 + 0] * ka, ga, s);
                s = fmaf(wk[q * 8 + 1] * kb, gb, s);
                unp2(ku.y, ka, kb); unp2(gu.y, ga, gb);
                s = fmaf(wk[q * 8 + 2] * ka, ga, s);
                s = fmaf(wk[q * 8 + 3] * kb, gb, s);
                unp2(ku.z, ka, kb); unp2(gu.z, ga, gb);
                s = fmaf(wk[q * 8 + 4] * ka, ga, s);
                s = fmaf(wk[q * 8 + 5] * kb, gb, s);
                unp2(ku.w, ka, kb); unp2(gu.w, ga, gb);
                s = fmaf(wk[q * 8 + 6] * ka, ga, s);
                s = fmaf(wk[q * 8 + 7] * kb, gb, s);
            }
            const float c0h = (h == 0) ? c0v.x : (h == 1) ? c0v.y : (h == 2) ? c0v.z : c0v.w;
            qkP[(size_t)h * EE + pos] = s + c0h;
        }
    }

    // ================= V path =================
    {
        const float b1a = wv1_b[lm], b1b = wv1_b[16 + lm];
        f32x4 acc[4][2];
        #pragma unroll
        for (int mt = 0; mt < 4; ++mt) {
            acc[mt][0] = f32x4{b1a, b1a, b1a, b1a};
            acc[mt][1] = f32x4{b1b, b1b, b1b, b1b};
        }
        const uint4 f00 = frag[6 * 64 + l], f01 = frag[7 * 64 + l];
        const uint4 f10 = frag[8 * 64 + l], f11 = frag[9 * 64 + l];
        #pragma unroll
        for (int mt = 0; mt < 4; ++mt) {
            acc[mt][0] = __builtin_amdgcn_mfma_f32_16x16x32_bf16(as_bf(eaf[mt][0]), as_bf(f00), acc[mt][0], 0, 0, 0);
            acc[mt][1] = __builtin_amdgcn_mfma_f32_16x16x32_bf16(as_bf(eaf[mt][0]), as_bf(f01), acc[mt][1], 0, 0, 0);
            acc[mt][0] = __builtin_amdgcn_mfma_f32_16x16x32_bf16(as_bf(eaf[mt][1]), as_bf(f10), acc[mt][0], 0, 0, 0);
            acc[mt][1] = __builtin_amdgcn_mfma_f32_16x16x32_bf16(as_bf(eaf[mt][1]), as_bf(f11), acc[mt][1], 0, 0, 0);
        }
        #pragma unroll
        for (int mt = 0; mt < 4; ++mt)
            #pragma unroll
            for (int nt = 0; nt < 2; ++nt)
                #pragma unroll
                for (int r = 0; r < 4; ++r)
                    L[(mt * 16 + lg * 4 + r) * LSTR + nt * 16 + lm] = ssp_f(acc[mt][nt][r]);

        const float b2a = wv2_b[lm], b2b = wv2_b[16 + lm];
        f32x4 acc2[4][2];
        const uint4 f20 = frag[10 * 64 + l], f21 = frag[11 * 64 + l];
        #pragma unroll
        for (int mt = 0; mt < 4; ++mt) {
            acc2[mt][0] = f32x4{b2a, b2a, b2a, b2a};
            acc2[mt][1] = f32x4{b2b, b2b, b2b, b2b};
            float av[8];
            #pragma unroll
            for (int j = 0; j < 8; ++j)
                av[j] = L[(mt * 16 + lm) * LSTR + lg * 8 + j];
            uint4 a2;
            a2.x = pk2f(av[0], av[1]); a2.y = pk2f(av[2], av[3]);
            a2.z = pk2f(av[4], av[5]); a2.w = pk2f(av[6], av[7]);
            acc2[mt][0] = __builtin_amdgcn_mfma_f32_16x16x32_bf16(as_bf(a2), as_bf(f20), acc2[mt][0], 0, 0, 0);
            acc2[mt][1] = __builtin_amdgcn_mfma_f32_16x16x32_bf16(as_bf(a2), as_bf(f21), acc2[mt][1], 0, 0, 0);
        }
        #pragma unroll
        for (int mt = 0; mt < 4; ++mt)
            #pragma unroll
            for (int nt = 0; nt < 2; ++nt)
                #pragma unroll
                for (int r = 0; r < 4; ++r)
                    L[(mt * 16 + lg * 4 + r) * LSTR + nt * 16 + lm] = acc2[mt][nt][r];
    }

    #pragma unroll
    for (int k = 0; k < 16; ++k) {
        const int f = k * 64 + l;
        const int pr = f >> 4, i = f & 15;
        wvP[(size_t)e0 * 16 + f] = pk2f(L[pr * LSTR + 2 * i], L[pr * LSTR + 2 * i + 1]);
    }
}

// ---------------- K3a: aggregation only (low VGPR, high occupancy) ----------
__global__ __launch_bounds__(256) void k_aggr(
    const float* __restrict__ qkP, const unsigned* __restrict__ wvP,
    const unsigned* __restrict__ hv_bf, const int* __restrict__ colv,
    const int* __restrict__ base, const int* __restrict__ deg,
    float* __restrict__ uP)
{
    const int w = threadIdx.x >> 6, l = threadIdx.x & 63;
    const int h = l >> 4, i = l & 15;

    for (int n = blockIdx.x * 4 + w; n < NN; n += 2048 * 4) {
        const int b0 = base[n];
        const int dn = deg[n];
        float acc0 = 0.f, acc1 = 0.f;
        if (dn > 0) {
            const float* qkh = qkP + (size_t)h * EE + b0;
            const int emax = b0 + dn - 1;
            float m = -3.0e38f;
            for (int c = i; c < dn; c += 16) m = fmaxf(m, qkh[c]);
            #pragma unroll
            for (int off = 1; off < 16; off <<= 1)
                m = fmaxf(m, __shfl_xor(m, off));
            float den = 0.f;
            for (int c = i; c < dn; c += 16) den += __expf(qkh[c] - m);
            #pragma unroll
            for (int off = 1; off < 16; off <<= 1) den += __shfl_xor(den, off);
            const float rden = (den > 0.f) ? 1.0f / den : 0.f;
            for (int c0 = 0; c0 < dn; c0 += 16) {
                const int tn = (dn - c0 < 16) ? (dn - c0) : 16;
                float ex = 0.f; int cq = 0;
                if (i < tn) {
                    ex = __expf(qkh[c0 + i] - m) * rden;
                    cq = colv[b0 + c0 + i];
                }
                const int t4 = (tn + 3) & ~3;
                for (int i2 = 0; i2 < t4; i2 += 4) {
                    #pragma unroll
                    for (int u = 0; u < 4; ++u) {
                        const int src = (l & 48) | (i2 + u);
                        const float wgt = __shfl(ex, src);
                        const int ce = __shfl(cq, src);
                        int ep = b0 + c0 + i2 + u;
                        ep = (ep > emax) ? emax : ep;
                        const unsigned hvv = hv_bf[(size_t)ce * 64 + l];
                        const unsigned wvv = wvP[(size_t)ep * 16 + i];
                        float ha, hb, wa, wb;
                        unp2(hvv, ha, hb); unp2(wvv, wa, wb);
                        acc0 = fmaf(wgt, wa * ha, acc0);
                        acc1 = fmaf(wgt, wb * hb, acc1);
                    }
                }
            }
        }
        *(float2*)(uP + (size_t)n * HD + 2 * l) = make_float2(acc0, acc1);
    }
}

// ---------------- K3b: wvl matvec + residual + LN2 + ssp -> x2, sbf ---------
__global__ __launch_bounds__(256) void k_tail_a(
    const float* __restrict__ x, const float* __restrict__ uP,
    const int* __restrict__ deg,
    const float* __restrict__ wvl_w, const float* __restrict__ wvl_b,
    const float* __restrict__ ln2_g, const float* __restrict__ ln2_b,
    float* __restrict__ x2P, unsigned* __restrict__ sbf)
{
    const int w = threadIdx.x >> 6, l = threadIdx.x & 63;
    const int h = l >> 4, i = l & 15;
    const int t0 = 2 * l;
    const float2 lg2 = *(const float2*)(ln2_g + t0);
    const float2 lb2 = *(const float2*)(ln2_b + t0);
    const int j0 = 2 * i;

    for (int n = blockIdx.x * 4 + w; n < NN; n += 2048 * 4) {
        const int dn = deg[n];
        const float2 xv = *(const float2*)(x + (size_t)n * HD + t0);

        float ag0 = 0.f, ag1 = 0.f;
        if (dn > 0) {
            const float2 wb = *(const float2*)(wvl_b + j0);
            ag0 = wb.x; ag1 = wb.y;
            const float4* up = (const float4*)(uP + (size_t)n * HD + h * HH);
            const float4* r0 = (const float4*)(wvl_w + (size_t)j0 * HH);
            const float4* r1 = (const float4*)(wvl_w + (size_t)(j0 + 1) * HH);
            #pragma unroll
            for (int q = 0; q < 8; ++q) {
                const float4 u = up[q];
                const float4 a = r0[q], b = r1[q];
                ag0 = fmaf(u.x, a.x, ag0); ag0 = fmaf(u.y, a.y, ag0);
                ag0 = fmaf(u.z, a.z, ag0); ag0 = fmaf(u.w, a.w, ag0);
                ag1 = fmaf(u.x, b.x, ag1); ag1 = fmaf(u.y, b.y, ag1);
                ag1 = fmaf(u.z, b.z, ag1); ag1 = fmaf(u.w, b.w, ag1);
            }
        }
        const float x20 = ag0 + xv.x;
        const float x21 = ag1 + xv.y;

        float s1 = x20 + x21, s2 = x20 * x20 + x21 * x21;
        #pragma unroll
        for (int off = 1; off < 64; off <<= 1) {
            s1 += __shfl_xor(s1, off);
            s2 += __shfl_xor(s2, off);
        }
        const float mean = s1 * (1.0f / HD);
        const float var  = s2 * (1.0f / HD) - mean * mean;
        const float rstd = rsqrtf(var + 1e-5f);
        const float ss0 = ssp_f((x20 - mean) * rstd * lg2.x + lb2.x);
        const float ss1 = ssp_f((x21 - mean) * rstd * lg2.y + lb2.y);

        *(float2*)(x2P + (size_t)n * HD + t0) = make_float2(x20, x21);
        sbf[(size_t)n * 64 + l] = pk2(ss0, ss1);
    }
}

// ---------------- K3c: MFMA out-GEMM: out = sbf @ out_w^T + out_b + x2 ------
__global__ __launch_bounds__(256) void k_tail_gemm(
    const unsigned short* __restrict__ sbf, const float* __restrict__ x2P,
    const uint4* __restrict__ owf, const float* __restrict__ out_b,
    float* __restrict__ out)
{
    const int w = threadIdx.x >> 6, l = threadIdx.x & 63;
    const int lm = l & 15, lg = l >> 4;
    const int tile = blockIdx.x * 4 + w;
    if (tile * 16 >= NN) return;
    const int n0 = tile * 16;

    uint4 af[4];
    #pragma unroll
    for (int kt = 0; kt < 4; ++kt)
        af[kt] = *(const uint4*)(sbf + (size_t)(n0 + lm) * HD + kt * 32 + lg * 8);

    f32x4 acc[8];
    #pragma unroll
    for (int nt = 0; nt < 8; ++nt) {
        const float b = out_b[nt * 16 + lm];
        acc[nt] = f32x4{b, b, b, b};
    }
    #pragma unroll
    for (int kt = 0; kt < 4; ++kt) {
        #pragma unroll
        for (int nt = 0; nt < 8; ++nt)
            acc[nt] = __builtin_amdgcn_mfma_f32_16x16x32_bf16(
                as_bf(af[kt]), as_bf(owf[(nt * 4 + kt) * 64 + l]), acc[nt], 0, 0, 0);
    }
    #pragma unroll
    for (int nt = 0; nt < 8; ++nt)
        #pragma unroll
        for (int r = 0; r < 4; ++r) {
            const size_t idx = (size_t)(n0 + lg * 4 + r) * HD + nt * 16 + lm;
            out[idx] = acc[nt][r] + x2P[idx];
        }
}

extern "C" void kernel_launch(void* const* d_in, const int* in_sizes, int n_in,
                              void* d_out, int out_size, void* d_ws, size_t ws_size,
                              hipStream_t stream) {
    const float* x         = (const float*)d_in[0];
    const float* edge_attr = (const float*)d_in[1];
    const int*   edge_index= (const int*)  d_in[2];
    const float* k_w   = (const float*)d_in[3];
    const float* q_w   = (const float*)d_in[4];
    const float* v_w   = (const float*)d_in[5];
    const float* wk1_w = (const float*)d_in[6];
    const float* wk1_b = (const float*)d_in[7];
    const float* wk2_w = (const float*)d_in[8];
    const float* wk2_b = (const float*)d_in[9];
    const float* wkl_w = (const float*)d_in[10];
    const float* wkl_b = (const float*)d_in[11];
    const float* wv1_w = (const float*)d_in[12];
    const float* wv1_b = (const float*)d_in[13];
    const float* wv2_w = (const float*)d_in[14];
    const float* wv2_b = (const float*)d_in[15];
    const float* wvl_w = (const float*)d_in[16];
    const float* wvl_b = (const float*)d_in[17];
    const float* out_w = (const float*)d_in[18];
    const float* out_b = (const float*)d_in[19];
    const float* ln1_g = (const float*)d_in[20];
    const float* ln1_b = (const float*)d_in[21];
    const float* ln2_g = (const float*)d_in[22];
    const float* ln2_b = (const float*)d_in[23];

    char* ws = (char*)d_ws;
    unsigned* hk_bf = (unsigned*)ws;            ws += (size_t)NN * 64 * 4;
    unsigned* hv_bf = (unsigned*)ws;            ws += (size_t)NN * 64 * 4;
    unsigned* g_bf  = (unsigned*)ws;            ws += (size_t)NN * 64 * 4;
    unsigned* y_bf  = (unsigned*)ws;            ws += (size_t)NN * 64 * 4;
    float* c0  = (float*)ws;                    ws += (size_t)NN * NHD * 4;
    float* qkP = (float*)ws;                    ws += (size_t)NHD * EE * 4;
    unsigned* wvP = (unsigned*)ws;              ws += (size_t)EE * 16 * 4;
    unsigned* ea_bf = (unsigned*)ws;            ws += (size_t)EE * 32 * 4;
    uint4* fragbuf = (uint4*)ws;                ws += (size_t)12 * 64 * 16;
    uint4* owfbuf  = (uint4*)ws;                ws += (size_t)32 * 64 * 16;
    uint4* pfbuf   = (uint4*)ws;                ws += (size_t)3 * 512 * 16;
    float* cw      = (float*)ws;                ws += (size_t)512 * 4;
    float* uP = (float*)ws;                     ws += (size_t)NN * HD * 4;
    float* x2P = (float*)ws;                    ws += (size_t)NN * HD * 4;
    unsigned* sbf = (unsigned*)ws;              ws += (size_t)NN * 64 * 4;
    int* deg    = (int*)ws;                     ws += (size_t)NN * 4;
    int* base   = (int*)ws;                     ws += (size_t)NN * 4;
    int* cursor = (int*)ws;                     ws += (size_t)NN * 4;
    int* bsum   = (int*)ws;                     ws += (size_t)SCAN_B * 4;
    int* eidx   = (int*)ws;                     ws += (size_t)EE * 4;
    int* rowv   = (int*)ws;                     ws += (size_t)EE * 4;
    int* colv   = (int*)ws;                     ws += (size_t)EE * 4;

    (void)hipMemsetAsync(deg, 0, (size_t)NN * 4, stream);

    k_wfrag<<<1, 256, 0, stream>>>(wk1_w, wk2_w, wv1_w, wv2_w, fragbuf);
    k_owfrag<<<1, 256, 0, stream>>>(out_w, owfbuf);
    k_pwfrag<<<1, 256, 0, stream>>>(k_w, v_w, q_w, wkl_w, wkl_b, pfbuf, cw);
    k_ln1<<<2048, 256, 0, stream>>>(x, ln1_g, ln1_b, cw, y_bf, c0);
    k_proj<<<(NTILE + 3) / 4, 256, 0, stream>>>(y_bf, pfbuf,
        (unsigned short*)hk_bf, (unsigned short*)hv_bf, (unsigned short*)g_bf);
    k_deg<<<1024, 256, 0, stream>>>(edge_index, deg);
    k_scan_block<<<NBLK, SCAN_B, 0, stream>>>(deg, base, bsum);
    k_scan_top<<<1, SCAN_B, 0, stream>>>(bsum);
    k_scan_add<<<NBLK, SCAN_B, 0, stream>>>(base, bsum, cursor);
    k_scatter<<<1024, 256, 0, stream>>>(edge_index, cursor, eidx, rowv, colv);
    k_ea_csr<<<2048, 256, 0, stream>>>(edge_attr, eidx, ea_bf);
    k_edge_mfma<<<EE / 256, 256, 0, stream>>>(ea_bf, rowv, colv,
        hk_bf, g_bf, c0, fragbuf,
        wk1_b, wk2_b, wv1_b, wv2_b, qkP, wvP);
    k_aggr<<<2048, 256, 0, stream>>>(qkP, wvP, hv_bf, colv, base, deg, uP);
    k_tail_a<<<2048, 256, 0, stream>>>(x, uP, deg, wvl_w, wvl_b,
        ln2_g, ln2_b, x2P, sbf);
    k_tail_gemm<<<(NN / 16 + 3) / 4, 256, 0, stream>>>(
        (const unsigned short*)sbf, x2P, owfbuf, out_b, (float*)d_out);
}

// Round 13
// 361.382 us; speedup vs baseline: 8.6514x; 1.1909x over previous
//
#include <hip/hip_runtime.h>
#include <math.h>

#define NN 50000
#define EE 640000
#define HD 128
#define ECD 64
#define NHD 4
#define HH 32
#define SCAN_B 256
#define NBLK ((NN + SCAN_B - 1) / SCAN_B)   // 196
#define LSTR 33
#define NTILE ((NN + 15) / 16)              // 3125

typedef short bf16x8 __attribute__((ext_vector_type(8)));
typedef float f32x4 __attribute__((ext_vector_type(4)));

__device__ __forceinline__ float ssp_f(float v) {
    return fmaxf(v, 0.0f) + __logf(1.0f + __expf(-fabsf(v))) - 0.69314718055994531f;
}
__device__ __forceinline__ unsigned f2bf_u(float f) {
    unsigned u = __float_as_uint(f);
    unsigned r = ((u >> 16) & 1u) + 0x7FFFu;
    return (u + r) >> 16;
}
__device__ __forceinline__ unsigned pk2(float a, float b) {
    return f2bf_u(a) | (f2bf_u(b) << 16);
}
__device__ __forceinline__ unsigned f2bf_f(float f) {
    return (__float_as_uint(f) + 0x8000u) >> 16;
}
__device__ __forceinline__ unsigned pk2f(float a, float b) {
    return f2bf_f(a) | (f2bf_f(b) << 16);
}
__device__ __forceinline__ void unp2(unsigned u, float& a, float& b) {
    a = __uint_as_float(u << 16);
    b = __uint_as_float(u & 0xffff0000u);
}
__device__ __forceinline__ bf16x8 as_bf(uint4 u) {
    union { uint4 a; bf16x8 b; } c; c.a = u; return c.b;
}

// ---------------- K1a: LN1 + c0 (wave-per-node, low VGPR) ----------------
__global__ __launch_bounds__(256) void k_ln1(
    const float* __restrict__ x, const float* __restrict__ ln1_g,
    const float* __restrict__ ln1_b, const float* __restrict__ cw,
    unsigned* __restrict__ y_bf, float* __restrict__ c0_out)
{
    const int w = threadIdx.x >> 6, l = threadIdx.x & 63;
    const int h = l >> 4, i16 = l & 15;
    const int t0 = 2 * l;
    const float2 lg2 = *(const float2*)(ln1_g + t0);
    const float2 lb2 = *(const float2*)(ln1_b + t0);
    const float2 cw2 = *(const float2*)(cw + t0);

    for (int n = blockIdx.x * 4 + w; n < NN; n += 2048 * 4) {
        const float2 xv = *(const float2*)(x + (size_t)n * HD + t0);
        float s1 = xv.x + xv.y;
        float s2 = xv.x * xv.x + xv.y * xv.y;
        #pragma unroll
        for (int off = 1; off < 64; off <<= 1) {
            s1 += __shfl_xor(s1, off);
            s2 += __shfl_xor(s2, off);
        }
        const float mean = s1 * (1.0f / HD);
        const float var  = s2 * (1.0f / HD) - mean * mean;
        const float rstd = rsqrtf(var + 1e-5f);
        const float y0 = (xv.x - mean) * rstd * lg2.x + lb2.x;
        const float y1 = (xv.y - mean) * rstd * lg2.y + lb2.y;
        y_bf[(size_t)n * 64 + l] = pk2(y0, y1);

        float p = y0 * cw2.x + y1 * cw2.y;
        #pragma unroll
        for (int off = 1; off < 16; off <<= 1) p += __shfl_xor(p, off);
        if (i16 == 0) c0_out[n * NHD + h] = p;
    }
}

// ---------------- projection weight packer ----------------
__global__ __launch_bounds__(256) void k_pwfrag(
    const float* __restrict__ kw, const float* __restrict__ vw,
    const float* __restrict__ qw, const float* __restrict__ wklw,
    const float* __restrict__ wklb,
    uint4* __restrict__ pf, float* __restrict__ cw)
{
    const int t = threadIdx.x;
    #pragma unroll
    for (int it = 0; it < 6; ++it) {
        const int f = t + it * 256;      // 0..1535
        const int tg = f >> 9;
        const int rem = f & 511;
        const int nt = rem >> 6, l = rem & 63;
        const int lm = l & 15, lg = l >> 4;
        const int h = nt >> 1, od = (nt & 1) * 16 + lm;
        float val[8];
        if (tg == 2) {
            #pragma unroll
            for (int j = 0; j < 8; ++j) {
                float s = 0.f;
                for (int j2 = 0; j2 < 32; ++j2)
                    s += qw[(size_t)(h * 32 + j2) * 32 + lg * 8 + j] * wklw[j2 * 32 + od];
                val[j] = s;
            }
        } else {
            const float* wp = (tg == 0) ? kw : vw;
            #pragma unroll
            for (int j = 0; j < 8; ++j)
                val[j] = wp[(size_t)(h * 32 + od) * 32 + lg * 8 + j];
        }
        uint4 o;
        o.x = pk2(val[0], val[1]); o.y = pk2(val[2], val[3]);
        o.z = pk2(val[4], val[5]); o.w = pk2(val[6], val[7]);
        pf[f] = o;
    }
    #pragma unroll
    for (int d2 = 0; d2 < 2; ++d2) {
        const int idx = t * 2 + d2;     // 0..511
        const int h = idx >> 5, d = idx & 31;
        float s = 0.f;
        for (int j = 0; j < 32; ++j)
            s += qw[(size_t)(h * 32 + j) * 32 + d] * wklb[j];
        cw[idx] = s;
    }
}

// ---------------- K1b: MFMA block-diag projections: hk, hv, g ---------------
__global__ __launch_bounds__(256) void k_proj(
    const unsigned* __restrict__ y_bf, const uint4* __restrict__ pf,
    unsigned short* __restrict__ hk16, unsigned short* __restrict__ hv16,
    unsigned short* __restrict__ g16)
{
    const int w = threadIdx.x >> 6, l = threadIdx.x & 63;
    const int lm = l & 15, lg = l >> 4;
    const int tile = blockIdx.x * 4 + w;
    if (tile >= NTILE) return;
    const int n0 = tile * 16;

    uint4 af[4];
    #pragma unroll
    for (int h = 0; h < 4; ++h)
        af[h] = *(const uint4*)(y_bf + (size_t)(n0 + lm) * 64 + h * 16 + lg * 4);

    unsigned short* const outs[3] = {hk16, hv16, g16};
    #pragma unroll
    for (int tg = 0; tg < 3; ++tg) {
        f32x4 acc[8];
        #pragma unroll
        for (int nt = 0; nt < 8; ++nt) {
            acc[nt] = f32x4{0.f, 0.f, 0.f, 0.f};
            acc[nt] = __builtin_amdgcn_mfma_f32_16x16x32_bf16(
                as_bf(af[nt >> 1]), as_bf(pf[tg * 512 + nt * 64 + l]), acc[nt], 0, 0, 0);
        }
        unsigned short* o = outs[tg];
        #pragma unroll
        for (int nt = 0; nt < 8; ++nt)
            #pragma unroll
            for (int r = 0; r < 4; ++r)
                o[(size_t)(n0 + lg * 4 + r) * HD + nt * 16 + lm] =
                    (unsigned short)f2bf_u(acc[nt][r]);
    }
}

// ---------------- CSR build ----------------
__global__ __launch_bounds__(256) void k_deg(
    const int* __restrict__ edge_index, int* __restrict__ deg)
{
    for (int e = blockIdx.x * blockDim.x + threadIdx.x; e < EE;
         e += gridDim.x * blockDim.x)
        atomicAdd(&deg[edge_index[e]], 1);
}

__global__ __launch_bounds__(SCAN_B) void k_scan_block(
    const int* __restrict__ deg, int* __restrict__ base, int* __restrict__ bsum)
{
    const int i = blockIdx.x * SCAN_B + threadIdx.x;
    const int v = (i < NN) ? deg[i] : 0;
    __shared__ int s[SCAN_B];
    s[threadIdx.x] = v;
    __syncthreads();
    for (int off = 1; off < SCAN_B; off <<= 1) {
        int t = (threadIdx.x >= off) ? s[threadIdx.x - off] : 0;
        __syncthreads();
        s[threadIdx.x] += t;
        __syncthreads();
    }
    if (i < NN) base[i] = s[threadIdx.x] - v;
    if (threadIdx.x == SCAN_B - 1) bsum[blockIdx.x] = s[SCAN_B - 1];
}

__global__ __launch_bounds__(SCAN_B) void k_scan_top(int* __restrict__ bsum)
{
    const int i = threadIdx.x;
    const int v = (i < NBLK) ? bsum[i] : 0;
    __shared__ int s[SCAN_B];
    s[i] = v;
    __syncthreads();
    for (int off = 1; off < SCAN_B; off <<= 1) {
        int t = (i >= off) ? s[i - off] : 0;
        __syncthreads();
        s[i] += t;
        __syncthreads();
    }
    if (i < NBLK) bsum[i] = s[i] - v;
}

__global__ __launch_bounds__(SCAN_B) void k_scan_add(
    int* __restrict__ base, const int* __restrict__ bsum, int* __restrict__ cursor)
{
    const int i = blockIdx.x * SCAN_B + threadIdx.x;
    if (i < NN) {
        const int b = base[i] + bsum[i >> 8];
        base[i] = b;
        cursor[i] = b;
    }
}

__global__ __launch_bounds__(256) void k_scatter(
    const int* __restrict__ edge_index, int* __restrict__ cursor,
    int* __restrict__ eidx, int* __restrict__ rowv, int* __restrict__ colv)
{
    for (int e = blockIdx.x * blockDim.x + threadIdx.x; e < EE;
         e += gridDim.x * blockDim.x) {
        const int r = edge_index[e];
        const int pos = atomicAdd(&cursor[r], 1);
        eidx[pos] = e;
        rowv[pos] = r;
        colv[pos] = edge_index[EE + e];
    }
}

// ---------------- ea -> bf16, permuted to CSR order (grid-stride) ----------
__global__ __launch_bounds__(256) void k_ea_csr(
    const float* __restrict__ ea, const int* __restrict__ eidx,
    unsigned* __restrict__ ea_bf)
{
    for (int i = blockIdx.x * 256 + threadIdx.x; i < EE * 32;
         i += 2048 * 256) {
        const int pos = i >> 5, u = i & 31;
        const int e = eidx[pos];
        const float2 v = *(const float2*)(ea + (size_t)e * ECD + u * 2);
        ea_bf[(size_t)pos * 32 + u] = pk2(v.x, v.y);
    }
}

// ---------------- edge-MLP weight fragment packer (1 block) ----------------
__global__ __launch_bounds__(256) void k_wfrag(
    const float* __restrict__ wk1_w, const float* __restrict__ wk2_w,
    const float* __restrict__ wv1_w, const float* __restrict__ wv2_w,
    uint4* __restrict__ frag)
{
    const int t = threadIdx.x;
    const int l = t & 63;
    const int lm = l & 15, lg = l >> 4;
    {
        const int f = t >> 6;          // 0..3
        const int kt = f >> 1, nt = f & 1;
        const int out = nt * 16 + lm;
        uint4 a, b;
        unsigned ra[4], rb[4];
        #pragma unroll
        for (int p = 0; p < 4; ++p) {
            const int in0 = kt * 32 + lg * 8 + 2 * p;
            ra[p] = pk2(wk1_w[(size_t)out * ECD + in0], wk1_w[(size_t)out * ECD + in0 + 1]);
            rb[p] = pk2(wv1_w[(size_t)out * ECD + in0], wv1_w[(size_t)out * ECD + in0 + 1]);
        }
        a.x = ra[0]; a.y = ra[1]; a.z = ra[2]; a.w = ra[3];
        b.x = rb[0]; b.y = rb[1]; b.z = rb[2]; b.w = rb[3];
        frag[f * 64 + l] = a;
        frag[(6 + f) * 64 + l] = b;
    }
    if (t < 128) {
        const int nt = t >> 6;
        const int out = nt * 16 + lm;
        uint4 a, b;
        unsigned ra[4], rb[4];
        #pragma unroll
        for (int p = 0; p < 4; ++p) {
            const int in0 = lg * 8 + 2 * p;
            ra[p] = pk2(wk2_w[(size_t)out * HH + in0], wk2_w[(size_t)out * HH + in0 + 1]);
            rb[p] = pk2(wv2_w[(size_t)out * HH + in0], wv2_w[(size_t)out * HH + in0 + 1]);
        }
        a.x = ra[0]; a.y = ra[1]; a.z = ra[2]; a.w = ra[3];
        b.x = rb[0]; b.y = rb[1]; b.z = rb[2]; b.w = rb[3];
        frag[(4 + nt) * 64 + l] = a;
        frag[(10 + nt) * 64 + l] = b;
    }
}

// ---------------- out_w fragment packer: owf[nt*4+kt][64] ----------------
__global__ __launch_bounds__(256) void k_owfrag(
    const float* __restrict__ out_w, uint4* __restrict__ owf)
{
    const int t = threadIdx.x;
    const int l = t & 63;
    const int lm = l & 15, lg = l >> 4;
    #pragma unroll
    for (int it = 0; it < 8; ++it) {
        const int f = (t >> 6) + it * 4;   // 0..31 = nt*4+kt
        const int nt = f >> 2, kt = f & 3;
        const int n = nt * 16 + lm;
        unsigned r[4];
        #pragma unroll
        for (int p = 0; p < 4; ++p) {
            const int k0 = kt * 32 + lg * 8 + 2 * p;
            r[p] = pk2(out_w[(size_t)n * HD + k0], out_w[(size_t)n * HD + k0 + 1]);
        }
        uint4 o; o.x = r[0]; o.y = r[1]; o.z = r[2]; o.w = r[3];
        owf[f * 64 + l] = o;
    }
}

// ---------------- K2: MFMA edge kernel (wave = 64 edges) --------------------
__global__ __launch_bounds__(256) void k_edge_mfma(
    const unsigned* __restrict__ ea_bf,
    const int* __restrict__ rowv, const int* __restrict__ colv,
    const unsigned* __restrict__ hk_bf, const unsigned* __restrict__ g_bf,
    const float* __restrict__ c0_in, const uint4* __restrict__ frag,
    const float* __restrict__ wk1_b, const float* __restrict__ wk2_b,
    const float* __restrict__ wv1_b, const float* __restrict__ wv2_b,
    float* __restrict__ qkP, unsigned* __restrict__ wvP)
{
    __shared__ float lds[4][64 * LSTR];
    const int w = threadIdx.x >> 6, l = threadIdx.x & 63;
    const int lm = l & 15, lg = l >> 4;
    float* L = lds[w];
    const int e0 = blockIdx.x * 256 + w * 64;
    const int pos = e0 + l;
    const int row = rowv[pos];
    const int col = colv[pos];

    uint4 eaf[4][2];
    #pragma unroll
    for (int mt = 0; mt < 4; ++mt)
        #pragma unroll
        for (int kt = 0; kt < 2; ++kt)
            eaf[mt][kt] = *(const uint4*)(ea_bf +
                (size_t)(e0 + mt * 16 + lm) * 32 + kt * 16 + lg * 4);

    // ================= K path =================
    {
        const float b1a = wk1_b[lm], b1b = wk1_b[16 + lm];
        f32x4 acc[4][2];
        #pragma unroll
        for (int mt = 0; mt < 4; ++mt) {
            acc[mt][0] = f32x4{b1a, b1a, b1a, b1a};
            acc[mt][1] = f32x4{b1b, b1b, b1b, b1b};
        }
        const uint4 f00 = frag[0 * 64 + l], f01 = frag[1 * 64 + l];
        const uint4 f10 = frag[2 * 64 + l], f11 = frag[3 * 64 + l];
        #pragma unroll
        for (int mt = 0; mt < 4; ++mt) {
            acc[mt][0] = __builtin_amdgcn_mfma_f32_16x16x32_bf16(as_bf(eaf[mt][0]), as_bf(f00), acc[mt][0], 0, 0, 0);
            acc[mt][1] = __builtin_amdgcn_mfma_f32_16x16x32_bf16(as_bf(eaf[mt][0]), as_bf(f01), acc[mt][1], 0, 0, 0);
            acc[mt][0] = __builtin_amdgcn_mfma_f32_16x16x32_bf16(as_bf(eaf[mt][1]), as_bf(f10), acc[mt][0], 0, 0, 0);
            acc[mt][1] = __builtin_amdgcn_mfma_f32_16x16x32_bf16(as_bf(eaf[mt][1]), as_bf(f11), acc[mt][1], 0, 0, 0);
        }
        #pragma unroll
        for (int mt = 0; mt < 4; ++mt)
            #pragma unroll
            for (int nt = 0; nt < 2; ++nt)
                #pragma unroll
                for (int r = 0; r < 4; ++r)
                    L[(mt * 16 + lg * 4 + r) * LSTR + nt * 16 + lm] = ssp_f(acc[mt][nt][r]);

        const float b2a = wk2_b[lm], b2b = wk2_b[16 + lm];
        f32x4 acc2[4][2];
        const uint4 f20 = frag[4 * 64 + l], f21 = frag[5 * 64 + l];
        #pragma unroll
        for (int mt = 0; mt < 4; ++mt) {
            acc2[mt][0] = f32x4{b2a, b2a, b2a, b2a};
            acc2[mt][1] = f32x4{b2b, b2b, b2b, b2b};
            float av[8];
            #pragma unroll
            for (int j = 0; j < 8; ++j)
                av[j] = L[(mt * 16 + lm) * LSTR + lg * 8 + j];
            uint4 a2;
            a2.x = pk2f(av[0], av[1]); a2.y = pk2f(av[2], av[3]);
            a2.z = pk2f(av[4], av[5]); a2.w = pk2f(av[6], av[7]);
            acc2[mt][0] = __builtin_amdgcn_mfma_f32_16x16x32_bf16(as_bf(a2), as_bf(f20), acc2[mt][0], 0, 0, 0);
            acc2[mt][1] = __builtin_amdgcn_mfma_f32_16x16x32_bf16(as_bf(a2), as_bf(f21), acc2[mt][1], 0, 0, 0);
        }
        #pragma unroll
        for (int mt = 0; mt < 4; ++mt)
            #pragma unroll
            for (int nt = 0; nt < 2; ++nt)
                #pragma unroll
                for (int r = 0; r < 4; ++r)
                    L[(mt * 16 + lg * 4 + r) * LSTR + nt * 16 + lm] = acc2[mt][nt][r];
    }

    float wk[32];
    #pragma unroll
    for (int j = 0; j < 32; ++j) wk[j] = L[l * LSTR + j];

    {
        const uint4* hkp = (const uint4*)(hk_bf + (size_t)col * 64);
        const uint4* gp  = (const uint4*)(g_bf  + (size_t)row * 64);
        const float4 c0v = *(const float4*)(c0_in + (size_t)row * NHD);
        #pragma unroll
        for (int h = 0; h < NHD; ++h) {
            float s = 0.f;
            #pragma unroll
            for (int q = 0; q < 4; ++q) {
                const uint4 ku = hkp[h * 4 + q];
                const uint4 gu = gp[h * 4 + q];
                float ka, kb, ga, gb;
                unp2(ku.x, ka, kb); unp2(gu.x, ga, gb);
                s = fmaf(wk[q * 8 + 0] * ka, ga, s);
                s = fmaf(wk[q * 8 + 1] * kb, gb, s);
                unp2(ku.y, ka, kb); unp2(gu.y, ga, gb);
                s = fmaf(wk[q * 8 + 2] * ka, ga, s);
                s = fmaf(wk[q * 8 + 3] * kb, gb, s);
                unp2(ku.z, ka, kb); unp2(gu.z, ga, gb);
                s = fmaf(wk[q * 8 + 4] * ka, ga, s);
                s = fmaf(wk[q * 8 + 5] * kb, gb, s);
                unp2(ku.w, ka, kb); unp2(gu.w, ga, gb);
                s = fmaf(wk[q * 8 + 6] * ka, ga, s);
                s = fmaf(wk[q * 8 + 7] * kb, gb, s);
            }
            const float c0h = (h == 0) ? c0v.x : (h == 1) ? c0v.y : (h == 2) ? c0v.z : c0v.w;
            qkP[(size_t)h * EE + pos] = s + c0h;
        }
    }

    // ================= V path =================
    {
        const float b1a = wv1_b[lm], b1b = wv1_b[16 + lm];
        f32x4 acc[4][2];
        #pragma unroll
        for (int mt = 0; mt < 4; ++mt) {
            acc[mt][0] = f32x4{b1a, b1a, b1a, b1a};
            acc[mt][1] = f32x4{b1b, b1b, b1b, b1b};
        }
        const uint4 f00 = frag[6 * 64 + l], f01 = frag[7 * 64 + l];
        const uint4 f10 = frag[8 * 64 + l], f11 = frag[9 * 64 + l];
        #pragma unroll
        for (int mt = 0; mt < 4; ++mt) {
            acc[mt][0] = __builtin_amdgcn_mfma_f32_16x16x32_bf16(as_bf(eaf[mt][0]), as_bf(f00), acc[mt][0], 0, 0, 0);
            acc[mt][1] = __builtin_amdgcn_mfma_f32_16x16x32_bf16(as_bf(eaf[mt][0]), as_bf(f01), acc[mt][1], 0, 0, 0);
            acc[mt][0] = __builtin_amdgcn_mfma_f32_16x16x32_bf16(as_bf(eaf[mt][1]), as_bf(f10), acc[mt][0], 0, 0, 0);
            acc[mt][1] = __builtin_amdgcn_mfma_f32_16x16x32_bf16(as_bf(eaf[mt][1]), as_bf(f11), acc[mt][1], 0, 0, 0);
        }
        #pragma unroll
        for (int mt = 0; mt < 4; ++mt)
            #pragma unroll
            for (int nt = 0; nt < 2; ++nt)
                #pragma unroll
                for (int r = 0; r < 4; ++r)
                    L[(mt * 16 + lg * 4 + r) * LSTR + nt * 16 + lm] = ssp_f(acc[mt][nt][r]);

        const float b2a = wv2_b[lm], b2b = wv2_b[16 + lm];
        f32x4 acc2[4][2];
        const uint4 f20 = frag[10 * 64 + l], f21 = frag[11 * 64 + l];
        #pragma unroll
        for (int mt = 0; mt < 4; ++mt) {
            acc2[mt][0] = f32x4{b2a, b2a, b2a, b2a};
            acc2[mt][1] = f32x4{b2b, b2b, b2b, b2b};
            float av[8];
            #pragma unroll
            for (int j = 0; j < 8; ++j)
                av[j] = L[(mt * 16 + lm) * LSTR + lg * 8 + j];
            uint4 a2;
            a2.x = pk2f(av[0], av[1]); a2.y = pk2f(av[2], av[3]);
            a2.z = pk2f(av[4], av[5]); a2.w = pk2f(av[6], av[7]);
            acc2[mt][0] = __builtin_amdgcn_mfma_f32_16x16x32_bf16(as_bf(a2), as_bf(f20), acc2[mt][0], 0, 0, 0);
            acc2[mt][1] = __builtin_amdgcn_mfma_f32_16x16x32_bf16(as_bf(a2), as_bf(f21), acc2[mt][1], 0, 0, 0);
        }
        #pragma unroll
        for (int mt = 0; mt < 4; ++mt)
            #pragma unroll
            for (int nt = 0; nt < 2; ++nt)
                #pragma unroll
                for (int r = 0; r < 4; ++r)
                    L[(mt * 16 + lg * 4 + r) * LSTR + nt * 16 + lm] = acc2[mt][nt][r];
    }

    #pragma unroll
    for (int k = 0; k < 16; ++k) {
        const int f = k * 64 + l;
        const int pr = f >> 4, i = f & 15;
        wvP[(size_t)e0 * 16 + f] = pk2f(L[pr * LSTR + 2 * i], L[pr * LSTR + 2 * i + 1]);
    }
}

// ---------------- K3: fused aggregation + wvl matvec + LN2 + ssp ------------
__global__ __launch_bounds__(256) void k_aggr_tail(
    const float* __restrict__ qkP, const unsigned* __restrict__ wvP,
    const unsigned* __restrict__ hv_bf, const int* __restrict__ colv,
    const int* __restrict__ base, const int* __restrict__ deg,
    const float* __restrict__ x,
    const float* __restrict__ wvl_w, const float* __restrict__ wvl_b,
    const float* __restrict__ ln2_g, const float* __restrict__ ln2_b,
    float* __restrict__ x2P, unsigned* __restrict__ sbf)
{
    __shared__ float swvl[HH * 34];      // wvl_w staged, stride 34 (2-way banks)
    __shared__ float su[4][HD];
    for (int idx = threadIdx.x; idx < HH * HH; idx += 256)
        swvl[(idx >> 5) * 34 + (idx & 31)] = wvl_w[idx];
    __syncthreads();   // only barrier; node loop below is barrier-free

    const int w = threadIdx.x >> 6, l = threadIdx.x & 63;
    const int h = l >> 4, i = l & 15;
    const int t0 = 2 * l;
    const float2 lg2 = *(const float2*)(ln2_g + t0);
    const float2 lb2 = *(const float2*)(ln2_b + t0);
    const int j0 = 2 * i;
    const float2 wb2 = *(const float2*)(wvl_b + j0);
    float* sb = su[w];

    for (int n = blockIdx.x * 4 + w; n < NN; n += 2048 * 4) {
        const int b0 = base[n];
        const int dn = deg[n];
        const float2 xv = *(const float2*)(x + (size_t)n * HD + t0);  // prefetch

        float acc0 = 0.f, acc1 = 0.f;
        if (dn > 0) {
            const float* qkh = qkP + (size_t)h * EE + b0;
            const int emax = b0 + dn - 1;
            float m = -3.0e38f;
            for (int c = i; c < dn; c += 16) m = fmaxf(m, qkh[c]);
            #pragma unroll
            for (int off = 1; off < 16; off <<= 1)
                m = fmaxf(m, __shfl_xor(m, off));
            float den = 0.f;
            for (int c = i; c < dn; c += 16) den += __expf(qkh[c] - m);
            #pragma unroll
            for (int off = 1; off < 16; off <<= 1) den += __shfl_xor(den, off);
            const float rden = (den > 0.f) ? 1.0f / den : 0.f;
            for (int c0 = 0; c0 < dn; c0 += 16) {
                const int tn = (dn - c0 < 16) ? (dn - c0) : 16;
                float ex = 0.f; int cq = 0;
                if (i < tn) {
                    ex = __expf(qkh[c0 + i] - m) * rden;
                    cq = colv[b0 + c0 + i];
                }
                const int t4 = (tn + 3) & ~3;
                for (int i2 = 0; i2 < t4; i2 += 4) {
                    #pragma unroll
                    for (int u = 0; u < 4; ++u) {
                        const int src = (l & 48) | (i2 + u);
                        const float wgt = __shfl(ex, src);
                        const int ce = __shfl(cq, src);
                        int ep = b0 + c0 + i2 + u;
                        ep = (ep > emax) ? emax : ep;
                        const unsigned hvv = hv_bf[(size_t)ce * 64 + l];
                        const unsigned wvv = wvP[(size_t)ep * 16 + i];
                        float ha, hb, wa, wb;
                        unp2(hvv, ha, hb); unp2(wvv, wa, wb);
                        acc0 = fmaf(wgt, wa * ha, acc0);
                        acc1 = fmaf(wgt, wb * hb, acc1);
                    }
                }
            }
        }

        // stage u (same-wave LDS; no barrier)
        *(float2*)(sb + t0) = make_float2(acc0, acc1);

        float ag0 = 0.f, ag1 = 0.f;
        if (dn > 0) {
            ag0 = wb2.x; ag1 = wb2.y;
            const float* uh = sb + h * HH;
            const float* r0 = swvl + j0 * 34;
            const float* r1 = r0 + 34;
            #pragma unroll
            for (int q = 0; q < 16; ++q) {
                const float2 u  = *(const float2*)(uh + 2 * q);
                const float2 a  = *(const float2*)(r0 + 2 * q);
                const float2 bb = *(const float2*)(r1 + 2 * q);
                ag0 = fmaf(u.x, a.x, ag0);  ag0 = fmaf(u.y, a.y, ag0);
                ag1 = fmaf(u.x, bb.x, ag1); ag1 = fmaf(u.y, bb.y, ag1);
            }
        }
        const float x20 = ag0 + xv.x;
        const float x21 = ag1 + xv.y;

        float s1 = x20 + x21, s2 = x20 * x20 + x21 * x21;
        #pragma unroll
        for (int off = 1; off < 64; off <<= 1) {
            s1 += __shfl_xor(s1, off);
            s2 += __shfl_xor(s2, off);
        }
        const float mean = s1 * (1.0f / HD);
        const float var  = s2 * (1.0f / HD) - mean * mean;
        const float rstd = rsqrtf(var + 1e-5f);
        const float ss0 = ssp_f((x20 - mean) * rstd * lg2.x + lb2.x);
        const float ss1 = ssp_f((x21 - mean) * rstd * lg2.y + lb2.y);

        *(float2*)(x2P + (size_t)n * HD + t0) = make_float2(x20, x21);
        sbf[(size_t)n * 64 + l] = pk2(ss0, ss1);
    }
}

// ---------------- K3c: MFMA out-GEMM: out = sbf @ out_w^T + out_b + x2 ------
__global__ __launch_bounds__(256) void k_tail_gemm(
    const unsigned short* __restrict__ sbf, const float* __restrict__ x2P,
    const uint4* __restrict__ owf, const float* __restrict__ out_b,
    float* __restrict__ out)
{
    const int w = threadIdx.x >> 6, l = threadIdx.x & 63;
    const int lm = l & 15, lg = l >> 4;
    const int tile = blockIdx.x * 4 + w;
    if (tile * 16 >= NN) return;
    const int n0 = tile * 16;

    uint4 af[4];
    #pragma unroll
    for (int kt = 0; kt < 4; ++kt)
        af[kt] = *(const uint4*)(sbf + (size_t)(n0 + lm) * HD + kt * 32 + lg * 8);

    f32x4 acc[8];
    #pragma unroll
    for (int nt = 0; nt < 8; ++nt) {
        const float b = out_b[nt * 16 + lm];
        acc[nt] = f32x4{b, b, b, b};
    }
    #pragma unroll
    for (int kt = 0; kt < 4; ++kt) {
        #pragma unroll
        for (int nt = 0; nt < 8; ++nt)
            acc[nt] = __builtin_amdgcn_mfma_f32_16x16x32_bf16(
                as_bf(af[kt]), as_bf(owf[(nt * 4 + kt) * 64 + l]), acc[nt], 0, 0, 0);
    }
    #pragma unroll
    for (int nt = 0; nt < 8; ++nt)
        #pragma unroll
        for (int r = 0; r < 4; ++r) {
            const size_t idx = (size_t)(n0 + lg * 4 + r) * HD + nt * 16 + lm;
            out[idx] = acc[nt][r] + x2P[idx];
        }
}

extern "C" void kernel_launch(void* const* d_in, const int* in_sizes, int n_in,
                              void* d_out, int out_size, void* d_ws, size_t ws_size,
                              hipStream_t stream) {
    const float* x         = (const float*)d_in[0];
    const float* edge_attr = (const float*)d_in[1];
    const int*   edge_index= (const int*)  d_in[2];
    const float* k_w   = (const float*)d_in[3];
    const float* q_w   = (const float*)d_in[4];
    const float* v_w   = (const float*)d_in[5];
    const float* wk1_w = (const float*)d_in[6];
    const float* wk1_b = (const float*)d_in[7];
    const float* wk2_w = (const float*)d_in[8];
    const float* wk2_b = (const float*)d_in[9];
    const float* wkl_w = (const float*)d_in[10];
    const float* wkl_b = (const float*)d_in[11];
    const float* wv1_w = (const float*)d_in[12];
    const float* wv1_b = (const float*)d_in[13];
    const float* wv2_w = (const float*)d_in[14];
    const float* wv2_b = (const float*)d_in[15];
    const float* wvl_w = (const float*)d_in[16];
    const float* wvl_b = (const float*)d_in[17];
    const float* out_w = (const float*)d_in[18];
    const float* out_b = (const float*)d_in[19];
    const float* ln1_g = (const float*)d_in[20];
    const float* ln1_b = (const float*)d_in[21];
    const float* ln2_g = (const float*)d_in[22];
    const float* ln2_b = (const float*)d_in[23];

    char* ws = (char*)d_ws;
    unsigned* hk_bf = (unsigned*)ws;            ws += (size_t)NN * 64 * 4;
    unsigned* hv_bf = (unsigned*)ws;            ws += (size_t)NN * 64 * 4;
    unsigned* g_bf  = (unsigned*)ws;            ws += (size_t)NN * 64 * 4;
    unsigned* y_bf  = (unsigned*)ws;            ws += (size_t)NN * 64 * 4;
    float* c0  = (float*)ws;                    ws += (size_t)NN * NHD * 4;
    float* qkP = (float*)ws;                    ws += (size_t)NHD * EE * 4;
    unsigned* wvP = (unsigned*)ws;              ws += (size_t)EE * 16 * 4;
    unsigned* ea_bf = (unsigned*)ws;            ws += (size_t)EE * 32 * 4;
    uint4* fragbuf = (uint4*)ws;                ws += (size_t)12 * 64 * 16;
    uint4* owfbuf  = (uint4*)ws;                ws += (size_t)32 * 64 * 16;
    uint4* pfbuf   = (uint4*)ws;                ws += (size_t)3 * 512 * 16;
    float* cw      = (float*)ws;                ws += (size_t)512 * 4;
    float* x2P = (float*)ws;                    ws += (size_t)NN * HD * 4;
    unsigned* sbf = (unsigned*)ws;              ws += (size_t)NN * 64 * 4;
    int* deg    = (int*)ws;                     ws += (size_t)NN * 4;
    int* base   = (int*)ws;                     ws += (size_t)NN * 4;
    int* cursor = (int*)ws;                     ws += (size_t)NN * 4;
    int* bsum   = (int*)ws;                     ws += (size_t)SCAN_B * 4;
    int* eidx   = (int*)ws;                     ws += (size_t)EE * 4;
    int* rowv   = (int*)ws;                     ws += (size_t)EE * 4;
    int* colv   = (int*)ws;                     ws += (size_t)EE * 4;

    (void)hipMemsetAsync(deg, 0, (size_t)NN * 4, stream);

    k_wfrag<<<1, 256, 0, stream>>>(wk1_w, wk2_w, wv1_w, wv2_w, fragbuf);
    k_owfrag<<<1, 256, 0, stream>>>(out_w, owfbuf);
    k_pwfrag<<<1, 256, 0, stream>>>(k_w, v_w, q_w, wkl_w, wkl_b, pfbuf, cw);
    k_ln1<<<2048, 256, 0, stream>>>(x, ln1_g, ln1_b, cw, y_bf, c0);
    k_proj<<<(NTILE + 3) / 4, 256, 0, stream>>>(y_bf, pfbuf,
        (unsigned short*)hk_bf, (unsigned short*)hv_bf, (unsigned short*)g_bf);
    k_deg<<<1024, 256, 0, stream>>>(edge_index, deg);
    k_scan_block<<<NBLK, SCAN_B, 0, stream>>>(deg, base, bsum);
    k_scan_top<<<1, SCAN_B, 0, stream>>>(bsum);
    k_scan_add<<<NBLK, SCAN_B, 0, stream>>>(base, bsum, cursor);
    k_scatter<<<1024, 256, 0, stream>>>(edge_index, cursor, eidx, rowv, colv);
    k_ea_csr<<<2048, 256, 0, stream>>>(edge_attr, eidx, ea_bf);
    k_edge_mfma<<<EE / 256, 256, 0, stream>>>(ea_bf, rowv, colv,
        hk_bf, g_bf, c0, fragbuf,
        wk1_b, wk2_b, wv1_b, wv2_b, qkP, wvP);
    k_aggr_tail<<<2048, 256, 0, stream>>>(qkP, wvP, hv_bf, colv, base, deg,
        x, wvl_w, wvl_b, ln2_g, ln2_b, x2P, sbf);
    k_tail_gemm<<<(NN / 16 + 3) / 4, 256, 0, stream>>>(
        (const unsigned short*)sbf, x2P, owfbuf, out_b, (float*)d_out);
}

// Round 14
// 309.718 us; speedup vs baseline: 10.0945x; 1.1668x over previous
//
#include <hip/hip_runtime.h>
#include <math.h>

#define NN 50000
#define EE 640000
#define HD 128
#define ECD 64
#define NHD 4
#define HH 32
#define SCAN_B 256
#define NBLK ((NN + SCAN_B - 1) / SCAN_B)   // 196
#define LSTR 33
#define NTILE (NN / 16)                     // 3125 (exact)

typedef short bf16x8 __attribute__((ext_vector_type(8)));
typedef float f32x4 __attribute__((ext_vector_type(4)));

__device__ __forceinline__ float ssp_f(float v) {
    return fmaxf(v, 0.0f) + __logf(1.0f + __expf(-fabsf(v))) - 0.69314718055994531f;
}
__device__ __forceinline__ unsigned f2bf_u(float f) {
    unsigned u = __float_as_uint(f);
    unsigned r = ((u >> 16) & 1u) + 0x7FFFu;
    return (u + r) >> 16;
}
__device__ __forceinline__ unsigned pk2(float a, float b) {
    return f2bf_u(a) | (f2bf_u(b) << 16);
}
__device__ __forceinline__ unsigned f2bf_f(float f) {
    return (__float_as_uint(f) + 0x8000u) >> 16;
}
__device__ __forceinline__ unsigned pk2f(float a, float b) {
    return f2bf_f(a) | (f2bf_f(b) << 16);
}
__device__ __forceinline__ void unp2(unsigned u, float& a, float& b) {
    a = __uint_as_float(u << 16);
    b = __uint_as_float(u & 0xffff0000u);
}
__device__ __forceinline__ bf16x8 as_bf(uint4 u) {
    union { uint4 a; bf16x8 b; } c; c.a = u; return c.b;
}

// ---------------- projection weight packer ----------------
__global__ __launch_bounds__(256) void k_pwfrag(
    const float* __restrict__ kw, const float* __restrict__ vw,
    const float* __restrict__ qw, const float* __restrict__ wklw,
    const float* __restrict__ wklb,
    uint4* __restrict__ pf, float* __restrict__ cw)
{
    const int t = threadIdx.x;
    #pragma unroll
    for (int it = 0; it < 6; ++it) {
        const int f = t + it * 256;      // 0..1535
        const int tg = f >> 9;
        const int rem = f & 511;
        const int nt = rem >> 6, l = rem & 63;
        const int lm = l & 15, lg = l >> 4;
        const int h = nt >> 1, od = (nt & 1) * 16 + lm;
        float val[8];
        if (tg == 2) {
            #pragma unroll
            for (int j = 0; j < 8; ++j) {
                float s = 0.f;
                for (int j2 = 0; j2 < 32; ++j2)
                    s += qw[(size_t)(h * 32 + j2) * 32 + lg * 8 + j] * wklw[j2 * 32 + od];
                val[j] = s;
            }
        } else {
            const float* wp = (tg == 0) ? kw : vw;
            #pragma unroll
            for (int j = 0; j < 8; ++j)
                val[j] = wp[(size_t)(h * 32 + od) * 32 + lg * 8 + j];
        }
        uint4 o;
        o.x = pk2(val[0], val[1]); o.y = pk2(val[2], val[3]);
        o.z = pk2(val[4], val[5]); o.w = pk2(val[6], val[7]);
        pf[f] = o;
    }
    #pragma unroll
    for (int d2 = 0; d2 < 2; ++d2) {
        const int idx = t * 2 + d2;     // 0..511
        const int h = idx >> 5, d = idx & 31;
        float s = 0.f;
        for (int j = 0; j < 32; ++j)
            s += qw[(size_t)(h * 32 + j) * 32 + d] * wklb[j];
        cw[idx] = s;
    }
}

// ---------------- K1: fused LN1 + c0 + MFMA projections ---------------------
// 2-phase per 16-node tile: 4 waves LN 4 nodes each -> LDS; then each wave
// builds its own A-fragment (af index = w, compile-time-safe) and runs 6 MFMA
// (tg=0..2 x nt=2w,2w+1).
__global__ __launch_bounds__(256) void k_ln1proj(
    const float* __restrict__ x, const float* __restrict__ ln1_g,
    const float* __restrict__ ln1_b, const float* __restrict__ cw,
    const uint4* __restrict__ pf, float* __restrict__ c0_out,
    unsigned short* __restrict__ hk16, unsigned short* __restrict__ hv16,
    unsigned short* __restrict__ g16)
{
    __shared__ unsigned ylds[16][68];   // 16 nodes x 64 uints, stride 68
    const int w = threadIdx.x >> 6, l = threadIdx.x & 63;
    const int lm = l & 15, lg = l >> 4;
    const int t0 = 2 * l;
    const float2 lg2 = *(const float2*)(ln1_g + t0);
    const float2 lb2 = *(const float2*)(ln1_b + t0);
    const float2 cw2 = *(const float2*)(cw + t0);

    for (int tile = blockIdx.x; tile < NTILE; tile += 1024) {
        const int n0 = tile * 16;
        __syncthreads();   // previous iteration's readers done
        #pragma unroll
        for (int it = 0; it < 4; ++it) {
            const int n = n0 + w * 4 + it;
            const float2 xv = *(const float2*)(x + (size_t)n * HD + t0);
            float s1 = xv.x + xv.y;
            float s2 = xv.x * xv.x + xv.y * xv.y;
            #pragma unroll
            for (int off = 1; off < 64; off <<= 1) {
                s1 += __shfl_xor(s1, off);
                s2 += __shfl_xor(s2, off);
            }
            const float mean = s1 * (1.0f / HD);
            const float var  = s2 * (1.0f / HD) - mean * mean;
            const float rstd = rsqrtf(var + 1e-5f);
            const float y0 = (xv.x - mean) * rstd * lg2.x + lb2.x;
            const float y1 = (xv.y - mean) * rstd * lg2.y + lb2.y;
            ylds[w * 4 + it][l] = pk2(y0, y1);
            float p = y0 * cw2.x + y1 * cw2.y;
            #pragma unroll
            for (int off = 1; off < 16; off <<= 1) p += __shfl_xor(p, off);
            if ((l & 15) == 0) c0_out[n * NHD + (l >> 4)] = p;
        }
        __syncthreads();
        // wave w's A fragment: head w, rows=nodes lm, k-slots lg*8..+7
        uint4 am;
        am.x = ylds[lm][w * 16 + lg * 4 + 0];
        am.y = ylds[lm][w * 16 + lg * 4 + 1];
        am.z = ylds[lm][w * 16 + lg * 4 + 2];
        am.w = ylds[lm][w * 16 + lg * 4 + 3];
        #pragma unroll
        for (int tg = 0; tg < 3; ++tg) {
            unsigned short* o = (tg == 0) ? hk16 : (tg == 1) ? hv16 : g16;
            #pragma unroll
            for (int q = 0; q < 2; ++q) {
                const int nt = 2 * w + q;
                f32x4 acc = f32x4{0.f, 0.f, 0.f, 0.f};
                acc = __builtin_amdgcn_mfma_f32_16x16x32_bf16(
                    as_bf(am), as_bf(pf[tg * 512 + nt * 64 + l]), acc, 0, 0, 0);
                #pragma unroll
                for (int r = 0; r < 4; ++r)
                    o[(size_t)(n0 + lg * 4 + r) * HD + nt * 16 + lm] =
                        (unsigned short)f2bf_u(acc[r]);
            }
        }
    }
}

// ---------------- CSR build ----------------
__global__ __launch_bounds__(256) void k_deg(
    const int* __restrict__ edge_index, int* __restrict__ deg)
{
    for (int e = blockIdx.x * blockDim.x + threadIdx.x; e < EE;
         e += gridDim.x * blockDim.x)
        atomicAdd(&deg[edge_index[e]], 1);
}

__global__ __launch_bounds__(SCAN_B) void k_scan_block(
    const int* __restrict__ deg, int* __restrict__ base, int* __restrict__ bsum)
{
    const int i = blockIdx.x * SCAN_B + threadIdx.x;
    const int v = (i < NN) ? deg[i] : 0;
    __shared__ int s[SCAN_B];
    s[threadIdx.x] = v;
    __syncthreads();
    for (int off = 1; off < SCAN_B; off <<= 1) {
        int t = (threadIdx.x >= off) ? s[threadIdx.x - off] : 0;
        __syncthreads();
        s[threadIdx.x] += t;
        __syncthreads();
    }
    if (i < NN) base[i] = s[threadIdx.x] - v;
    if (threadIdx.x == SCAN_B - 1) bsum[blockIdx.x] = s[SCAN_B - 1];
}

__global__ __launch_bounds__(SCAN_B) void k_scan_top(int* __restrict__ bsum)
{
    const int i = threadIdx.x;
    const int v = (i < NBLK) ? bsum[i] : 0;
    __shared__ int s[SCAN_B];
    s[i] = v;
    __syncthreads();
    for (int off = 1; off < SCAN_B; off <<= 1) {
        int t = (i >= off) ? s[i - off] : 0;
        __syncthreads();
        s[i] += t;
        __syncthreads();
    }
    if (i < NBLK) bsum[i] = s[i] - v;
}

__global__ __launch_bounds__(SCAN_B) void k_scan_add(
    int* __restrict__ base, const int* __restrict__ bsum, int* __restrict__ cursor)
{
    const int i = blockIdx.x * SCAN_B + threadIdx.x;
    if (i < NN) {
        const int b = base[i] + bsum[i >> 8];
        base[i] = b;
        cursor[i] = b;
    }
}

__global__ __launch_bounds__(256) void k_scatter(
    const int* __restrict__ edge_index, int* __restrict__ cursor,
    int* __restrict__ eidx, int* __restrict__ rowv, int* __restrict__ colv)
{
    for (int e = blockIdx.x * blockDim.x + threadIdx.x; e < EE;
         e += gridDim.x * blockDim.x) {
        const int r = edge_index[e];
        const int pos = atomicAdd(&cursor[r], 1);
        eidx[pos] = e;
        rowv[pos] = r;
        colv[pos] = edge_index[EE + e];
    }
}

// ---------------- edge-MLP weight fragment packer (1 block) ----------------
__global__ __launch_bounds__(256) void k_wfrag(
    const float* __restrict__ wk1_w, const float* __restrict__ wk2_w,
    const float* __restrict__ wv1_w, const float* __restrict__ wv2_w,
    uint4* __restrict__ frag)
{
    const int t = threadIdx.x;
    const int l = t & 63;
    const int lm = l & 15, lg = l >> 4;
    {
        const int f = t >> 6;          // 0..3
        const int kt = f >> 1, nt = f & 1;
        const int out = nt * 16 + lm;
        uint4 a, b;
        unsigned ra[4], rb[4];
        #pragma unroll
        for (int p = 0; p < 4; ++p) {
            const int in0 = kt * 32 + lg * 8 + 2 * p;
            ra[p] = pk2(wk1_w[(size_t)out * ECD + in0], wk1_w[(size_t)out * ECD + in0 + 1]);
            rb[p] = pk2(wv1_w[(size_t)out * ECD + in0], wv1_w[(size_t)out * ECD + in0 + 1]);
        }
        a.x = ra[0]; a.y = ra[1]; a.z = ra[2]; a.w = ra[3];
        b.x = rb[0]; b.y = rb[1]; b.z = rb[2]; b.w = rb[3];
        frag[f * 64 + l] = a;
        frag[(6 + f) * 64 + l] = b;
    }
    if (t < 128) {
        const int nt = t >> 6;
        const int out = nt * 16 + lm;
        uint4 a, b;
        unsigned ra[4], rb[4];
        #pragma unroll
        for (int p = 0; p < 4; ++p) {
            const int in0 = lg * 8 + 2 * p;
            ra[p] = pk2(wk2_w[(size_t)out * HH + in0], wk2_w[(size_t)out * HH + in0 + 1]);
            rb[p] = pk2(wv2_w[(size_t)out * HH + in0], wv2_w[(size_t)out * HH + in0 + 1]);
        }
        a.x = ra[0]; a.y = ra[1]; a.z = ra[2]; a.w = ra[3];
        b.x = rb[0]; b.y = rb[1]; b.z = rb[2]; b.w = rb[3];
        frag[(4 + nt) * 64 + l] = a;
        frag[(10 + nt) * 64 + l] = b;
    }
}

// ---------------- out_w fragment packer: owf[nt*4+kt][64] ----------------
__global__ __launch_bounds__(256) void k_owfrag(
    const float* __restrict__ out_w, uint4* __restrict__ owf)
{
    const int t = threadIdx.x;
    const int l = t & 63;
    const int lm = l & 15, lg = l >> 4;
    #pragma unroll
    for (int it = 0; it < 8; ++it) {
        const int f = (t >> 6) + it * 4;   // 0..31 = nt*4+kt
        const int nt = f >> 2, kt = f & 3;
        const int n = nt * 16 + lm;
        unsigned r[4];
        #pragma unroll
        for (int p = 0; p < 4; ++p) {
            const int k0 = kt * 32 + lg * 8 + 2 * p;
            r[p] = pk2(out_w[(size_t)n * HD + k0], out_w[(size_t)n * HD + k0 + 1]);
        }
        uint4 o; o.x = r[0]; o.y = r[1]; o.z = r[2]; o.w = r[3];
        owf[f * 64 + l] = o;
    }
}

// ---------------- K2: MFMA edge kernel (wave = 64 edges, direct f32 ea) -----
__global__ __launch_bounds__(256) void k_edge_mfma(
    const float* __restrict__ ea, const int* __restrict__ eidx,
    const int* __restrict__ rowv, const int* __restrict__ colv,
    const unsigned* __restrict__ hk_bf, const unsigned* __restrict__ g_bf,
    const float* __restrict__ c0_in, const uint4* __restrict__ frag,
    const float* __restrict__ wk1_b, const float* __restrict__ wk2_b,
    const float* __restrict__ wv1_b, const float* __restrict__ wv2_b,
    float* __restrict__ qkP, unsigned* __restrict__ wvP)
{
    __shared__ float lds[4][64 * LSTR];
    const int w = threadIdx.x >> 6, l = threadIdx.x & 63;
    const int lm = l & 15, lg = l >> 4;
    float* L = lds[w];
    const int e0 = blockIdx.x * 256 + w * 64;
    const int pos = e0 + l;
    const int row = rowv[pos];
    const int col = colv[pos];

    // A fragments: load original-order f32 ea via eidx, convert to bf16
    uint4 eaf[4][2];
    #pragma unroll
    for (int mt = 0; mt < 4; ++mt) {
        const int ee = eidx[e0 + mt * 16 + lm];
        const float* ep = ea + (size_t)ee * ECD + lg * 8;
        const float4 a0 = *(const float4*)(ep);
        const float4 a1 = *(const float4*)(ep + 4);
        const float4 b0 = *(const float4*)(ep + 32);
        const float4 b1 = *(const float4*)(ep + 36);
        eaf[mt][0].x = pk2f(a0.x, a0.y); eaf[mt][0].y = pk2f(a0.z, a0.w);
        eaf[mt][0].z = pk2f(a1.x, a1.y); eaf[mt][0].w = pk2f(a1.z, a1.w);
        eaf[mt][1].x = pk2f(b0.x, b0.y); eaf[mt][1].y = pk2f(b0.z, b0.w);
        eaf[mt][1].z = pk2f(b1.x, b1.y); eaf[mt][1].w = pk2f(b1.z, b1.w);
    }

    // ================= K path =================
    {
        const float b1a = wk1_b[lm], b1b = wk1_b[16 + lm];
        f32x4 acc[4][2];
        #pragma unroll
        for (int mt = 0; mt < 4; ++mt) {
            acc[mt][0] = f32x4{b1a, b1a, b1a, b1a};
            acc[mt][1] = f32x4{b1b, b1b, b1b, b1b};
        }
        const uint4 f00 = frag[0 * 64 + l], f01 = frag[1 * 64 + l];
        const uint4 f10 = frag[2 * 64 + l], f11 = frag[3 * 64 + l];
        #pragma unroll
        for (int mt = 0; mt < 4; ++mt) {
            acc[mt][0] = __builtin_amdgcn_mfma_f32_16x16x32_bf16(as_bf(eaf[mt][0]), as_bf(f00), acc[mt][0], 0, 0, 0);
            acc[mt][1] = __builtin_amdgcn_mfma_f32_16x16x32_bf16(as_bf(eaf[mt][0]), as_bf(f01), acc[mt][1], 0, 0, 0);
            acc[mt][0] = __builtin_amdgcn_mfma_f32_16x16x32_bf16(as_bf(eaf[mt][1]), as_bf(f10), acc[mt][0], 0, 0, 0);
            acc[mt][1] = __builtin_amdgcn_mfma_f32_16x16x32_bf16(as_bf(eaf[mt][1]), as_bf(f11), acc[mt][1], 0, 0, 0);
        }
        #pragma unroll
        for (int mt = 0; mt < 4; ++mt)
            #pragma unroll
            for (int nt = 0; nt < 2; ++nt)
                #pragma unroll
                for (int r = 0; r < 4; ++r)
                    L[(mt * 16 + lg * 4 + r) * LSTR + nt * 16 + lm] = ssp_f(acc[mt][nt][r]);

        const float b2a = wk2_b[lm], b2b = wk2_b[16 + lm];
        f32x4 acc2[4][2];
        const uint4 f20 = frag[4 * 64 + l], f21 = frag[5 * 64 + l];
        #pragma unroll
        for (int mt = 0; mt < 4; ++mt) {
            acc2[mt][0] = f32x4{b2a, b2a, b2a, b2a};
            acc2[mt][1] = f32x4{b2b, b2b, b2b, b2b};
            float av[8];
            #pragma unroll
            for (int j = 0; j < 8; ++j)
                av[j] = L[(mt * 16 + lm) * LSTR + lg * 8 + j];
            uint4 a2;
            a2.x = pk2f(av[0], av[1]); a2.y = pk2f(av[2], av[3]);
            a2.z = pk2f(av[4], av[5]); a2.w = pk2f(av[6], av[7]);
            acc2[mt][0] = __builtin_amdgcn_mfma_f32_16x16x32_bf16(as_bf(a2), as_bf(f20), acc2[mt][0], 0, 0, 0);
            acc2[mt][1] = __builtin_amdgcn_mfma_f32_16x16x32_bf16(as_bf(a2), as_bf(f21), acc2[mt][1], 0, 0, 0);
        }
        #pragma unroll
        for (int mt = 0; mt < 4; ++mt)
            #pragma unroll
            for (int nt = 0; nt < 2; ++nt)
                #pragma unroll
                for (int r = 0; r < 4; ++r)
                    L[(mt * 16 + lg * 4 + r) * LSTR + nt * 16 + lm] = acc2[mt][nt][r];
    }

    float wk[32];
    #pragma unroll
    for (int j = 0; j < 32; ++j) wk[j] = L[l * LSTR + j];

    {
        const uint4* hkp = (const uint4*)(hk_bf + (size_t)col * 64);
        const uint4* gp  = (const uint4*)(g_bf  + (size_t)row * 64);
        const float4 c0v = *(const float4*)(c0_in + (size_t)row * NHD);
        #pragma unroll
        for (int h = 0; h < NHD; ++h) {
            float s = 0.f;
            #pragma unroll
            for (int q = 0; q < 4; ++q) {
                const uint4 ku = hkp[h * 4 + q];
                const uint4 gu = gp[h * 4 + q];
                float ka, kb, ga, gb;
                unp2(ku.x, ka, kb); unp2(gu.x, ga, gb);
                s = fmaf(wk[q * 8 + 0] * ka, ga, s);
                s = fmaf(wk[q * 8 + 1] * kb, gb, s);
                unp2(ku.y, ka, kb); unp2(gu.y, ga, gb);
                s = fmaf(wk[q * 8 + 2] * ka, ga, s);
                s = fmaf(wk[q * 8 + 3] * kb, gb, s);
                unp2(ku.z, ka, kb); unp2(gu.z, ga, gb);
                s = fmaf(wk[q * 8 + 4] * ka, ga, s);
                s = fmaf(wk[q * 8 + 5] * kb, gb, s);
                unp2(ku.w, ka, kb); unp2(gu.w, ga, gb);
                s = fmaf(wk[q * 8 + 6] * ka, ga, s);
                s = fmaf(wk[q * 8 + 7] * kb, gb, s);
            }
            const float c0h = (h == 0) ? c0v.x : (h == 1) ? c0v.y : (h == 2) ? c0v.z : c0v.w;
            qkP[(size_t)h * EE + pos] = s + c0h;
        }
    }

    // ================= V path =================
    {
        const float b1a = wv1_b[lm], b1b = wv1_b[16 + lm];
        f32x4 acc[4][2];
        #pragma unroll
        for (int mt = 0; mt < 4; ++mt) {
            acc[mt][0] = f32x4{b1a, b1a, b1a, b1a};
            acc[mt][1] = f32x4{b1b, b1b, b1b, b1b};
        }
        const uint4 f00 = frag[6 * 64 + l], f01 = frag[7 * 64 + l];
        const uint4 f10 = frag[8 * 64 + l], f11 = frag[9 * 64 + l];
        #pragma unroll
        for (int mt = 0; mt < 4; ++mt) {
            acc[mt][0] = __builtin_amdgcn_mfma_f32_16x16x32_bf16(as_bf(eaf[mt][0]), as_bf(f00), acc[mt][0], 0, 0, 0);
            acc[mt][1] = __builtin_amdgcn_mfma_f32_16x16x32_bf16(as_bf(eaf[mt][0]), as_bf(f01), acc[mt][1], 0, 0, 0);
            acc[mt][0] = __builtin_amdgcn_mfma_f32_16x16x32_bf16(as_bf(eaf[mt][1]), as_bf(f10), acc[mt][0], 0, 0, 0);
            acc[mt][1] = __builtin_amdgcn_mfma_f32_16x16x32_bf16(as_bf(eaf[mt][1]), as_bf(f11), acc[mt][1], 0, 0, 0);
        }
        #pragma unroll
        for (int mt = 0; mt < 4; ++mt)
            #pragma unroll
            for (int nt = 0; nt < 2; ++nt)
                #pragma unroll
                for (int r = 0; r < 4; ++r)
                    L[(mt * 16 + lg * 4 + r) * LSTR + nt * 16 + lm] = ssp_f(acc[mt][nt][r]);

        const float b2a = wv2_b[lm], b2b = wv2_b[16 + lm];
        f32x4 acc2[4][2];
        const uint4 f20 = frag[10 * 64 + l], f21 = frag[11 * 64 + l];
        #pragma unroll
        for (int mt = 0; mt < 4; ++mt) {
            acc2[mt][0] = f32x4{b2a, b2a, b2a, b2a};
            acc2[mt][1] = f32x4{b2b, b2b, b2b, b2b};
            float av[8];
            #pragma unroll
            for (int j = 0; j < 8; ++j)
                av[j] = L[(mt * 16 + lm) * LSTR + lg * 8 + j];
            uint4 a2;
            a2.x = pk2f(av[0], av[1]); a2.y = pk2f(av[2], av[3]);
            a2.z = pk2f(av[4], av[5]); a2.w = pk2f(av[6], av[7]);
            acc2[mt][0] = __builtin_amdgcn_mfma_f32_16x16x32_bf16(as_bf(a2), as_bf(f20), acc2[mt][0], 0, 0, 0);
            acc2[mt][1] = __builtin_amdgcn_mfma_f32_16x16x32_bf16(as_bf(a2), as_bf(f21), acc2[mt][1], 0, 0, 0);
        }
        #pragma unroll
        for (int mt = 0; mt < 4; ++mt)
            #pragma unroll
            for (int nt = 0; nt < 2; ++nt)
                #pragma unroll
                for (int r = 0; r < 4; ++r)
                    L[(mt * 16 + lg * 4 + r) * LSTR + nt * 16 + lm] = acc2[mt][nt][r];
    }

    #pragma unroll
    for (int k = 0; k < 16; ++k) {
        const int f = k * 64 + l;
        const int pr = f >> 4, i = f & 15;
        wvP[(size_t)e0 * 16 + f] = pk2f(L[pr * LSTR + 2 * i], L[pr * LSTR + 2 * i + 1]);
    }
}

// ---------------- K3: fused aggregation + wvl matvec + LN2 + ssp ------------
__global__ __launch_bounds__(256) void k_aggr_tail(
    const float* __restrict__ qkP, const unsigned* __restrict__ wvP,
    const unsigned* __restrict__ hv_bf, const int* __restrict__ colv,
    const int* __restrict__ base, const int* __restrict__ deg,
    const float* __restrict__ x,
    const float* __restrict__ wvl_w, const float* __restrict__ wvl_b,
    const float* __restrict__ ln2_g, const float* __restrict__ ln2_b,
    float* __restrict__ x2P, unsigned* __restrict__ sbf)
{
    __shared__ float swvl[HH * 34];
    __shared__ float su[4][HD];
    for (int idx = threadIdx.x; idx < HH * HH; idx += 256)
        swvl[(idx >> 5) * 34 + (idx & 31)] = wvl_w[idx];
    __syncthreads();

    const int w = threadIdx.x >> 6, l = threadIdx.x & 63;
    const int h = l >> 4, i = l & 15;
    const int t0 = 2 * l;
    const float2 lg2 = *(const float2*)(ln2_g + t0);
    const float2 lb2 = *(const float2*)(ln2_b + t0);
    const int j0 = 2 * i;
    const float2 wb2 = *(const float2*)(wvl_b + j0);
    float* sb = su[w];

    for (int n = blockIdx.x * 4 + w; n < NN; n += 2048 * 4) {
        const int b0 = base[n];
        const int dn = deg[n];
        const float2 xv = *(const float2*)(x + (size_t)n * HD + t0);

        float acc0 = 0.f, acc1 = 0.f;
        if (dn > 0) {
            const float* qkh = qkP + (size_t)h * EE + b0;
            const int emax = b0 + dn - 1;
            float m = -3.0e38f;
            for (int c = i; c < dn; c += 16) m = fmaxf(m, qkh[c]);
            #pragma unroll
            for (int off = 1; off < 16; off <<= 1)
                m = fmaxf(m, __shfl_xor(m, off));
            float den = 0.f;
            for (int c = i; c < dn; c += 16) den += __expf(qkh[c] - m);
            #pragma unroll
            for (int off = 1; off < 16; off <<= 1) den += __shfl_xor(den, off);
            const float rden = (den > 0.f) ? 1.0f / den : 0.f;
            for (int c0 = 0; c0 < dn; c0 += 16) {
                const int tn = (dn - c0 < 16) ? (dn - c0) : 16;
                float ex = 0.f; int cq = 0;
                if (i < tn) {
                    ex = __expf(qkh[c0 + i] - m) * rden;
                    cq = colv[b0 + c0 + i];
                }
                const int t4 = (tn + 3) & ~3;
                for (int i2 = 0; i2 < t4; i2 += 4) {
                    #pragma unroll
                    for (int u = 0; u < 4; ++u) {
                        const int src = (l & 48) | (i2 + u);
                        const float wgt = __shfl(ex, src);
                        const int ce = __shfl(cq, src);
                        int ep = b0 + c0 + i2 + u;
                        ep = (ep > emax) ? emax : ep;
                        const unsigned hvv = hv_bf[(size_t)ce * 64 + l];
                        const unsigned wvv = wvP[(size_t)ep * 16 + i];
                        float ha, hb, wa, wb;
                        unp2(hvv, ha, hb); unp2(wvv, wa, wb);
                        acc0 = fmaf(wgt, wa * ha, acc0);
                        acc1 = fmaf(wgt, wb * hb, acc1);
                    }
                }
            }
        }

        *(float2*)(sb + t0) = make_float2(acc0, acc1);

        float ag0 = 0.f, ag1 = 0.f;
        if (dn > 0) {
            ag0 = wb2.x; ag1 = wb2.y;
            const float* uh = sb + h * HH;
            const float* r0 = swvl + j0 * 34;
            const float* r1 = r0 + 34;
            #pragma unroll
            for (int q = 0; q < 16; ++q) {
                const float2 u  = *(const float2*)(uh + 2 * q);
                const float2 a  = *(const float2*)(r0 + 2 * q);
                const float2 bb = *(const float2*)(r1 + 2 * q);
                ag0 = fmaf(u.x, a.x, ag0);  ag0 = fmaf(u.y, a.y, ag0);
                ag1 = fmaf(u.x, bb.x, ag1); ag1 = fmaf(u.y, bb.y, ag1);
            }
        }
        const float x20 = ag0 + xv.x;
        const float x21 = ag1 + xv.y;

        float s1 = x20 + x21, s2 = x20 * x20 + x21 * x21;
        #pragma unroll
        for (int off = 1; off < 64; off <<= 1) {
            s1 += __shfl_xor(s1, off);
            s2 += __shfl_xor(s2, off);
        }
        const float mean = s1 * (1.0f / HD);
        const float var  = s2 * (1.0f / HD) - mean * mean;
        const float rstd = rsqrtf(var + 1e-5f);
        const float ss0 = ssp_f((x20 - mean) * rstd * lg2.x + lb2.x);
        const float ss1 = ssp_f((x21 - mean) * rstd * lg2.y + lb2.y);

        *(float2*)(x2P + (size_t)n * HD + t0) = make_float2(x20, x21);
        sbf[(size_t)n * 64 + l] = pk2(ss0, ss1);
    }
}

// ---------------- K3c: MFMA out-GEMM: out = sbf @ out_w^T + out_b + x2 ------
__global__ __launch_bounds__(256) void k_tail_gemm(
    const unsigned short* __restrict__ sbf, const float* __restrict__ x2P,
    const uint4* __restrict__ owf, const float* __restrict__ out_b,
    float* __restrict__ out)
{
    const int w = threadIdx.x >> 6, l = threadIdx.x & 63;
    const int lm = l & 15, lg = l >> 4;
    const int tile = blockIdx.x * 4 + w;
    if (tile * 16 >= NN) return;
    const int n0 = tile * 16;

    uint4 af[4];
    #pragma unroll
    for (int kt = 0; kt < 4; ++kt)
        af[kt] = *(const uint4*)(sbf + (size_t)(n0 + lm) * HD + kt * 32 + lg * 8);

    f32x4 acc[8];
    #pragma unroll
    for (int nt = 0; nt < 8; ++nt) {
        const float b = out_b[nt * 16 + lm];
        acc[nt] = f32x4{b, b, b, b};
    }
    #pragma unroll
    for (int kt = 0; kt < 4; ++kt) {
        #pragma unroll
        for (int nt = 0; nt < 8; ++nt)
            acc[nt] = __builtin_amdgcn_mfma_f32_16x16x32_bf16(
                as_bf(af[kt]), as_bf(owf[(nt * 4 + kt) * 64 + l]), acc[nt], 0, 0, 0);
    }
    #pragma unroll
    for (int nt = 0; nt < 8; ++nt)
        #pragma unroll
        for (int r = 0; r < 4; ++r) {
            const size_t idx = (size_t)(n0 + lg * 4 + r) * HD + nt * 16 + lm;
            out[idx] = acc[nt][r] + x2P[idx];
        }
}

extern "C" void kernel_launch(void* const* d_in, const int* in_sizes, int n_in,
                              void* d_out, int out_size, void* d_ws, size_t ws_size,
                              hipStream_t stream) {
    const float* x         = (const float*)d_in[0];
    const float* edge_attr = (const float*)d_in[1];
    const int*   edge_index= (const int*)  d_in[2];
    const float* k_w   = (const float*)d_in[3];
    const float* q_w   = (const float*)d_in[4];
    const float* v_w   = (const float*)d_in[5];
    const float* wk1_w = (const float*)d_in[6];
    const float* wk1_b = (const float*)d_in[7];
    const float* wk2_w = (const float*)d_in[8];
    const float* wk2_b = (const float*)d_in[9];
    const float* wkl_w = (const float*)d_in[10];
    const float* wkl_b = (const float*)d_in[11];
    const float* wv1_w = (const float*)d_in[12];
    const float* wv1_b = (const float*)d_in[13];
    const float* wv2_w = (const float*)d_in[14];
    const float* wv2_b = (const float*)d_in[15];
    const float* wvl_w = (const float*)d_in[16];
    const float* wvl_b = (const float*)d_in[17];
    const float* out_w = (const float*)d_in[18];
    const float* out_b = (const float*)d_in[19];
    const float* ln1_g = (const float*)d_in[20];
    const float* ln1_b = (const float*)d_in[21];
    const float* ln2_g = (const float*)d_in[22];
    const float* ln2_b = (const float*)d_in[23];

    char* ws = (char*)d_ws;
    unsigned* hk_bf = (unsigned*)ws;            ws += (size_t)NN * 64 * 4;
    unsigned* hv_bf = (unsigned*)ws;            ws += (size_t)NN * 64 * 4;
    unsigned* g_bf  = (unsigned*)ws;            ws += (size_t)NN * 64 * 4;
    float* c0  = (float*)ws;                    ws += (size_t)NN * NHD * 4;
    float* qkP = (float*)ws;                    ws += (size_t)NHD * EE * 4;
    unsigned* wvP = (unsigned*)ws;              ws += (size_t)EE * 16 * 4;
    uint4* fragbuf = (uint4*)ws;                ws += (size_t)12 * 64 * 16;
    uint4* owfbuf  = (uint4*)ws;                ws += (size_t)32 * 64 * 16;
    uint4* pfbuf   = (uint4*)ws;                ws += (size_t)3 * 512 * 16;
    float* cw      = (float*)ws;                ws += (size_t)512 * 4;
    float* x2P = (float*)ws;                    ws += (size_t)NN * HD * 4;
    unsigned* sbf = (unsigned*)ws;              ws += (size_t)NN * 64 * 4;
    int* deg    = (int*)ws;                     ws += (size_t)NN * 4;
    int* base   = (int*)ws;                     ws += (size_t)NN * 4;
    int* cursor = (int*)ws;                     ws += (size_t)NN * 4;
    int* bsum   = (int*)ws;                     ws += (size_t)SCAN_B * 4;
    int* eidx   = (int*)ws;                     ws += (size_t)EE * 4;
    int* rowv   = (int*)ws;                     ws += (size_t)EE * 4;
    int* colv   = (int*)ws;                     ws += (size_t)EE * 4;

    (void)hipMemsetAsync(deg, 0, (size_t)NN * 4, stream);

    k_wfrag<<<1, 256, 0, stream>>>(wk1_w, wk2_w, wv1_w, wv2_w, fragbuf);
    k_owfrag<<<1, 256, 0, stream>>>(out_w, owfbuf);
    k_pwfrag<<<1, 256, 0, stream>>>(k_w, v_w, q_w, wkl_w, wkl_b, pfbuf, cw);
    k_ln1proj<<<1024, 256, 0, stream>>>(x, ln1_g, ln1_b, cw, pfbuf, c0,
        (unsigned short*)hk_bf, (unsigned short*)hv_bf, (unsigned short*)g_bf);
    k_deg<<<1024, 256, 0, stream>>>(edge_index, deg);
    k_scan_block<<<NBLK, SCAN_B, 0, stream>>>(deg, base, bsum);
    k_scan_top<<<1, SCAN_B, 0, stream>>>(bsum);
    k_scan_add<<<NBLK, SCAN_B, 0, stream>>>(base, bsum, cursor);
    k_scatter<<<1024, 256, 0, stream>>>(edge_index, cursor, eidx, rowv, colv);
    k_edge_mfma<<<EE / 256, 256, 0, stream>>>(edge_attr, eidx, rowv, colv,
        hk_bf, g_bf, c0, fragbuf,
        wk1_b, wk2_b, wv1_b, wv2_b, qkP, wvP);
    k_aggr_tail<<<2048, 256, 0, stream>>>(qkP, wvP, hv_bf, colv, base, deg,
        x, wvl_w, wvl_b, ln2_g, ln2_b, x2P, sbf);
    k_tail_gemm<<<(NN / 16 + 3) / 4, 256, 0, stream>>>(
        (const unsigned short*)sbf, x2P, owfbuf, out_b, (float*)d_out);
}

// Round 16
// 309.370 us; speedup vs baseline: 10.1059x; 1.0011x over previous
//
#include <hip/hip_runtime.h>
#include <math.h>

#define NN 50000
#define EE 640000
#define HD 128
#define ECD 64
#define NHD 4
#define HH 32
#define SCAN_B 256
#define NBLK ((NN + SCAN_B - 1) / SCAN_B)   // 196
#define LSTR 33
#define NTILE (NN / 16)                     // 3125 (exact)

typedef short bf16x8 __attribute__((ext_vector_type(8)));
typedef float f32x4 __attribute__((ext_vector_type(4)));

__device__ __forceinline__ float ssp_f(float v) {
    return fmaxf(v, 0.0f) + __logf(1.0f + __expf(-fabsf(v))) - 0.69314718055994531f;
}
__device__ __forceinline__ unsigned f2bf_u(float f) {
    unsigned u = __float_as_uint(f);
    unsigned r = ((u >> 16) & 1u) + 0x7FFFu;
    return (u + r) >> 16;
}
__device__ __forceinline__ unsigned pk2(float a, float b) {
    return f2bf_u(a) | (f2bf_u(b) << 16);
}
__device__ __forceinline__ unsigned f2bf_f(float f) {
    return (__float_as_uint(f) + 0x8000u) >> 16;
}
__device__ __forceinline__ unsigned pk2f(float a, float b) {
    return f2bf_f(a) | (f2bf_f(b) << 16);
}
__device__ __forceinline__ void unp2(unsigned u, float& a, float& b) {
    a = __uint_as_float(u << 16);
    b = __uint_as_float(u & 0xffff0000u);
}
__device__ __forceinline__ bf16x8 as_bf(uint4 u) {
    union { uint4 a; bf16x8 b; } c; c.a = u; return c.b;
}

// ---------------- projection weight packer ----------------
__global__ __launch_bounds__(256) void k_pwfrag(
    const float* __restrict__ kw, const float* __restrict__ vw,
    const float* __restrict__ qw, const float* __restrict__ wklw,
    const float* __restrict__ wklb,
    uint4* __restrict__ pf, float* __restrict__ cw)
{
    const int t = threadIdx.x;
    #pragma unroll
    for (int it = 0; it < 6; ++it) {
        const int f = t + it * 256;      // 0..1535
        const int tg = f >> 9;
        const int rem = f & 511;
        const int nt = rem >> 6, l = rem & 63;
        const int lm = l & 15, lg = l >> 4;
        const int h = nt >> 1, od = (nt & 1) * 16 + lm;
        float val[8];
        if (tg == 2) {
            #pragma unroll
            for (int j = 0; j < 8; ++j) {
                float s = 0.f;
                for (int j2 = 0; j2 < 32; ++j2)
                    s += qw[(size_t)(h * 32 + j2) * 32 + lg * 8 + j] * wklw[j2 * 32 + od];
                val[j] = s;
            }
        } else {
            const float* wp = (tg == 0) ? kw : vw;
            #pragma unroll
            for (int j = 0; j < 8; ++j)
                val[j] = wp[(size_t)(h * 32 + od) * 32 + lg * 8 + j];
        }
        uint4 o;
        o.x = pk2(val[0], val[1]); o.y = pk2(val[2], val[3]);
        o.z = pk2(val[4], val[5]); o.w = pk2(val[6], val[7]);
        pf[f] = o;
    }
    #pragma unroll
    for (int d2 = 0; d2 < 2; ++d2) {
        const int idx = t * 2 + d2;     // 0..511
        const int h = idx >> 5, d = idx & 31;
        float s = 0.f;
        for (int j = 0; j < 32; ++j)
            s += qw[(size_t)(h * 32 + j) * 32 + d] * wklb[j];
        cw[idx] = s;
    }
}

// ---------------- K1: fused LN1 + c0 + MFMA projections ---------------------
__global__ __launch_bounds__(256) void k_ln1proj(
    const float* __restrict__ x, const float* __restrict__ ln1_g,
    const float* __restrict__ ln1_b, const float* __restrict__ cw,
    const uint4* __restrict__ pf, float* __restrict__ c0_out,
    unsigned short* __restrict__ hk16, unsigned short* __restrict__ hv16,
    unsigned short* __restrict__ g16)
{
    __shared__ unsigned ylds[16][68];   // 16 nodes x 64 uints, stride 68
    const int w = threadIdx.x >> 6, l = threadIdx.x & 63;
    const int lm = l & 15, lg = l >> 4;
    const int t0 = 2 * l;
    const float2 lg2 = *(const float2*)(ln1_g + t0);
    const float2 lb2 = *(const float2*)(ln1_b + t0);
    const float2 cw2 = *(const float2*)(cw + t0);

    for (int tile = blockIdx.x; tile < NTILE; tile += 1024) {
        const int n0 = tile * 16;
        __syncthreads();   // previous iteration's readers done
        #pragma unroll
        for (int it = 0; it < 4; ++it) {
            const int n = n0 + w * 4 + it;
            const float2 xv = *(const float2*)(x + (size_t)n * HD + t0);
            float s1 = xv.x + xv.y;
            float s2 = xv.x * xv.x + xv.y * xv.y;
            #pragma unroll
            for (int off = 1; off < 64; off <<= 1) {
                s1 += __shfl_xor(s1, off);
                s2 += __shfl_xor(s2, off);
            }
            const float mean = s1 * (1.0f / HD);
            const float var  = s2 * (1.0f / HD) - mean * mean;
            const float rstd = rsqrtf(var + 1e-5f);
            const float y0 = (xv.x - mean) * rstd * lg2.x + lb2.x;
            const float y1 = (xv.y - mean) * rstd * lg2.y + lb2.y;
            ylds[w * 4 + it][l] = pk2(y0, y1);
            float p = y0 * cw2.x + y1 * cw2.y;
            #pragma unroll
            for (int off = 1; off < 16; off <<= 1) p += __shfl_xor(p, off);
            if ((l & 15) == 0) c0_out[n * NHD + (l >> 4)] = p;
        }
        __syncthreads();
        // wave w's A fragment: head w, rows=nodes lm, k-slots lg*8..+7
        uint4 am;
        am.x = ylds[lm][w * 16 + lg * 4 + 0];
        am.y = ylds[lm][w * 16 + lg * 4 + 1];
        am.z = ylds[lm][w * 16 + lg * 4 + 2];
        am.w = ylds[lm][w * 16 + lg * 4 + 3];
        #pragma unroll
        for (int tg = 0; tg < 3; ++tg) {
            unsigned short* o = (tg == 0) ? hk16 : (tg == 1) ? hv16 : g16;
            #pragma unroll
            for (int q = 0; q < 2; ++q) {
                const int nt = 2 * w + q;
                f32x4 acc = f32x4{0.f, 0.f, 0.f, 0.f};
                acc = __builtin_amdgcn_mfma_f32_16x16x32_bf16(
                    as_bf(am), as_bf(pf[tg * 512 + nt * 64 + l]), acc, 0, 0, 0);
                #pragma unroll
                for (int r = 0; r < 4; ++r)
                    o[(size_t)(n0 + lg * 4 + r) * HD + nt * 16 + lm] =
                        (unsigned short)f2bf_u(acc[r]);
            }
        }
    }
}

// ---------------- CSR build ----------------
__global__ __launch_bounds__(256) void k_deg(
    const int* __restrict__ edge_index, int* __restrict__ deg)
{
    for (int e = blockIdx.x * blockDim.x + threadIdx.x; e < EE;
         e += gridDim.x * blockDim.x)
        atomicAdd(&deg[edge_index[e]], 1);
}

__global__ __launch_bounds__(SCAN_B) void k_scan_block(
    const int* __restrict__ deg, int* __restrict__ base, int* __restrict__ bsum)
{
    const int i = blockIdx.x * SCAN_B + threadIdx.x;
    const int v = (i < NN) ? deg[i] : 0;
    __shared__ int s[SCAN_B];
    s[threadIdx.x] = v;
    __syncthreads();
    for (int off = 1; off < SCAN_B; off <<= 1) {
        int t = (threadIdx.x >= off) ? s[threadIdx.x - off] : 0;
        __syncthreads();
        s[threadIdx.x] += t;
        __syncthreads();
    }
    if (i < NN) base[i] = s[threadIdx.x] - v;
    if (threadIdx.x == SCAN_B - 1) bsum[blockIdx.x] = s[SCAN_B - 1];
}

__global__ __launch_bounds__(SCAN_B) void k_scan_top(int* __restrict__ bsum)
{
    const int i = threadIdx.x;
    const int v = (i < NBLK) ? bsum[i] : 0;
    __shared__ int s[SCAN_B];
    s[i] = v;
    __syncthreads();
    for (int off = 1; off < SCAN_B; off <<= 1) {
        int t = (i >= off) ? s[i - off] : 0;
        __syncthreads();
        s[i] += t;
        __syncthreads();
    }
    if (i < NBLK) bsum[i] = s[i] - v;
}

__global__ __launch_bounds__(SCAN_B) void k_scan_add(
    int* __restrict__ base, const int* __restrict__ bsum, int* __restrict__ cursor)
{
    const int i = blockIdx.x * SCAN_B + threadIdx.x;
    if (i < NN) {
        const int b = base[i] + bsum[i >> 8];
        base[i] = b;
        cursor[i] = b;
    }
}

__global__ __launch_bounds__(256) void k_scatter(
    const int* __restrict__ edge_index, int* __restrict__ cursor,
    int* __restrict__ eidx, int* __restrict__ rowv, int* __restrict__ colv)
{
    for (int e = blockIdx.x * blockDim.x + threadIdx.x; e < EE;
         e += gridDim.x * blockDim.x) {
        const int r = edge_index[e];
        const int pos = atomicAdd(&cursor[r], 1);
        eidx[pos] = e;
        rowv[pos] = r;
        colv[pos] = edge_index[EE + e];
    }
}

// ---------------- edge-MLP weight fragment packer (1 block) ----------------
__global__ __launch_bounds__(256) void k_wfrag(
    const float* __restrict__ wk1_w, const float* __restrict__ wk2_w,
    const float* __restrict__ wv1_w, const float* __restrict__ wv2_w,
    uint4* __restrict__ frag)
{
    const int t = threadIdx.x;
    const int l = t & 63;
    const int lm = l & 15, lg = l >> 4;
    {
        const int f = t >> 6;          // 0..3
        const int kt = f >> 1, nt = f & 1;
        const int out = nt * 16 + lm;
        uint4 a, b;
        unsigned ra[4], rb[4];
        #pragma unroll
        for (int p = 0; p < 4; ++p) {
            const int in0 = kt * 32 + lg * 8 + 2 * p;
            ra[p] = pk2(wk1_w[(size_t)out * ECD + in0], wk1_w[(size_t)out * ECD + in0 + 1]);
            rb[p] = pk2(wv1_w[(size_t)out * ECD + in0], wv1_w[(size_t)out * ECD + in0 + 1]);
        }
        a.x = ra[0]; a.y = ra[1]; a.z = ra[2]; a.w = ra[3];
        b.x = rb[0]; b.y = rb[1]; b.z = rb[2]; b.w = rb[3];
        frag[f * 64 + l] = a;
        frag[(6 + f) * 64 + l] = b;
    }
    if (t < 128) {
        const int nt = t >> 6;
        const int out = nt * 16 + lm;
        uint4 a, b;
        unsigned ra[4], rb[4];
        #pragma unroll
        for (int p = 0; p < 4; ++p) {
            const int in0 = lg * 8 + 2 * p;
            ra[p] = pk2(wk2_w[(size_t)out * HH + in0], wk2_w[(size_t)out * HH + in0 + 1]);
            rb[p] = pk2(wv2_w[(size_t)out * HH + in0], wv2_w[(size_t)out * HH + in0 + 1]);
        }
        a.x = ra[0]; a.y = ra[1]; a.z = ra[2]; a.w = ra[3];
        b.x = rb[0]; b.y = rb[1]; b.z = rb[2]; b.w = rb[3];
        frag[(4 + nt) * 64 + l] = a;
        frag[(10 + nt) * 64 + l] = b;
    }
}

// ---------------- out_w fragment packer: owf[nt*4+kt][64] ----------------
__global__ __launch_bounds__(256) void k_owfrag(
    const float* __restrict__ out_w, uint4* __restrict__ owf)
{
    const int t = threadIdx.x;
    const int l = t & 63;
    const int lm = l & 15, lg = l >> 4;
    #pragma unroll
    for (int it = 0; it < 8; ++it) {
        const int f = (t >> 6) + it * 4;   // 0..31 = nt*4+kt
        const int nt = f >> 2, kt = f & 3;
        const int n = nt * 16 + lm;
        unsigned r[4];
        #pragma unroll
        for (int p = 0; p < 4; ++p) {
            const int k0 = kt * 32 + lg * 8 + 2 * p;
            r[p] = pk2(out_w[(size_t)n * HD + k0], out_w[(size_t)n * HD + k0 + 1]);
        }
        uint4 o; o.x = r[0]; o.y = r[1]; o.z = r[2]; o.w = r[3];
        owf[f * 64 + l] = o;
    }
}

// ---------------- K2: MFMA edge kernel (wave = 64 edges, direct f32 ea) -----
__global__ __launch_bounds__(256) void k_edge_mfma(
    const float* __restrict__ ea, const int* __restrict__ eidx,
    const int* __restrict__ rowv, const int* __restrict__ colv,
    const unsigned* __restrict__ hk_bf, const unsigned* __restrict__ g_bf,
    const float* __restrict__ c0_in, const uint4* __restrict__ frag,
    const float* __restrict__ wk1_b, const float* __restrict__ wk2_b,
    const float* __restrict__ wv1_b, const float* __restrict__ wv2_b,
    float* __restrict__ qkP, unsigned* __restrict__ wvP)
{
    __shared__ float lds[4][64 * LSTR];
    const int w = threadIdx.x >> 6, l = threadIdx.x & 63;
    const int lm = l & 15, lg = l >> 4;
    float* L = lds[w];
    const int e0 = blockIdx.x * 256 + w * 64;
    const int pos = e0 + l;
    const int row = rowv[pos];
    const int col = colv[pos];

    // A fragments: load original-order f32 ea via eidx, convert to bf16
    uint4 eaf[4][2];
    #pragma unroll
    for (int mt = 0; mt < 4; ++mt) {
        const int ee = eidx[e0 + mt * 16 + lm];
        const float* ep = ea + (size_t)ee * ECD + lg * 8;
        const float4 a0 = *(const float4*)(ep);
        const float4 a1 = *(const float4*)(ep + 4);
        const float4 b0 = *(const float4*)(ep + 32);
        const float4 b1 = *(const float4*)(ep + 36);
        eaf[mt][0].x = pk2f(a0.x, a0.y); eaf[mt][0].y = pk2f(a0.z, a0.w);
        eaf[mt][0].z = pk2f(a1.x, a1.y); eaf[mt][0].w = pk2f(a1.z, a1.w);
        eaf[mt][1].x = pk2f(b0.x, b0.y); eaf[mt][1].y = pk2f(b0.z, b0.w);
        eaf[mt][1].z = pk2f(b1.x, b1.y); eaf[mt][1].w = pk2f(b1.z, b1.w);
    }

    // ================= K path =================
    {
        const float b1a = wk1_b[lm], b1b = wk1_b[16 + lm];
        f32x4 acc[4][2];
        #pragma unroll
        for (int mt = 0; mt < 4; ++mt) {
            acc[mt][0] = f32x4{b1a, b1a, b1a, b1a};
            acc[mt][1] = f32x4{b1b, b1b, b1b, b1b};
        }
        const uint4 f00 = frag[0 * 64 + l], f01 = frag[1 * 64 + l];
        const uint4 f10 = frag[2 * 64 + l], f11 = frag[3 * 64 + l];
        #pragma unroll
        for (int mt = 0; mt < 4; ++mt) {
            acc[mt][0] = __builtin_amdgcn_mfma_f32_16x16x32_bf16(as_bf(eaf[mt][0]), as_bf(f00), acc[mt][0], 0, 0, 0);
            acc[mt][1] = __builtin_amdgcn_mfma_f32_16x16x32_bf16(as_bf(eaf[mt][0]), as_bf(f01), acc[mt][1], 0, 0, 0);
            acc[mt][0] = __builtin_amdgcn_mfma_f32_16x16x32_bf16(as_bf(eaf[mt][1]), as_bf(f10), acc[mt][0], 0, 0, 0);
            acc[mt][1] = __builtin_amdgcn_mfma_f32_16x16x32_bf16(as_bf(eaf[mt][1]), as_bf(f11), acc[mt][1], 0, 0, 0);
        }
        #pragma unroll
        for (int mt = 0; mt < 4; ++mt)
            #pragma unroll
            for (int nt = 0; nt < 2; ++nt)
                #pragma unroll
                for (int r = 0; r < 4; ++r)
                    L[(mt * 16 + lg * 4 + r) * LSTR + nt * 16 + lm] = ssp_f(acc[mt][nt][r]);

        const float b2a = wk2_b[lm], b2b = wk2_b[16 + lm];
        f32x4 acc2[4][2];
        const uint4 f20 = frag[4 * 64 + l], f21 = frag[5 * 64 + l];
        #pragma unroll
        for (int mt = 0; mt < 4; ++mt) {
            acc2[mt][0] = f32x4{b2a, b2a, b2a, b2a};
            acc2[mt][1] = f32x4{b2b, b2b, b2b, b2b};
            float av[8];
            #pragma unroll
            for (int j = 0; j < 8; ++j)
                av[j] = L[(mt * 16 + lm) * LSTR + lg * 8 + j];
            uint4 a2;
            a2.x = pk2f(av[0], av[1]); a2.y = pk2f(av[2], av[3]);
            a2.z = pk2f(av[4], av[5]); a2.w = pk2f(av[6], av[7]);
            acc2[mt][0] = __builtin_amdgcn_mfma_f32_16x16x32_bf16(as_bf(a2), as_bf(f20), acc2[mt][0], 0, 0, 0);
            acc2[mt][1] = __builtin_amdgcn_mfma_f32_16x16x32_bf16(as_bf(a2), as_bf(f21), acc2[mt][1], 0, 0, 0);
        }
        #pragma unroll
        for (int mt = 0; mt < 4; ++mt)
            #pragma unroll
            for (int nt = 0; nt < 2; ++nt)
                #pragma unroll
                for (int r = 0; r < 4; ++r)
                    L[(mt * 16 + lg * 4 + r) * LSTR + nt * 16 + lm] = acc2[mt][nt][r];
    }

    float wk[32];
    #pragma unroll
    for (int j = 0; j < 32; ++j) wk[j] = L[l * LSTR + j];

    {
        const uint4* hkp = (const uint4*)(hk_bf + (size_t)col * 64);
        const uint4* gp  = (const uint4*)(g_bf  + (size_t)row * 64);
        const float4 c0v = *(const float4*)(c0_in + (size_t)row * NHD);
        #pragma unroll
        for (int h = 0; h < NHD; ++h) {
            float s = 0.f;
            #pragma unroll
            for (int q = 0; q < 4; ++q) {
                const uint4 ku = hkp[h * 4 + q];
                const uint4 gu = gp[h * 4 + q];
                float ka, kb, ga, gb;
                unp2(ku.x, ka, kb); unp2(gu.x, ga, gb);
                s = fmaf(wk[q * 8 + 0] * ka, ga, s);
                s = fmaf(wk[q * 8 + 1] * kb, gb, s);
                unp2(ku.y, ka, kb); unp2(gu.y, ga, gb);
                s = fmaf(wk[q * 8 + 2] * ka, ga, s);
                s = fmaf(wk[q * 8 + 3] * kb, gb, s);
                unp2(ku.z, ka, kb); unp2(gu.z, ga, gb);
                s = fmaf(wk[q * 8 + 4] * ka, ga, s);
                s = fmaf(wk[q * 8 + 5] * kb, gb, s);
                unp2(ku.w, ka, kb); unp2(gu.w, ga, gb);
                s = fmaf(wk[q * 8 + 6] * ka, ga, s);
                s = fmaf(wk[q * 8 + 7] * kb, gb, s);
            }
            const float c0h = (h == 0) ? c0v.x : (h == 1) ? c0v.y : (h == 2) ? c0v.z : c0v.w;
            qkP[(size_t)h * EE + pos] = s + c0h;
        }
    }

    // ================= V path =================
    {
        const float b1a = wv1_b[lm], b1b = wv1_b[16 + lm];
        f32x4 acc[4][2];
        #pragma unroll
        for (int mt = 0; mt < 4; ++mt) {
            acc[mt][0] = f32x4{b1a, b1a, b1a, b1a};
            acc[mt][1] = f32x4{b1b, b1b, b1b, b1b};
        }
        const uint4 f00 = frag[6 * 64 + l], f01 = frag[7 * 64 + l];
        const uint4 f10 = frag[8 * 64 + l], f11 = frag[9 * 64 + l];
        #pragma unroll
        for (int mt = 0; mt < 4; ++mt) {
            acc[mt][0] = __builtin_amdgcn_mfma_f32_16x16x32_bf16(as_bf(eaf[mt][0]), as_bf(f00), acc[mt][0], 0, 0, 0);
            acc[mt][1] = __builtin_amdgcn_mfma_f32_16x16x32_bf16(as_bf(eaf[mt][0]), as_bf(f01), acc[mt][1], 0, 0, 0);
            acc[mt][0] = __builtin_amdgcn_mfma_f32_16x16x32_bf16(as_bf(eaf[mt][1]), as_bf(f10), acc[mt][0], 0, 0, 0);
            acc[mt][1] = __builtin_amdgcn_mfma_f32_16x16x32_bf16(as_bf(eaf[mt][1]), as_bf(f11), acc[mt][1], 0, 0, 0);
        }
        #pragma unroll
        for (int mt = 0; mt < 4; ++mt)
            #pragma unroll
            for (int nt = 0; nt < 2; ++nt)
                #pragma unroll
                for (int r = 0; r < 4; ++r)
                    L[(mt * 16 + lg * 4 + r) * LSTR + nt * 16 + lm] = ssp_f(acc[mt][nt][r]);

        const float b2a = wv2_b[lm], b2b = wv2_b[16 + lm];
        f32x4 acc2[4][2];
        const uint4 f20 = frag[10 * 64 + l], f21 = frag[11 * 64 + l];
        #pragma unroll
        for (int mt = 0; mt < 4; ++mt) {
            acc2[mt][0] = f32x4{b2a, b2a, b2a, b2a};
            acc2[mt][1] = f32x4{b2b, b2b, b2b, b2b};
            float av[8];
            #pragma unroll
            for (int j = 0; j < 8; ++j)
                av[j] = L[(mt * 16 + lm) * LSTR + lg * 8 + j];
            uint4 a2;
            a2.x = pk2f(av[0], av[1]); a2.y = pk2f(av[2], av[3]);
            a2.z = pk2f(av[4], av[5]); a2.w = pk2f(av[6], av[7]);
            acc2[mt][0] = __builtin_amdgcn_mfma_f32_16x16x32_bf16(as_bf(a2), as_bf(f20), acc2[mt][0], 0, 0, 0);
            acc2[mt][1] = __builtin_amdgcn_mfma_f32_16x16x32_bf16(as_bf(a2), as_bf(f21), acc2[mt][1], 0, 0, 0);
        }
        #pragma unroll
        for (int mt = 0; mt < 4; ++mt)
            #pragma unroll
            for (int nt = 0; nt < 2; ++nt)
                #pragma unroll
                for (int r = 0; r < 4; ++r)
                    L[(mt * 16 + lg * 4 + r) * LSTR + nt * 16 + lm] = acc2[mt][nt][r];
    }

    #pragma unroll
    for (int k = 0; k < 16; ++k) {
        const int f = k * 64 + l;
        const int pr = f >> 4, i = f & 15;
        wvP[(size_t)e0 * 16 + f] = pk2f(L[pr * LSTR + 2 * i], L[pr * LSTR + 2 * i + 1]);
    }
}

// ---------------- K3: fused aggregation + wvl matvec + LN2 + ssp ------------
__global__ __launch_bounds__(256) void k_aggr_tail(
    const float* __restrict__ qkP, const unsigned* __restrict__ wvP,
    const unsigned* __restrict__ hv_bf, const int* __restrict__ colv,
    const int* __restrict__ base, const int* __restrict__ deg,
    const float* __restrict__ x,
    const float* __restrict__ wvl_w, const float* __restrict__ wvl_b,
    const float* __restrict__ ln2_g, const float* __restrict__ ln2_b,
    float* __restrict__ x2P, unsigned* __restrict__ sbf)
{
    __shared__ float swvl[HH * 34];
    __shared__ float su[4][HD];
    for (int idx = threadIdx.x; idx < HH * HH; idx += 256)
        swvl[(idx >> 5) * 34 + (idx & 31)] = wvl_w[idx];
    __syncthreads();

    const int w = threadIdx.x >> 6, l = threadIdx.x & 63;
    const int h = l >> 4, i = l & 15;
    const int t0 = 2 * l;
    const float2 lg2 = *(const float2*)(ln2_g + t0);
    const float2 lb2 = *(const float2*)(ln2_b + t0);
    const int j0 = 2 * i;
    const float2 wb2 = *(const float2*)(wvl_b + j0);
    float* sb = su[w];

    for (int n = blockIdx.x * 4 + w; n < NN; n += 2048 * 4) {
        const int b0 = base[n];
        const int dn = deg[n];
        const float2 xv = *(const float2*)(x + (size_t)n * HD + t0);

        float acc0 = 0.f, acc1 = 0.f;
        if (dn > 0) {
            const float* qkh = qkP + (size_t)h * EE + b0;
            const int emax = b0 + dn - 1;
            float m = -3.0e38f;
            for (int c = i; c < dn; c += 16) m = fmaxf(m, qkh[c]);
            #pragma unroll
            for (int off = 1; off < 16; off <<= 1)
                m = fmaxf(m, __shfl_xor(m, off));
            float den = 0.f;
            for (int c = i; c < dn; c += 16) den += __expf(qkh[c] - m);
            #pragma unroll
            for (int off = 1; off < 16; off <<= 1) den += __shfl_xor(den, off);
            const float rden = (den > 0.f) ? 1.0f / den : 0.f;
            for (int c0 = 0; c0 < dn; c0 += 16) {
                const int tn = (dn - c0 < 16) ? (dn - c0) : 16;
                float ex = 0.f; int cq = 0;
                if (i < tn) {
                    ex = __expf(qkh[c0 + i] - m) * rden;
                    cq = colv[b0 + c0 + i];
                }
                const int t4 = (tn + 3) & ~3;
                for (int i2 = 0; i2 < t4; i2 += 4) {
                    #pragma unroll
                    for (int u = 0; u < 4; ++u) {
                        const int src = (l & 48) | (i2 + u);
                        const float wgt = __shfl(ex, src);
                        const int ce = __shfl(cq, src);
                        int ep = b0 + c0 + i2 + u;
                        ep = (ep > emax) ? emax : ep;
                        const unsigned hvv = hv_bf[(size_t)ce * 64 + l];
                        const unsigned wvv = wvP[(size_t)ep * 16 + i];
                        float ha, hb, wa, wb;
                        unp2(hvv, ha, hb); unp2(wvv, wa, wb);
                        acc0 = fmaf(wgt, wa * ha, acc0);
                        acc1 = fmaf(wgt, wb * hb, acc1);
                    }
                }
            }
        }

        *(float2*)(sb + t0) = make_float2(acc0, acc1);

        float ag0 = 0.f, ag1 = 0.f;
        if (dn > 0) {
            ag0 = wb2.x; ag1 = wb2.y;
            const float* uh = sb + h * HH;
            const float* r0 = swvl + j0 * 34;
            const float* r1 = r0 + 34;
            #pragma unroll
            for (int q = 0; q < 16; ++q) {
                const float2 u  = *(const float2*)(uh + 2 * q);
                const float2 a  = *(const float2*)(r0 + 2 * q);
                const float2 bb = *(const float2*)(r1 + 2 * q);
                ag0 = fmaf(u.x, a.x, ag0);  ag0 = fmaf(u.y, a.y, ag0);
                ag1 = fmaf(u.x, bb.x, ag1); ag1 = fmaf(u.y, bb.y, ag1);
            }
        }
        const float x20 = ag0 + xv.x;
        const float x21 = ag1 + xv.y;

        float s1 = x20 + x21, s2 = x20 * x20 + x21 * x21;
        #pragma unroll
        for (int off = 1; off < 64; off <<= 1) {
            s1 += __shfl_xor(s1, off);
            s2 += __shfl_xor(s2, off);
        }
        const float mean = s1 * (1.0f / HD);
        const float var  = s2 * (1.0f / HD) - mean * mean;
        const float rstd = rsqrtf(var + 1e-5f);
        const float ss0 = ssp_f((x20 - mean) * rstd * lg2.x + lb2.x);
        const float ss1 = ssp_f((x21 - mean) * rstd * lg2.y + lb2.y);

        *(float2*)(x2P + (size_t)n * HD + t0) = make_float2(x20, x21);
        sbf[(size_t)n * 64 + l] = pk2(ss0, ss1);
    }
}

// ---------------- K3c: MFMA out-GEMM: out = sbf @ out_w^T + out_b + x2 ------
__global__ __launch_bounds__(256) void k_tail_gemm(
    const unsigned short* __restrict__ sbf, const float* __restrict__ x2P,
    const uint4* __restrict__ owf, const float* __restrict__ out_b,
    float* __restrict__ out)
{
    const int w = threadIdx.x >> 6, l = threadIdx.x & 63;
    const int lm = l & 15, lg = l >> 4;
    const int tile = blockIdx.x * 4 + w;
    if (tile * 16 >= NN) return;
    const int n0 = tile * 16;

    uint4 af[4];
    #pragma unroll
    for (int kt = 0; kt < 4; ++kt)
        af[kt] = *(const uint4*)(sbf + (size_t)(n0 + lm) * HD + kt * 32 + lg * 8);

    f32x4 acc[8];
    #pragma unroll
    for (int nt = 0; nt < 8; ++nt) {
        const float b = out_b[nt * 16 + lm];
        acc[nt] = f32x4{b, b, b, b};
    }
    #pragma unroll
    for (int kt = 0; kt < 4; ++kt) {
        #pragma unroll
        for (int nt = 0; nt < 8; ++nt)
            acc[nt] = __builtin_amdgcn_mfma_f32_16x16x32_bf16(
                as_bf(af[kt]), as_bf(owf[(nt * 4 + kt) * 64 + l]), acc[nt], 0, 0, 0);
    }
    #pragma unroll
    for (int nt = 0; nt < 8; ++nt)
        #pragma unroll
        for (int r = 0; r < 4; ++r) {
            const size_t idx = (size_t)(n0 + lg * 4 + r) * HD + nt * 16 + lm;
            out[idx] = acc[nt][r] + x2P[idx];
        }
}

extern "C" void kernel_launch(void* const* d_in, const int* in_sizes, int n_in,
                              void* d_out, int out_size, void* d_ws, size_t ws_size,
                              hipStream_t stream) {
    const float* x         = (const float*)d_in[0];
    const float* edge_attr = (const float*)d_in[1];
    const int*   edge_index= (const int*)  d_in[2];
    const float* k_w   = (const float*)d_in[3];
    const float* q_w   = (const float*)d_in[4];
    const float* v_w   = (const float*)d_in[5];
    const float* wk1_w = (const float*)d_in[6];
    const float* wk1_b = (const float*)d_in[7];
    const float* wk2_w = (const float*)d_in[8];
    const float* wk2_b = (const float*)d_in[9];
    const float* wkl_w = (const float*)d_in[10];
    const float* wkl_b = (const float*)d_in[11];
    const float* wv1_w = (const float*)d_in[12];
    const float* wv1_b = (const float*)d_in[13];
    const float* wv2_w = (const float*)d_in[14];
    const float* wv2_b = (const float*)d_in[15];
    const float* wvl_w = (const float*)d_in[16];
    const float* wvl_b = (const float*)d_in[17];
    const float* out_w = (const float*)d_in[18];
    const float* out_b = (const float*)d_in[19];
    const float* ln1_g = (const float*)d_in[20];
    const float* ln1_b = (const float*)d_in[21];
    const float* ln2_g = (const float*)d_in[22];
    const float* ln2_b = (const float*)d_in[23];

    char* ws = (char*)d_ws;
    unsigned* hk_bf = (unsigned*)ws;            ws += (size_t)NN * 64 * 4;
    unsigned* hv_bf = (unsigned*)ws;            ws += (size_t)NN * 64 * 4;
    unsigned* g_bf  = (unsigned*)ws;            ws += (size_t)NN * 64 * 4;
    float* c0  = (float*)ws;                    ws += (size_t)NN * NHD * 4;
    float* qkP = (float*)ws;                    ws += (size_t)NHD * EE * 4;
    unsigned* wvP = (unsigned*)ws;              ws += (size_t)EE * 16 * 4;
    uint4* fragbuf = (uint4*)ws;                ws += (size_t)12 * 64 * 16;
    uint4* owfbuf  = (uint4*)ws;                ws += (size_t)32 * 64 * 16;
    uint4* pfbuf   = (uint4*)ws;                ws += (size_t)3 * 512 * 16;
    float* cw      = (float*)ws;                ws += (size_t)512 * 4;
    float* x2P = (float*)ws;                    ws += (size_t)NN * HD * 4;
    unsigned* sbf = (unsigned*)ws;              ws += (size_t)NN * 64 * 4;
    int* deg    = (int*)ws;                     ws += (size_t)NN * 4;
    int* base   = (int*)ws;                     ws += (size_t)NN * 4;
    int* cursor = (int*)ws;                     ws += (size_t)NN * 4;
    int* bsum   = (int*)ws;                     ws += (size_t)SCAN_B * 4;
    int* eidx   = (int*)ws;                     ws += (size_t)EE * 4;
    int* rowv   = (int*)ws;                     ws += (size_t)EE * 4;
    int* colv   = (int*)ws;                     ws += (size_t)EE * 4;

    (void)hipMemsetAsync(deg, 0, (size_t)NN * 4, stream);

    k_wfrag<<<1, 256, 0, stream>>>(wk1_w, wk2_w, wv1_w, wv2_w, fragbuf);
    k_owfrag<<<1, 256, 0, stream>>>(out_w, owfbuf);
    k_pwfrag<<<1, 256, 0, stream>>>(k_w, v_w, q_w, wkl_w, wkl_b, pfbuf, cw);
    k_ln1proj<<<1024, 256, 0, stream>>>(x, ln1_g, ln1_b, cw, pfbuf, c0,
        (unsigned short*)hk_bf, (unsigned short*)hv_bf, (unsigned short*)g_bf);
    k_deg<<<1024, 256, 0, stream>>>(edge_index, deg);
    k_scan_block<<<NBLK, SCAN_B, 0, stream>>>(deg, base, bsum);
    k_scan_top<<<1, SCAN_B, 0, stream>>>(bsum);
    k_scan_add<<<NBLK, SCAN_B, 0, stream>>>(base, bsum, cursor);
    k_scatter<<<1024, 256, 0, stream>>>(edge_index, cursor, eidx, rowv, colv);
    k_edge_mfma<<<EE / 256, 256, 0, stream>>>(edge_attr, eidx, rowv, colv,
        hk_bf, g_bf, c0, fragbuf,
        wk1_b, wk2_b, wv1_b, wv2_b, qkP, wvP);
    k_aggr_tail<<<2048, 256, 0, stream>>>(qkP, wvP, hv_bf, colv, base, deg,
        x, wvl_w, wvl_b, ln2_g, ln2_b, x2P, sbf);
    k_tail_gemm<<<(NN / 16 + 3) / 4, 256, 0, stream>>>(
        (const unsigned short*)sbf, x2P, owfbuf, out_b, (float*)d_out);
}